// Round 1
// baseline (2131.045 us; speedup 1.0000x reference)
//
#include <hip/hip_runtime.h>

#define N_TOTAL 194048
#define NE      3104768
#define HID     64
#define NNODES  1516
#define CIN     32
#define FIN     97024
#define EPS     1e-5f

// ---------------- setup: degree, dinv, CSR build ----------------
__global__ __launch_bounds__(256) void k_init(float* deg, int* cnt){
    int i = blockIdx.x*256 + threadIdx.x;
    if (i < N_TOTAL){ deg[i] = 1.0f; cnt[i] = 0; }   // self-loop weight 1
}

__global__ __launch_bounds__(256) void k_deg(const int* __restrict__ col,
                                             const float* __restrict__ w,
                                             float* deg, int* cnt){
    int e = blockIdx.x*256 + threadIdx.x;
    if (e < NE){
        int c = col[e];
        atomicAdd(&deg[c], w[e]);
        atomicAdd(&cnt[c], 1);
    }
}

__global__ __launch_bounds__(256) void k_dinv(const float* __restrict__ deg, float* dinv){
    int i = blockIdx.x*256 + threadIdx.x;
    if (i < N_TOTAL){
        float d = deg[i];
        dinv[i] = d > 0.f ? 1.0f/sqrtf(d) : 0.f;
    }
}

// block-level exclusive scan of cnt -> startv (within block), block totals -> bs
__global__ __launch_bounds__(256) void k_scan1(const int* __restrict__ cnt, int* startv, int* bs){
    __shared__ int s[256];
    int t = threadIdx.x;
    int i = blockIdx.x*256 + t;
    int v = (i < N_TOTAL) ? cnt[i] : 0;
    s[t] = v; __syncthreads();
    for (int off = 1; off < 256; off <<= 1){
        int u = (t >= off) ? s[t-off] : 0;
        __syncthreads();
        s[t] += u;
        __syncthreads();
    }
    if (i < N_TOTAL) startv[i] = s[t] - v;
    if (t == 255) bs[blockIdx.x] = s[255];
}

// single block scans the 758 block sums (3 elems/thread)
__global__ __launch_bounds__(256) void k_scan2(const int* __restrict__ bs, int* boff){
    __shared__ int s[256];
    int t = threadIdx.x;
    int i0 = t*3;
    int a = (i0   < 758) ? bs[i0]   : 0;
    int b = (i0+1 < 758) ? bs[i0+1] : 0;
    int c = (i0+2 < 758) ? bs[i0+2] : 0;
    int tot = a+b+c;
    s[t] = tot; __syncthreads();
    for (int off = 1; off < 256; off <<= 1){
        int u = (t >= off) ? s[t-off] : 0;
        __syncthreads();
        s[t] += u;
        __syncthreads();
    }
    int ex = s[t] - tot;
    if (i0   < 758) boff[i0]   = ex;
    if (i0+1 < 758) boff[i0+1] = ex + a;
    if (i0+2 < 758) boff[i0+2] = ex + a + b;
}

__global__ __launch_bounds__(256) void k_scan3(int* startv, const int* __restrict__ boff, int* cursor){
    int i = blockIdx.x*256 + threadIdx.x;
    if (i < N_TOTAL){ startv[i] += boff[i >> 8]; cursor[i] = 0; }
}

__global__ __launch_bounds__(256) void k_fill(const int* __restrict__ row, const int* __restrict__ col,
                                              const float* __restrict__ w, const float* __restrict__ dinv,
                                              const int* __restrict__ startv, int* cursor,
                                              int* __restrict__ csr_src, float* __restrict__ csr_norm){
    int e = blockIdx.x*256 + threadIdx.x;
    if (e < NE){
        int r = row[e], c = col[e];
        int pos  = atomicAdd(&cursor[c], 1);
        int slot = startv[c] + pos;
        csr_src[slot]  = r;
        csr_norm[slot] = dinv[r]*w[e]*dinv[c];
    }
}

// ---------------- dense GEMM: hW[n][64] = h[n][CINP] @ W[64][CINP]^T ----------------
template<int CINP, bool LAYER1>
__global__ __launch_bounds__(256) void k_gemm(const float* __restrict__ hin,
                                              const float* __restrict__ W,
                                              float* __restrict__ hW){
    constexpr int SH = CINP + 4;   // padded strides (16B-aligned rows, conflict-free)
    constexpr int SW = 68;
    __shared__ float sh_h[64*SH];
    __shared__ float sh_w[64*SW];
    int t = threadIdx.x;
    int nodeBase = blockIdx.x * 64;

    // stage W (row-major [64][CINP])
    #pragma unroll
    for (int r = 0; r < CINP/16; ++r){
        int flat = (r*256 + t)*4;
        int o = flat / CINP, k = flat - o*CINP;
        float4 v = *(const float4*)(W + flat);
        *(float4*)(&sh_w[o*SW + k]) = v;
    }
    // stage h
    if (LAYER1){
        // x layout [B][32][1516]; node = b*1516+nn  (fused transpose)
        int c  = t >> 3;     // 0..31
        int i8 = t & 7;
        #pragma unroll
        for (int jj = 0; jj < 8; ++jj){
            int nl   = i8*8 + jj;
            int node = nodeBase + nl;
            int b    = node / NNODES;
            int nn   = node - b*NNODES;
            sh_h[nl*SH + c] = hin[(b*CIN + c)*NNODES + nn];
        }
    } else {
        #pragma unroll
        for (int r = 0; r < CINP/16; ++r){
            int flat = (r*256 + t)*4;
            int nl = flat / CINP, k = flat - nl*CINP;
            float4 v = *(const float4*)(hin + (size_t)nodeBase*CINP + flat);
            *(float4*)(&sh_h[nl*SH + k]) = v;
        }
    }
    __syncthreads();

    int nl = t >> 2, q = t & 3;      // node, out-group (16 outputs)
    float acc[16];
    #pragma unroll
    for (int i = 0; i < 16; ++i) acc[i] = 0.f;
    const float* hrow = &sh_h[nl*SH];
    #pragma unroll
    for (int k = 0; k < CINP; k += 4){
        float4 hv = *(const float4*)(hrow + k);
        #pragma unroll
        for (int o = 0; o < 16; ++o){
            float4 wv = *(const float4*)(&sh_w[(q*16+o)*SW + k]);
            acc[o] += hv.x*wv.x + hv.y*wv.y + hv.z*wv.z + hv.w*wv.w;
        }
    }
    float* dst = hW + (size_t)(nodeBase + nl)*64 + q*16;
    #pragma unroll
    for (int o = 0; o < 4; ++o)
        *(float4*)(dst + o*4) = make_float4(acc[o*4], acc[o*4+1], acc[o*4+2], acc[o*4+3]);
}

// ---------------- CSR gather: out[i] = b + selfnorm*hW[i] + sum norm*hW[src] ----------------
__global__ __launch_bounds__(256) void k_gather(const float* __restrict__ hW, const float* __restrict__ bias,
                                                const float* __restrict__ dinv, const int* __restrict__ startv,
                                                const int* __restrict__ cnt, const int* __restrict__ csr_src,
                                                const float* __restrict__ csr_norm, float* __restrict__ out){
    int node = blockIdx.x*4 + (threadIdx.x >> 6);
    int f    = threadIdx.x & 63;
    if (node >= N_TOTAL) return;
    float di  = dinv[node];
    float acc = bias[f] + di*di*hW[(size_t)node*64 + f];
    int s0 = startv[node];
    int c  = cnt[node];
    for (int s = s0; s < s0 + c; ++s){
        acc += csr_norm[s] * hW[(size_t)csr_src[s]*64 + f];
    }
    out[(size_t)node*64 + f] = acc;
}

// ---------------- BN over node axis (per 64-feature channel) ----------------
__global__ __launch_bounds__(256) void k_bn_reduce(const float* __restrict__ x, float* gsum, float* gsq){
    int t = threadIdx.x;
    int f = t & 63, g4 = t >> 6;
    float s = 0.f, q = 0.f;
    for (int i = blockIdx.x*4 + g4; i < N_TOTAL; i += gridDim.x*4){
        float v = x[(size_t)i*64 + f];
        s += v; q += v*v;
    }
    __shared__ float sh[2][4][64];
    sh[0][g4][f] = s; sh[1][g4][f] = q;
    __syncthreads();
    if (t < 64){
        float ss = sh[0][0][t] + sh[0][1][t] + sh[0][2][t] + sh[0][3][t];
        float qq = sh[1][0][t] + sh[1][1][t] + sh[1][2][t] + sh[1][3][t];
        atomicAdd(&gsum[t], ss);
        atomicAdd(&gsq[t],  qq);
    }
}

__global__ void k_bn_final(const float* __restrict__ gsum, const float* __restrict__ gsq,
                           const float* __restrict__ g, const float* __restrict__ be,
                           float* scale, float* shift){
    int f = threadIdx.x;
    if (f < 64){
        float mean = gsum[f] / (float)N_TOTAL;
        float var  = gsq[f] / (float)N_TOTAL - mean*mean;
        float sc   = g[f] / sqrtf(var + EPS);
        scale[f] = sc;
        shift[f] = be[f] - mean*sc;
    }
}

__global__ __launch_bounds__(256) void k_bn_relu(float* __restrict__ x, const float* __restrict__ scale,
                                                 const float* __restrict__ shift){
    int i = blockIdx.x*256 + threadIdx.x;      // float4 index; N_TOTAL*16 total
    if (i < N_TOTAL*16){
        float4 v = ((float4*)x)[i];
        int f = (i & 15)*4;
        v.x = fmaxf(0.f, v.x*scale[f]   + shift[f]);
        v.y = fmaxf(0.f, v.y*scale[f+1] + shift[f+1]);
        v.z = fmaxf(0.f, v.z*scale[f+2] + shift[f+2]);
        v.w = fmaxf(0.f, v.w*scale[f+3] + shift[f+3]);
        ((float4*)x)[i] = v;
    }
}

// ---------------- FC1: C[128][128] = A[128][97024] @ Wl1[128][97024]^T  (split-K) ----------------
__global__ __launch_bounds__(256) void k_fc1_part(const float* __restrict__ A,
                                                  const float* __restrict__ Wl1,
                                                  float* __restrict__ part){
    int bid = blockIdx.x;                 // 512 = 128 k-chunks * 4 (bb,jb) tiles
    int kc  = bid >> 2, sub = bid & 3;
    int bb  = (sub >> 1) * 64, jb = (sub & 1) * 64;
    int t = threadIdx.x;
    int tb = t >> 4, tj = t & 15;
    int b0 = bb + tb*4, j0 = jb + tj*4;
    const float* a0 = A   + (size_t)b0*FIN + kc*758;
    const float* w0 = Wl1 + (size_t)j0*FIN + kc*758;
    float acc[4][4] = {};
    for (int k = 0; k < 758; k += 2){
        float2 a[4], w[4];
        #pragma unroll
        for (int i = 0; i < 4; ++i) a[i] = *(const float2*)(a0 + (size_t)i*FIN + k);
        #pragma unroll
        for (int j = 0; j < 4; ++j) w[j] = *(const float2*)(w0 + (size_t)j*FIN + k);
        #pragma unroll
        for (int i = 0; i < 4; ++i)
            #pragma unroll
            for (int j = 0; j < 4; ++j)
                acc[i][j] += a[i].x*w[j].x + a[i].y*w[j].y;
    }
    float* p = part + (size_t)bid*4096;
    #pragma unroll
    for (int i = 0; i < 4; ++i)
        #pragma unroll
        for (int j = 0; j < 4; ++j)
            p[(tb*4+i)*64 + tj*4+j] = acc[i][j];
}

__global__ __launch_bounds__(256) void k_fc1_reduce(const float* __restrict__ part,
                                                    const float* __restrict__ bl1,
                                                    float* __restrict__ C){
    int idx = blockIdx.x*256 + threadIdx.x;   // 16384
    int b = idx >> 7, j = idx & 127;
    int sub = ((b >> 6) << 1) | (j >> 6);
    const float* p = part + (size_t)sub*4096 + (b & 63)*64 + (j & 63);
    float s = 0.f;
    for (int kc = 0; kc < 128; ++kc) s += p[(size_t)kc*4*4096];
    C[idx] = s + bl1[j];
}

__global__ void k_fc_stats(const float* __restrict__ C, const float* __restrict__ g,
                           const float* __restrict__ be, float* scale2, float* shift2){
    int j = threadIdx.x;
    if (j < 128){
        float s = 0.f, q = 0.f;
        for (int b = 0; b < 128; ++b){ float v = C[b*128 + j]; s += v; q += v*v; }
        float mean = s / 128.f;
        float var  = q / 128.f - mean*mean;
        float sc   = g[j] / sqrtf(var + EPS);
        scale2[j] = sc;
        shift2[j] = be[j] - mean*sc;
    }
}

__global__ __launch_bounds__(256) void k_fc2(const float* __restrict__ C, const float* __restrict__ scale2,
                                             const float* __restrict__ shift2, const float* __restrict__ Wl3,
                                             const float* __restrict__ bl3, float* __restrict__ out){
    int id = blockIdx.x*256 + threadIdx.x;
    if (id < 1280){
        int b = id / 10, c = id - b*10;
        float acc = bl3[c];
        for (int j = 0; j < 128; ++j){
            float hv = fmaxf(0.f, C[b*128 + j]*scale2[j] + shift2[j]);
            acc += hv * Wl3[c*128 + j];
        }
        out[id] = acc;
    }
}

// ---------------- launch ----------------
extern "C" void kernel_launch(void* const* d_in, const int* in_sizes, int n_in,
                              void* d_out, int out_size, void* d_ws, size_t ws_size,
                              hipStream_t stream){
    const float* x   = (const float*)d_in[0];
    const int*   ei  = (const int*)  d_in[1];
    const float* ew  = (const float*)d_in[2];
    const float* W1  = (const float*)d_in[3];
    const float* b1  = (const float*)d_in[4];
    const float* W2  = (const float*)d_in[5];
    const float* b2  = (const float*)d_in[6];
    const float* W3  = (const float*)d_in[7];
    const float* b3  = (const float*)d_in[8];
    const float* g1  = (const float*)d_in[9];
    const float* be1 = (const float*)d_in[10];
    const float* g2  = (const float*)d_in[11];
    const float* be2 = (const float*)d_in[12];
    const float* g3  = (const float*)d_in[13];
    const float* be3 = (const float*)d_in[14];
    const float* Wl1 = (const float*)d_in[15];
    const float* bl1 = (const float*)d_in[16];
    const float* gl1 = (const float*)d_in[17];
    const float* bel1= (const float*)d_in[18];
    const float* Wl3 = (const float*)d_in[19];
    const float* bl3 = (const float*)d_in[20];
    const int* row = ei;
    const int* col = ei + NE;

    char* p = (char*)d_ws;
    auto alloc = [&](size_t bytes)->char*{
        char* r = p; p += (bytes + 255) & ~(size_t)255; return r;
    };
    float* bufA     = (float*)alloc((size_t)N_TOTAL*64*4);
    float* bufB     = (float*)alloc((size_t)N_TOTAL*64*4);
    float* deg      = (float*)alloc(N_TOTAL*4);
    float* dinv     = (float*)alloc(N_TOTAL*4);
    int*   cnt      = (int*)  alloc(N_TOTAL*4);
    int*   startv   = (int*)  alloc(N_TOTAL*4);
    int*   cursor   = (int*)  alloc(N_TOTAL*4);
    int*   bs       = (int*)  alloc(4096);
    int*   boff     = (int*)  alloc(4096);
    int*   csr_src  = (int*)  alloc((size_t)NE*4);
    float* csr_norm = (float*)alloc((size_t)NE*4);
    float* gsum     = (float*)alloc(256);
    float* gsq      = (float*)alloc(256);
    float* scale    = (float*)alloc(256);
    float* shift    = (float*)alloc(256);
    float* part     = (float*)alloc((size_t)512*4096*4);
    float* Cfc      = (float*)alloc(65536);
    float* scale2   = (float*)alloc(512);
    float* shift2   = (float*)alloc(512);

    const int NB_N = 758;     // N_TOTAL/256
    const int NB_E = 12128;   // NE/256
    k_init <<<NB_N, 256, 0, stream>>>(deg, cnt);
    k_deg  <<<NB_E, 256, 0, stream>>>(col, ew, deg, cnt);
    k_dinv <<<NB_N, 256, 0, stream>>>(deg, dinv);
    k_scan1<<<NB_N, 256, 0, stream>>>(cnt, startv, bs);
    k_scan2<<<1,    256, 0, stream>>>(bs, boff);
    k_scan3<<<NB_N, 256, 0, stream>>>(startv, boff, cursor);
    k_fill <<<NB_E, 256, 0, stream>>>(row, col, ew, dinv, startv, cursor, csr_src, csr_norm);

    // ---- layer 1 ----
    k_gemm<32, true><<<3032, 256, 0, stream>>>(x, W1, bufB);
    hipMemsetAsync(gsum, 0, 512, stream);          // gsum+gsq contiguous
    k_gather   <<<48512, 256, 0, stream>>>(bufB, b1, dinv, startv, cnt, csr_src, csr_norm, bufA);
    k_bn_reduce<<<1024,  256, 0, stream>>>(bufA, gsum, gsq);
    k_bn_final <<<1, 64, 0, stream>>>(gsum, gsq, g1, be1, scale, shift);
    k_bn_relu  <<<12128, 256, 0, stream>>>(bufA, scale, shift);
    // ---- layer 2 ----
    k_gemm<64, false><<<3032, 256, 0, stream>>>(bufA, W2, bufB);
    hipMemsetAsync(gsum, 0, 512, stream);
    k_gather   <<<48512, 256, 0, stream>>>(bufB, b2, dinv, startv, cnt, csr_src, csr_norm, bufA);
    k_bn_reduce<<<1024,  256, 0, stream>>>(bufA, gsum, gsq);
    k_bn_final <<<1, 64, 0, stream>>>(gsum, gsq, g2, be2, scale, shift);
    k_bn_relu  <<<12128, 256, 0, stream>>>(bufA, scale, shift);
    // ---- layer 3 ----
    k_gemm<64, false><<<3032, 256, 0, stream>>>(bufA, W3, bufB);
    hipMemsetAsync(gsum, 0, 512, stream);
    k_gather   <<<48512, 256, 0, stream>>>(bufB, b3, dinv, startv, cnt, csr_src, csr_norm, bufA);
    k_bn_reduce<<<1024,  256, 0, stream>>>(bufA, gsum, gsq);
    k_bn_final <<<1, 64, 0, stream>>>(gsum, gsq, g3, be3, scale, shift);
    k_bn_relu  <<<12128, 256, 0, stream>>>(bufA, scale, shift);

    // ---- FC head ----
    k_fc1_part  <<<512, 256, 0, stream>>>(bufA, Wl1, part);
    k_fc1_reduce<<<64,  256, 0, stream>>>(part, bl1, Cfc);
    k_fc_stats  <<<1,   128, 0, stream>>>(Cfc, gl1, bel1, scale2, shift2);
    k_fc2       <<<5,   256, 0, stream>>>(Cfc, scale2, shift2, Wl3, bl3, (float*)d_out);
}

// Round 2
// 1819.182 us; speedup vs baseline: 1.1714x; 1.1714x over previous
//
#include <hip/hip_runtime.h>

#define N_TOTAL 194048
#define NE      3104768
#define HID     64
#define NNODES  1516
#define CIN     32
#define FIN     97024
#define EPS     1e-5f

// ---------------- setup: degree, dinv, CSR build ----------------
__global__ __launch_bounds__(256) void k_init(float* deg, int* cnt){
    int i = blockIdx.x*256 + threadIdx.x;
    if (i < N_TOTAL){ deg[i] = 1.0f; cnt[i] = 0; }   // self-loop weight 1
}

__global__ __launch_bounds__(256) void k_deg(const int* __restrict__ col,
                                             const float* __restrict__ w,
                                             float* deg, int* cnt){
    int e = blockIdx.x*256 + threadIdx.x;
    if (e < NE){
        int c = col[e];
        atomicAdd(&deg[c], w[e]);
        atomicAdd(&cnt[c], 1);
    }
}

__global__ __launch_bounds__(256) void k_dinv(const float* __restrict__ deg, float* dinv){
    int i = blockIdx.x*256 + threadIdx.x;
    if (i < N_TOTAL){
        float d = deg[i];
        dinv[i] = d > 0.f ? 1.0f/sqrtf(d) : 0.f;
    }
}

// block-level exclusive scan of cnt -> startv (within block), block totals -> bs
__global__ __launch_bounds__(256) void k_scan1(const int* __restrict__ cnt, int* startv, int* bs){
    __shared__ int s[256];
    int t = threadIdx.x;
    int i = blockIdx.x*256 + t;
    int v = (i < N_TOTAL) ? cnt[i] : 0;
    s[t] = v; __syncthreads();
    for (int off = 1; off < 256; off <<= 1){
        int u = (t >= off) ? s[t-off] : 0;
        __syncthreads();
        s[t] += u;
        __syncthreads();
    }
    if (i < N_TOTAL) startv[i] = s[t] - v;
    if (t == 255) bs[blockIdx.x] = s[255];
}

// single block scans the 758 block sums (3 elems/thread)
__global__ __launch_bounds__(256) void k_scan2(const int* __restrict__ bs, int* boff){
    __shared__ int s[256];
    int t = threadIdx.x;
    int i0 = t*3;
    int a = (i0   < 758) ? bs[i0]   : 0;
    int b = (i0+1 < 758) ? bs[i0+1] : 0;
    int c = (i0+2 < 758) ? bs[i0+2] : 0;
    int tot = a+b+c;
    s[t] = tot; __syncthreads();
    for (int off = 1; off < 256; off <<= 1){
        int u = (t >= off) ? s[t-off] : 0;
        __syncthreads();
        s[t] += u;
        __syncthreads();
    }
    int ex = s[t] - tot;
    if (i0   < 758) boff[i0]   = ex;
    if (i0+1 < 758) boff[i0+1] = ex + a;
    if (i0+2 < 758) boff[i0+2] = ex + a + b;
}

__global__ __launch_bounds__(256) void k_scan3(int* startv, const int* __restrict__ boff, int* cursor){
    int i = blockIdx.x*256 + threadIdx.x;
    if (i < N_TOTAL){ startv[i] += boff[i >> 8]; cursor[i] = 0; }
}

__global__ __launch_bounds__(256) void k_fill(const int* __restrict__ row, const int* __restrict__ col,
                                              const float* __restrict__ w, const float* __restrict__ dinv,
                                              const int* __restrict__ startv, int* cursor,
                                              int* __restrict__ csr_src, float* __restrict__ csr_norm){
    int e = blockIdx.x*256 + threadIdx.x;
    if (e < NE){
        int r = row[e], c = col[e];
        int pos  = atomicAdd(&cursor[c], 1);
        int slot = startv[c] + pos;
        csr_src[slot]  = r;
        csr_norm[slot] = dinv[r]*w[e]*dinv[c];
    }
}

// ---------------- dense GEMM: hW[n][64] = f(h)[n][CINP] @ W[64][CINP]^T ----------------
// MODE 0: layer1 (x is [B][32][1516], fused transpose, no BN)
// MODE 1: hin is pre-BN [n][64]; apply relu(v*scale+shift) while staging
template<int CINP, int MODE>
__global__ __launch_bounds__(256) void k_gemm(const float* __restrict__ hin,
                                              const float* __restrict__ W,
                                              const float* __restrict__ scale,
                                              const float* __restrict__ shift,
                                              float* __restrict__ hW){
    constexpr int SH = CINP + 4;   // padded strides
    constexpr int SW = 68;
    __shared__ float sh_h[64*SH];
    __shared__ float sh_w[64*SW];
    __shared__ float s_sc[64], s_sh[64];
    int t = threadIdx.x;
    int nodeBase = blockIdx.x * 64;

    if (MODE == 1 && t < 64){ s_sc[t] = scale[t]; s_sh[t] = shift[t]; }
    // stage W (row-major [64][CINP])
    #pragma unroll
    for (int r = 0; r < CINP/16; ++r){
        int flat = (r*256 + t)*4;
        int o = flat / CINP, k = flat - o*CINP;
        float4 v = *(const float4*)(W + flat);
        *(float4*)(&sh_w[o*SW + k]) = v;
    }
    __syncthreads();
    // stage h
    if (MODE == 0){
        // x layout [B][32][1516]; node = b*1516+nn  (fused transpose)
        int c  = t >> 3;     // 0..31
        int i8 = t & 7;
        #pragma unroll
        for (int jj = 0; jj < 8; ++jj){
            int nl   = i8*8 + jj;
            int node = nodeBase + nl;
            int b    = node / NNODES;
            int nn   = node - b*NNODES;
            sh_h[nl*SH + c] = hin[(b*CIN + c)*NNODES + nn];
        }
    } else {
        #pragma unroll
        for (int r = 0; r < CINP/16; ++r){
            int flat = (r*256 + t)*4;
            int nl = flat / CINP, k = flat - nl*CINP;
            float4 v = *(const float4*)(hin + (size_t)nodeBase*CINP + flat);
            v.x = fmaxf(0.f, v.x*s_sc[k]   + s_sh[k]);
            v.y = fmaxf(0.f, v.y*s_sc[k+1] + s_sh[k+1]);
            v.z = fmaxf(0.f, v.z*s_sc[k+2] + s_sh[k+2]);
            v.w = fmaxf(0.f, v.w*s_sc[k+3] + s_sh[k+3]);
            *(float4*)(&sh_h[nl*SH + k]) = v;
        }
    }
    __syncthreads();

    int nl = t >> 2, q = t & 3;      // node, out-group (16 outputs)
    float acc[16];
    #pragma unroll
    for (int i = 0; i < 16; ++i) acc[i] = 0.f;
    const float* hrow = &sh_h[nl*SH];
    #pragma unroll
    for (int k = 0; k < CINP; k += 4){
        float4 hv = *(const float4*)(hrow + k);
        #pragma unroll
        for (int o = 0; o < 16; ++o){
            float4 wv = *(const float4*)(&sh_w[(q*16+o)*SW + k]);
            acc[o] += hv.x*wv.x + hv.y*wv.y + hv.z*wv.z + hv.w*wv.w;
        }
    }
    float* dst = hW + (size_t)(nodeBase + nl)*64 + q*16;
    #pragma unroll
    for (int o = 0; o < 4; ++o)
        *(float4*)(dst + o*4) = make_float4(acc[o*4], acc[o*4+1], acc[o*4+2], acc[o*4+3]);
}

// ---------------- CSR gather: out[i] = b + selfnorm*hW[i] + sum norm*hW[src] ----------------
__global__ __launch_bounds__(256) void k_gather(const float* __restrict__ hW, const float* __restrict__ bias,
                                                const float* __restrict__ dinv, const int* __restrict__ startv,
                                                const int* __restrict__ cnt, const int* __restrict__ csr_src,
                                                const float* __restrict__ csr_norm, float* __restrict__ out){
    int node = blockIdx.x*4 + (threadIdx.x >> 6);
    int f    = threadIdx.x & 63;
    if (node >= N_TOTAL) return;
    float di  = dinv[node];
    float acc = bias[f] + di*di*hW[(size_t)node*64 + f];
    int s0 = startv[node];
    int c  = cnt[node];
    for (int s = s0; s < s0 + c; ++s){
        acc += csr_norm[s] * hW[(size_t)csr_src[s]*64 + f];
    }
    out[(size_t)node*64 + f] = acc;
}

// ---------------- BN stats over node axis (per 64-feature channel) ----------------
__global__ __launch_bounds__(256) void k_bn_reduce(const float* __restrict__ x, float* gsum, float* gsq){
    int t = threadIdx.x;
    int f = t & 63, g4 = t >> 6;
    float s = 0.f, q = 0.f;
    for (int i = blockIdx.x*4 + g4; i < N_TOTAL; i += gridDim.x*4){
        float v = x[(size_t)i*64 + f];
        s += v; q += v*v;
    }
    __shared__ float sh[2][4][64];
    sh[0][g4][f] = s; sh[1][g4][f] = q;
    __syncthreads();
    if (t < 64){
        float ss = sh[0][0][t] + sh[0][1][t] + sh[0][2][t] + sh[0][3][t];
        float qq = sh[1][0][t] + sh[1][1][t] + sh[1][2][t] + sh[1][3][t];
        atomicAdd(&gsum[t], ss);
        atomicAdd(&gsq[t],  qq);
    }
}

__global__ void k_bn_final(const float* __restrict__ gsum, const float* __restrict__ gsq,
                           const float* __restrict__ g, const float* __restrict__ be,
                           float* scale, float* shift){
    int f = threadIdx.x;
    if (f < 64){
        float mean = gsum[f] / (float)N_TOTAL;
        float var  = gsq[f] / (float)N_TOTAL - mean*mean;
        float sc   = g[f] / sqrtf(var + EPS);
        scale[f] = sc;
        shift[f] = be[f] - mean*sc;
    }
}

// ---------------- FC1: C[128][128] = relu(bn(A))[128][97024] @ Wl1[128][97024]^T ----------------
// Split-K: 758 blocks, 4 K-tiles of 32 each. LDS-tiled, coalesced staging,
// 8x8 register tiles with interleaved row/col mapping (conflict-free LDS reads).
__global__ __launch_bounds__(256) void k_fc1(const float* __restrict__ A,
                                             const float* __restrict__ Wl1,
                                             const float* __restrict__ scale,
                                             const float* __restrict__ shift,
                                             float* __restrict__ part){
    __shared__ float sA[128*36];
    __shared__ float sW[128*36];
    __shared__ float s_sc[64], s_sh[64];
    int t = threadIdx.x;
    if (t < 64){ s_sc[t] = scale[t]; s_sh[t] = shift[t]; }
    int tr = t >> 4, tc = t & 15;
    float acc[8][8] = {};
    for (int ti = 0; ti < 4; ++ti){
        int tile  = blockIdx.x*4 + ti;
        int kbase = tile*32;
        int fb    = (tile & 1) << 5;
        __syncthreads();     // LDS reuse + s_sc visibility on first iter
        #pragma unroll
        for (int r = 0; r < 4; ++r){
            int f4  = r*256 + t;
            int rowi = f4 >> 3, kq = (f4 & 7)*4;
            size_t gofs = (size_t)rowi*FIN + kbase + kq;
            float4 a = *(const float4*)(A + gofs);
            int f = fb + kq;
            a.x = fmaxf(0.f, a.x*s_sc[f]   + s_sh[f]);
            a.y = fmaxf(0.f, a.y*s_sc[f+1] + s_sh[f+1]);
            a.z = fmaxf(0.f, a.z*s_sc[f+2] + s_sh[f+2]);
            a.w = fmaxf(0.f, a.w*s_sc[f+3] + s_sh[f+3]);
            *(float4*)(&sA[rowi*36 + kq]) = a;
            float4 w = *(const float4*)(Wl1 + gofs);
            *(float4*)(&sW[rowi*36 + kq]) = w;
        }
        __syncthreads();
        #pragma unroll 2
        for (int k = 0; k < 32; k += 2){
            float2 a2[8], w2[8];
            #pragma unroll
            for (int i = 0; i < 8; ++i) a2[i] = *(const float2*)(&sA[(tr+16*i)*36 + k]);
            #pragma unroll
            for (int j = 0; j < 8; ++j) w2[j] = *(const float2*)(&sW[(tc+16*j)*36 + k]);
            #pragma unroll
            for (int i = 0; i < 8; ++i)
                #pragma unroll
                for (int j = 0; j < 8; ++j)
                    acc[i][j] += a2[i].x*w2[j].x + a2[i].y*w2[j].y;
        }
    }
    float* p = part + (size_t)blockIdx.x*16384;
    #pragma unroll
    for (int i = 0; i < 8; ++i)
        #pragma unroll
        for (int j = 0; j < 8; ++j)
            p[(tr+16*i)*128 + tc+16*j] = acc[i][j];
}

__global__ __launch_bounds__(256) void k_fc1_reduce(const float* __restrict__ part,
                                                    const float* __restrict__ bl1,
                                                    float* __restrict__ C){
    int idx = blockIdx.x*256 + threadIdx.x;   // 16384
    float s = 0.f;
    for (int kc = 0; kc < 758; ++kc) s += part[(size_t)kc*16384 + idx];
    C[idx] = s + bl1[idx & 127];
}

__global__ void k_fc_stats(const float* __restrict__ C, const float* __restrict__ g,
                           const float* __restrict__ be, float* scale2, float* shift2){
    int j = threadIdx.x;
    if (j < 128){
        float s = 0.f, q = 0.f;
        for (int b = 0; b < 128; ++b){ float v = C[b*128 + j]; s += v; q += v*v; }
        float mean = s / 128.f;
        float var  = q / 128.f - mean*mean;
        float sc   = g[j] / sqrtf(var + EPS);
        scale2[j] = sc;
        shift2[j] = be[j] - mean*sc;
    }
}

__global__ __launch_bounds__(256) void k_fc2(const float* __restrict__ C, const float* __restrict__ scale2,
                                             const float* __restrict__ shift2, const float* __restrict__ Wl3,
                                             const float* __restrict__ bl3, float* __restrict__ out){
    int id = blockIdx.x*256 + threadIdx.x;
    if (id < 1280){
        int b = id / 10, c = id - b*10;
        float acc = bl3[c];
        for (int j = 0; j < 128; ++j){
            float hv = fmaxf(0.f, C[b*128 + j]*scale2[j] + shift2[j]);
            acc += hv * Wl3[c*128 + j];
        }
        out[id] = acc;
    }
}

// ---------------- launch ----------------
extern "C" void kernel_launch(void* const* d_in, const int* in_sizes, int n_in,
                              void* d_out, int out_size, void* d_ws, size_t ws_size,
                              hipStream_t stream){
    const float* x   = (const float*)d_in[0];
    const int*   ei  = (const int*)  d_in[1];
    const float* ew  = (const float*)d_in[2];
    const float* W1  = (const float*)d_in[3];
    const float* b1  = (const float*)d_in[4];
    const float* W2  = (const float*)d_in[5];
    const float* b2  = (const float*)d_in[6];
    const float* W3  = (const float*)d_in[7];
    const float* b3  = (const float*)d_in[8];
    const float* g1  = (const float*)d_in[9];
    const float* be1 = (const float*)d_in[10];
    const float* g2  = (const float*)d_in[11];
    const float* be2 = (const float*)d_in[12];
    const float* g3  = (const float*)d_in[13];
    const float* be3 = (const float*)d_in[14];
    const float* Wl1 = (const float*)d_in[15];
    const float* bl1 = (const float*)d_in[16];
    const float* gl1 = (const float*)d_in[17];
    const float* bel1= (const float*)d_in[18];
    const float* Wl3 = (const float*)d_in[19];
    const float* bl3 = (const float*)d_in[20];
    const int* row = ei;
    const int* col = ei + NE;

    char* p = (char*)d_ws;
    auto alloc = [&](size_t bytes)->char*{
        char* r = p; p += (bytes + 255) & ~(size_t)255; return r;
    };
    float* bufA     = (float*)alloc((size_t)N_TOTAL*64*4);
    float* bufB     = (float*)alloc((size_t)N_TOTAL*64*4);   // hW scratch; reused as FC1 partials
    float* deg      = (float*)alloc(N_TOTAL*4);
    float* dinv     = (float*)alloc(N_TOTAL*4);
    int*   cnt      = (int*)  alloc(N_TOTAL*4);
    int*   startv   = (int*)  alloc(N_TOTAL*4);
    int*   cursor   = (int*)  alloc(N_TOTAL*4);
    int*   bs       = (int*)  alloc(4096);
    int*   boff     = (int*)  alloc(4096);
    int*   csr_src  = (int*)  alloc((size_t)NE*4);
    float* csr_norm = (float*)alloc((size_t)NE*4);
    float* gsum     = (float*)alloc(256);
    float* gsq      = (float*)alloc(256);
    float* scale1   = (float*)alloc(256);
    float* shift1   = (float*)alloc(256);
    float* scale2l  = (float*)alloc(256);
    float* shift2l  = (float*)alloc(256);
    float* scale3   = (float*)alloc(256);
    float* shift3   = (float*)alloc(256);
    float* Cfc      = (float*)alloc(65536);
    float* scaleF   = (float*)alloc(512);
    float* shiftF   = (float*)alloc(512);

    const int NB_N = 758;     // N_TOTAL/256
    const int NB_E = 12128;   // NE/256
    k_init <<<NB_N, 256, 0, stream>>>(deg, cnt);
    k_deg  <<<NB_E, 256, 0, stream>>>(col, ew, deg, cnt);
    k_dinv <<<NB_N, 256, 0, stream>>>(deg, dinv);
    k_scan1<<<NB_N, 256, 0, stream>>>(cnt, startv, bs);
    k_scan2<<<1,    256, 0, stream>>>(bs, boff);
    k_scan3<<<NB_N, 256, 0, stream>>>(startv, boff, cursor);
    k_fill <<<NB_E, 256, 0, stream>>>(row, col, ew, dinv, startv, cursor, csr_src, csr_norm);

    // ---- layer 1 ----
    k_gemm<32, 0><<<3032, 256, 0, stream>>>(x, W1, nullptr, nullptr, bufB);
    hipMemsetAsync(gsum, 0, 512, stream);          // gsum+gsq contiguous
    k_gather   <<<48512, 256, 0, stream>>>(bufB, b1, dinv, startv, cnt, csr_src, csr_norm, bufA);
    k_bn_reduce<<<1024,  256, 0, stream>>>(bufA, gsum, gsq);
    k_bn_final <<<1, 64, 0, stream>>>(gsum, gsq, g1, be1, scale1, shift1);
    // ---- layer 2 (BN1+ReLU fused into GEMM staging) ----
    k_gemm<64, 1><<<3032, 256, 0, stream>>>(bufA, W2, scale1, shift1, bufB);
    hipMemsetAsync(gsum, 0, 512, stream);
    k_gather   <<<48512, 256, 0, stream>>>(bufB, b2, dinv, startv, cnt, csr_src, csr_norm, bufA);
    k_bn_reduce<<<1024,  256, 0, stream>>>(bufA, gsum, gsq);
    k_bn_final <<<1, 64, 0, stream>>>(gsum, gsq, g2, be2, scale2l, shift2l);
    // ---- layer 3 ----
    k_gemm<64, 1><<<3032, 256, 0, stream>>>(bufA, W3, scale2l, shift2l, bufB);
    hipMemsetAsync(gsum, 0, 512, stream);
    k_gather   <<<48512, 256, 0, stream>>>(bufB, b3, dinv, startv, cnt, csr_src, csr_norm, bufA);
    k_bn_reduce<<<1024,  256, 0, stream>>>(bufA, gsum, gsq);
    k_bn_final <<<1, 64, 0, stream>>>(gsum, gsq, g3, be3, scale3, shift3);

    // ---- FC head (BN3+ReLU fused into FC1 A-staging; bufB reused as partials) ----
    k_fc1       <<<758, 256, 0, stream>>>(bufA, Wl1, scale3, shift3, bufB);
    k_fc1_reduce<<<64,  256, 0, stream>>>(bufB, bl1, Cfc);
    k_fc_stats  <<<1,   128, 0, stream>>>(Cfc, gl1, bel1, scaleF, shiftF);
    k_fc2       <<<5,   256, 0, stream>>>(Cfc, scaleF, shiftF, Wl3, bl3, (float*)d_out);
}

// Round 3
// 1753.726 us; speedup vs baseline: 1.2152x; 1.0373x over previous
//
#include <hip/hip_runtime.h>
#include <hip/hip_fp16.h>

#define N_TOTAL 194048
#define NE      3104768
#define HID     64
#define NNODES  1516
#define CIN     32
#define FIN     97024
#define EPS     1e-5f

__device__ inline uint f2u(float a, float b){
    __half2 h = __floats2half2_rn(a, b);
    return *(const uint*)&h;
}
__device__ inline float2 u2f(uint u){
    __half2 h = *(const __half2*)&u;
    return __half22float2(h);
}

// ---------------- setup: degree, dinv, CSR build ----------------
__global__ __launch_bounds__(256) void k_init(float* deg, int* cnt){
    int i = blockIdx.x*256 + threadIdx.x;
    if (i < N_TOTAL){ deg[i] = 1.0f; cnt[i] = 0; }   // self-loop weight 1
}

__global__ __launch_bounds__(256) void k_deg(const int* __restrict__ col,
                                             const float* __restrict__ w,
                                             float* deg, int* cnt){
    int e = blockIdx.x*256 + threadIdx.x;
    if (e < NE){
        int c = col[e];
        atomicAdd(&deg[c], w[e]);
        atomicAdd(&cnt[c], 1);
    }
}

__global__ __launch_bounds__(256) void k_dinv(const float* __restrict__ deg, float* dinv){
    int i = blockIdx.x*256 + threadIdx.x;
    if (i < N_TOTAL){
        float d = deg[i];
        dinv[i] = d > 0.f ? 1.0f/sqrtf(d) : 0.f;
    }
}

__global__ __launch_bounds__(256) void k_scan1(const int* __restrict__ cnt, int* startv, int* bs){
    __shared__ int s[256];
    int t = threadIdx.x;
    int i = blockIdx.x*256 + t;
    int v = (i < N_TOTAL) ? cnt[i] : 0;
    s[t] = v; __syncthreads();
    for (int off = 1; off < 256; off <<= 1){
        int u = (t >= off) ? s[t-off] : 0;
        __syncthreads();
        s[t] += u;
        __syncthreads();
    }
    if (i < N_TOTAL) startv[i] = s[t] - v;
    if (t == 255) bs[blockIdx.x] = s[255];
}

__global__ __launch_bounds__(256) void k_scan2(const int* __restrict__ bs, int* boff){
    __shared__ int s[256];
    int t = threadIdx.x;
    int i0 = t*3;
    int a = (i0   < 758) ? bs[i0]   : 0;
    int b = (i0+1 < 758) ? bs[i0+1] : 0;
    int c = (i0+2 < 758) ? bs[i0+2] : 0;
    int tot = a+b+c;
    s[t] = tot; __syncthreads();
    for (int off = 1; off < 256; off <<= 1){
        int u = (t >= off) ? s[t-off] : 0;
        __syncthreads();
        s[t] += u;
        __syncthreads();
    }
    int ex = s[t] - tot;
    if (i0   < 758) boff[i0]   = ex;
    if (i0+1 < 758) boff[i0+1] = ex + a;
    if (i0+2 < 758) boff[i0+2] = ex + a + b;
}

__global__ __launch_bounds__(256) void k_scan3(int* startv, const int* __restrict__ boff, int* cursor){
    int i = blockIdx.x*256 + threadIdx.x;
    if (i < N_TOTAL){ startv[i] += boff[i >> 8]; cursor[i] = 0; }
}

__global__ __launch_bounds__(256) void k_fill(const int* __restrict__ row, const int* __restrict__ col,
                                              const float* __restrict__ w, const float* __restrict__ dinv,
                                              const int* __restrict__ startv, int* cursor,
                                              int* __restrict__ csr_src, float* __restrict__ csr_norm){
    int e = blockIdx.x*256 + threadIdx.x;
    if (e < NE){
        int r = row[e], c = col[e];
        int pos  = atomicAdd(&cursor[c], 1);
        int slot = startv[c] + pos;
        csr_src[slot]  = r;
        csr_norm[slot] = dinv[r]*w[e]*dinv[c];
    }
}

// ---------------- transpose x [B][32][1516] -> xh fp16 [N][32] ----------------
__global__ __launch_bounds__(256) void k_prep1(const float* __restrict__ x, __half* __restrict__ xh){
    int idx = blockIdx.x*256 + threadIdx.x;
    if (idx >= N_TOTAL) return;
    int b = idx / NNODES, nn = idx - b*NNODES;
    const float* xp = x + (size_t)b*CIN*NNODES + nn;
    uint u[16];
    #pragma unroll
    for (int c2 = 0; c2 < 16; ++c2){
        float a0 = xp[(size_t)(2*c2)*NNODES];
        float a1 = xp[(size_t)(2*c2+1)*NNODES];
        u[c2] = f2u(a0, a1);
    }
    uint4* dst = (uint4*)(xh + (size_t)idx*CIN);
    dst[0] = make_uint4(u[0], u[1], u[2],  u[3]);
    dst[1] = make_uint4(u[4], u[5], u[6],  u[7]);
    dst[2] = make_uint4(u[8], u[9], u[10], u[11]);
    dst[3] = make_uint4(u[12],u[13],u[14], u[15]);
}

// ---------------- CSR gather on fp16 payload: agg[i] = di^2*h[i] + sum norm*h[src] ----------------
template<int F>
__global__ __launch_bounds__(256) void k_gatherH(const __half* __restrict__ h,
                                                 const float* __restrict__ dinv,
                                                 const int* __restrict__ startv,
                                                 const int* __restrict__ cnt,
                                                 const int* __restrict__ csr_src,
                                                 const float* __restrict__ csr_norm,
                                                 __half* __restrict__ agg){
    int node = blockIdx.x*(256/F) + threadIdx.x/F;
    int f    = threadIdx.x & (F-1);
    float di  = dinv[node];
    float acc = di*di*__half2float(h[(size_t)node*F + f]);
    int s0 = startv[node];
    int c  = cnt[node];
    for (int s = s0; s < s0 + c; ++s){
        int   src = csr_src[s];
        float nm  = csr_norm[s];
        acc += nm * __half2float(h[(size_t)src*F + f]);
    }
    agg[(size_t)node*F + f] = __float2half(acc);
}

// ---------------- dense GEMM: out[n][64] = agg[n][CINP](fp16) @ W[64][CINP]^T + b ----------------
template<int CINP>
__global__ __launch_bounds__(256) void k_gemmH(const __half* __restrict__ hin,
                                               const float* __restrict__ W,
                                               const float* __restrict__ bias,
                                               float* __restrict__ out){
    constexpr int SH = CINP + 4;
    constexpr int SW = 68;
    __shared__ float sh_h[64*SH];
    __shared__ float sh_w[64*SW];
    __shared__ float s_b[64];
    int t = threadIdx.x;
    int nodeBase = blockIdx.x * 64;

    if (t < 64) s_b[t] = bias[t];
    // stage W (row-major [64][CINP], fp32)
    #pragma unroll
    for (int r = 0; r < CINP/16; ++r){
        int flat = (r*256 + t)*4;
        int o = flat / CINP, k = flat - o*CINP;
        float4 v = *(const float4*)(W + flat);
        *(float4*)(&sh_w[o*SW + k]) = v;
    }
    // stage h (fp16 -> fp32 in LDS); groups of 8 halves
    constexpr int GPR = CINP/8;      // 8-half groups per row
    #pragma unroll
    for (int r = 0; r < CINP/32; ++r){
        int g = r*256 + t;
        int rowi = g / GPR, kq = (g % GPR)*8;
        uint4 u = *(const uint4*)(hin + (size_t)(nodeBase + rowi)*CINP + kq);
        float2 f0 = u2f(u.x), f1 = u2f(u.y), f2v = u2f(u.z), f3 = u2f(u.w);
        float* d = &sh_h[rowi*SH + kq];
        *(float4*)(d)   = make_float4(f0.x, f0.y, f1.x, f1.y);
        *(float4*)(d+4) = make_float4(f2v.x, f2v.y, f3.x, f3.y);
    }
    __syncthreads();

    int nl = t >> 2, q = t & 3;
    float acc[16];
    #pragma unroll
    for (int i = 0; i < 16; ++i) acc[i] = 0.f;
    const float* hrow = &sh_h[nl*SH];
    #pragma unroll
    for (int k = 0; k < CINP; k += 4){
        float4 hv = *(const float4*)(hrow + k);
        #pragma unroll
        for (int o = 0; o < 16; ++o){
            float4 wv = *(const float4*)(&sh_w[(q*16+o)*SW + k]);
            acc[o] += hv.x*wv.x + hv.y*wv.y + hv.z*wv.z + hv.w*wv.w;
        }
    }
    float* dst = out + (size_t)(nodeBase + nl)*64 + q*16;
    #pragma unroll
    for (int o = 0; o < 4; ++o)
        *(float4*)(dst + o*4) = make_float4(acc[o*4] + s_b[q*16+o*4],
                                            acc[o*4+1] + s_b[q*16+o*4+1],
                                            acc[o*4+2] + s_b[q*16+o*4+2],
                                            acc[o*4+3] + s_b[q*16+o*4+3]);
}

// ---------------- BN stats over node axis ----------------
__global__ __launch_bounds__(256) void k_bn_reduce(const float* __restrict__ x, float* gsum, float* gsq){
    int t = threadIdx.x;
    int f = t & 63, g4 = t >> 6;
    float s = 0.f, q = 0.f;
    for (int i = blockIdx.x*4 + g4; i < N_TOTAL; i += gridDim.x*4){
        float v = x[(size_t)i*64 + f];
        s += v; q += v*v;
    }
    __shared__ float sh[2][4][64];
    sh[0][g4][f] = s; sh[1][g4][f] = q;
    __syncthreads();
    if (t < 64){
        float ss = sh[0][0][t] + sh[0][1][t] + sh[0][2][t] + sh[0][3][t];
        float qq = sh[1][0][t] + sh[1][1][t] + sh[1][2][t] + sh[1][3][t];
        atomicAdd(&gsum[t], ss);
        atomicAdd(&gsq[t],  qq);
    }
}

__global__ void k_bn_final(const float* __restrict__ gsum, const float* __restrict__ gsq,
                           const float* __restrict__ g, const float* __restrict__ be,
                           float* scale, float* shift){
    int f = threadIdx.x;
    if (f < 64){
        float mean = gsum[f] / (float)N_TOTAL;
        float var  = gsq[f] / (float)N_TOTAL - mean*mean;
        float sc   = g[f] / sqrtf(var + EPS);
        scale[f] = sc;
        shift[f] = be[f] - mean*sc;
    }
}

// ---------------- fused BN+ReLU + fp16 convert: hh = relu(x*scale+shift) ----------------
__global__ __launch_bounds__(256) void k_bnrelu_h(const float* __restrict__ x,
                                                  const float* __restrict__ scale,
                                                  const float* __restrict__ shift,
                                                  __half* __restrict__ out){
    __shared__ float ssc[64], ssh[64];
    int t = threadIdx.x;
    if (t < 64){ ssc[t] = scale[t]; ssh[t] = shift[t]; }
    __syncthreads();
    int idx = blockIdx.x*256 + t;            // 8-elem groups; total N*64/8
    size_t i8 = (size_t)idx*8;
    int f = (int)(i8 & 63);
    float4 a = *(const float4*)(x + i8);
    float4 b = *(const float4*)(x + i8 + 4);
    float r0 = fmaxf(0.f, a.x*ssc[f]   + ssh[f]);
    float r1 = fmaxf(0.f, a.y*ssc[f+1] + ssh[f+1]);
    float r2 = fmaxf(0.f, a.z*ssc[f+2] + ssh[f+2]);
    float r3 = fmaxf(0.f, a.w*ssc[f+3] + ssh[f+3]);
    float r4 = fmaxf(0.f, b.x*ssc[f+4] + ssh[f+4]);
    float r5 = fmaxf(0.f, b.y*ssc[f+5] + ssh[f+5]);
    float r6 = fmaxf(0.f, b.z*ssc[f+6] + ssh[f+6]);
    float r7 = fmaxf(0.f, b.w*ssc[f+7] + ssh[f+7]);
    *(uint4*)(out + i8) = make_uint4(f2u(r0,r1), f2u(r2,r3), f2u(r4,r5), f2u(r6,r7));
}

// ---------------- FC1: C[128][128] = A(fp16)[128][97024] @ Wl1[128][97024]^T ----------------
__global__ __launch_bounds__(256) void k_fc1(const __half* __restrict__ A,
                                             const float* __restrict__ Wl1,
                                             float* __restrict__ part){
    __shared__ float sA[128*36];
    __shared__ float sW[128*36];
    int t = threadIdx.x;
    int tr = t >> 4, tc = t & 15;
    float acc[8][8] = {};
    for (int ti = 0; ti < 4; ++ti){
        int tile  = blockIdx.x*4 + ti;
        int kbase = tile*32;
        __syncthreads();     // LDS reuse across tiles
        // stage A: 128 rows x 32 halves; groups of 8 halves
        #pragma unroll
        for (int r = 0; r < 2; ++r){
            int g = r*256 + t;
            int rowi = g >> 2, kq = (g & 3)*8;
            uint4 u = *(const uint4*)(A + (size_t)rowi*FIN + kbase + kq);
            float2 f0 = u2f(u.x), f1 = u2f(u.y), f2v = u2f(u.z), f3 = u2f(u.w);
            float* d = &sA[rowi*36 + kq];
            *(float4*)(d)   = make_float4(f0.x, f0.y, f1.x, f1.y);
            *(float4*)(d+4) = make_float4(f2v.x, f2v.y, f3.x, f3.y);
        }
        // stage W: 128 rows x 32 floats
        #pragma unroll
        for (int r = 0; r < 4; ++r){
            int g = r*256 + t;
            int rowi = g >> 3, kq = (g & 7)*4;
            float4 w = *(const float4*)(Wl1 + (size_t)rowi*FIN + kbase + kq);
            *(float4*)(&sW[rowi*36 + kq]) = w;
        }
        __syncthreads();
        #pragma unroll 2
        for (int k = 0; k < 32; k += 2){
            float2 a2[8], w2[8];
            #pragma unroll
            for (int i = 0; i < 8; ++i) a2[i] = *(const float2*)(&sA[(tr+16*i)*36 + k]);
            #pragma unroll
            for (int j = 0; j < 8; ++j) w2[j] = *(const float2*)(&sW[(tc+16*j)*36 + k]);
            #pragma unroll
            for (int i = 0; i < 8; ++i)
                #pragma unroll
                for (int j = 0; j < 8; ++j)
                    acc[i][j] += a2[i].x*w2[j].x + a2[i].y*w2[j].y;
        }
    }
    float* p = part + (size_t)blockIdx.x*16384;
    #pragma unroll
    for (int i = 0; i < 8; ++i)
        #pragma unroll
        for (int j = 0; j < 8; ++j)
            p[(tr+16*i)*128 + tc+16*j] = acc[i][j];
}

__global__ __launch_bounds__(256) void k_fc1_reduce(const float* __restrict__ part,
                                                    const float* __restrict__ bl1,
                                                    float* __restrict__ C){
    int idx = blockIdx.x*256 + threadIdx.x;   // 16384
    float s = 0.f;
    for (int kc = 0; kc < 758; ++kc) s += part[(size_t)kc*16384 + idx];
    C[idx] = s + bl1[idx & 127];
}

__global__ void k_fc_stats(const float* __restrict__ C, const float* __restrict__ g,
                           const float* __restrict__ be, float* scale2, float* shift2){
    int j = threadIdx.x;
    if (j < 128){
        float s = 0.f, q = 0.f;
        for (int b = 0; b < 128; ++b){ float v = C[b*128 + j]; s += v; q += v*v; }
        float mean = s / 128.f;
        float var  = q / 128.f - mean*mean;
        float sc   = g[j] / sqrtf(var + EPS);
        scale2[j] = sc;
        shift2[j] = be[j] - mean*sc;
    }
}

__global__ __launch_bounds__(256) void k_fc2(const float* __restrict__ C, const float* __restrict__ scale2,
                                             const float* __restrict__ shift2, const float* __restrict__ Wl3,
                                             const float* __restrict__ bl3, float* __restrict__ out){
    int id = blockIdx.x*256 + threadIdx.x;
    if (id < 1280){
        int b = id / 10, c = id - b*10;
        float acc = bl3[c];
        for (int j = 0; j < 128; ++j){
            float hv = fmaxf(0.f, C[b*128 + j]*scale2[j] + shift2[j]);
            acc += hv * Wl3[c*128 + j];
        }
        out[id] = acc;
    }
}

// ---------------- launch ----------------
extern "C" void kernel_launch(void* const* d_in, const int* in_sizes, int n_in,
                              void* d_out, int out_size, void* d_ws, size_t ws_size,
                              hipStream_t stream){
    const float* x   = (const float*)d_in[0];
    const int*   ei  = (const int*)  d_in[1];
    const float* ew  = (const float*)d_in[2];
    const float* W1  = (const float*)d_in[3];
    const float* b1  = (const float*)d_in[4];
    const float* W2  = (const float*)d_in[5];
    const float* b2  = (const float*)d_in[6];
    const float* W3  = (const float*)d_in[7];
    const float* b3  = (const float*)d_in[8];
    const float* g1  = (const float*)d_in[9];
    const float* be1 = (const float*)d_in[10];
    const float* g2  = (const float*)d_in[11];
    const float* be2 = (const float*)d_in[12];
    const float* g3  = (const float*)d_in[13];
    const float* be3 = (const float*)d_in[14];
    const float* Wl1 = (const float*)d_in[15];
    const float* bl1 = (const float*)d_in[16];
    const float* gl1 = (const float*)d_in[17];
    const float* bel1= (const float*)d_in[18];
    const float* Wl3 = (const float*)d_in[19];
    const float* bl3 = (const float*)d_in[20];
    const int* row = ei;
    const int* col = ei + NE;

    char* p = (char*)d_ws;
    auto alloc = [&](size_t bytes)->char*{
        char* r = p; p += (bytes + 255) & ~(size_t)255; return r;
    };
    float*  bufA     = (float*)alloc((size_t)N_TOTAL*64*4);   // conv out fp32
    float*  bufB     = (float*)alloc((size_t)758*16384*4);    // FC1 partials / layer-scratch
    __half* hh       = (__half*)alloc((size_t)N_TOTAL*64*2);  // post-BN-relu fp16
    __half* xh       = (__half*)alloc((size_t)N_TOTAL*32*2);  // transposed input fp16
    float*  deg      = (float*)alloc(N_TOTAL*4);
    float*  dinv     = (float*)alloc(N_TOTAL*4);
    int*    cnt      = (int*)  alloc(N_TOTAL*4);
    int*    startv   = (int*)  alloc(N_TOTAL*4);
    int*    cursor   = (int*)  alloc(N_TOTAL*4);
    int*    bs       = (int*)  alloc(4096);
    int*    boff     = (int*)  alloc(4096);
    int*    csr_src  = (int*)  alloc((size_t)NE*4);
    float*  csr_norm = (float*)alloc((size_t)NE*4);
    float*  gsum     = (float*)alloc(256);
    float*  gsq      = (float*)alloc(256);
    float*  scale1   = (float*)alloc(256);
    float*  shift1   = (float*)alloc(256);
    float*  scale2l  = (float*)alloc(256);
    float*  shift2l  = (float*)alloc(256);
    float*  scale3   = (float*)alloc(256);
    float*  shift3   = (float*)alloc(256);
    float*  Cfc      = (float*)alloc(65536);
    float*  scaleF   = (float*)alloc(512);
    float*  shiftF   = (float*)alloc(512);
    // aggregated fp16 features live in bufB's space (dead until FC1)
    __half* agg32    = (__half*)bufB;                          // [N][32] fp16
    __half* agg64    = (__half*)bufB;                          // [N][64] fp16

    const int NB_N = 758;     // N_TOTAL/256
    const int NB_E = 12128;   // NE/256
    k_init <<<NB_N, 256, 0, stream>>>(deg, cnt);
    k_deg  <<<NB_E, 256, 0, stream>>>(col, ew, deg, cnt);
    k_dinv <<<NB_N, 256, 0, stream>>>(deg, dinv);
    k_scan1<<<NB_N, 256, 0, stream>>>(cnt, startv, bs);
    k_scan2<<<1,    256, 0, stream>>>(bs, boff);
    k_scan3<<<NB_N, 256, 0, stream>>>(startv, boff, cursor);
    k_fill <<<NB_E, 256, 0, stream>>>(row, col, ew, dinv, startv, cursor, csr_src, csr_norm);
    k_prep1<<<NB_N, 256, 0, stream>>>(x, xh);

    // ---- layer 1 (aggregate-first in 32-dim fp16) ----
    k_gatherH<32><<<24256, 256, 0, stream>>>(xh, dinv, startv, cnt, csr_src, csr_norm, agg32);
    k_gemmH<32>  <<<3032,  256, 0, stream>>>(agg32, W1, b1, bufA);
    hipMemsetAsync(gsum, 0, 512, stream);
    k_bn_reduce  <<<1024,  256, 0, stream>>>(bufA, gsum, gsq);
    k_bn_final   <<<1, 64, 0, stream>>>(gsum, gsq, g1, be1, scale1, shift1);
    // ---- layer 2 ----
    k_bnrelu_h   <<<6064,  256, 0, stream>>>(bufA, scale1, shift1, hh);
    k_gatherH<64><<<48512, 256, 0, stream>>>(hh, dinv, startv, cnt, csr_src, csr_norm, agg64);
    k_gemmH<64>  <<<3032,  256, 0, stream>>>(agg64, W2, b2, bufA);
    hipMemsetAsync(gsum, 0, 512, stream);
    k_bn_reduce  <<<1024,  256, 0, stream>>>(bufA, gsum, gsq);
    k_bn_final   <<<1, 64, 0, stream>>>(gsum, gsq, g2, be2, scale2l, shift2l);
    // ---- layer 3 ----
    k_bnrelu_h   <<<6064,  256, 0, stream>>>(bufA, scale2l, shift2l, hh);
    k_gatherH<64><<<48512, 256, 0, stream>>>(hh, dinv, startv, cnt, csr_src, csr_norm, agg64);
    k_gemmH<64>  <<<3032,  256, 0, stream>>>(agg64, W3, b3, bufA);
    hipMemsetAsync(gsum, 0, 512, stream);
    k_bn_reduce  <<<1024,  256, 0, stream>>>(bufA, gsum, gsq);
    k_bn_final   <<<1, 64, 0, stream>>>(gsum, gsq, g3, be3, scale3, shift3);

    // ---- FC head (hh = post-BN3-relu fp16 is FC1's A matrix; bufB = partials) ----
    k_bnrelu_h  <<<6064, 256, 0, stream>>>(bufA, scale3, shift3, hh);
    k_fc1       <<<758,  256, 0, stream>>>(hh, Wl1, bufB);
    k_fc1_reduce<<<64,   256, 0, stream>>>(bufB, bl1, Cfc);
    k_fc_stats  <<<1,    128, 0, stream>>>(Cfc, gl1, bel1, scaleF, shiftF);
    k_fc2       <<<5,    256, 0, stream>>>(Cfc, scaleF, shiftF, Wl3, bl3, (float*)d_out);
}

// Round 4
// 1269.688 us; speedup vs baseline: 1.6784x; 1.3812x over previous
//
#include <hip/hip_runtime.h>
#include <hip/hip_fp16.h>

#define N_TOTAL 194048
#define NE      3104768
#define HID     64
#define NNODES  1516
#define CIN     32
#define FIN     97024
#define EPS     1e-5f

__device__ inline uint f2u(float a, float b){
    __half2 h = __floats2half2_rn(a, b);
    return *(const uint*)&h;
}
__device__ inline float2 u2f(uint u){
    __half2 h = *(const __half2*)&u;
    return __half22float2(h);
}

// ---------------- setup: degree, dinv, CSR build ----------------
__global__ __launch_bounds__(256) void k_init(float* deg, int* cnt){
    int i = blockIdx.x*256 + threadIdx.x;
    if (i < N_TOTAL){ deg[i] = 1.0f; cnt[i] = 0; }   // self-loop weight 1
}

__global__ __launch_bounds__(256) void k_deg(const int* __restrict__ col,
                                             const float* __restrict__ w,
                                             float* deg, int* cnt){
    int e = blockIdx.x*256 + threadIdx.x;
    if (e < NE){
        int c = col[e];
        atomicAdd(&deg[c], w[e]);
        atomicAdd(&cnt[c], 1);
    }
}

__global__ __launch_bounds__(256) void k_dinv(const float* __restrict__ deg, float* dinv){
    int i = blockIdx.x*256 + threadIdx.x;
    if (i < N_TOTAL){
        float d = deg[i];
        dinv[i] = d > 0.f ? 1.0f/sqrtf(d) : 0.f;
    }
}

__global__ __launch_bounds__(256) void k_scan1(const int* __restrict__ cnt, int* startv, int* bs){
    __shared__ int s[256];
    int t = threadIdx.x;
    int i = blockIdx.x*256 + t;
    int v = (i < N_TOTAL) ? cnt[i] : 0;
    s[t] = v; __syncthreads();
    for (int off = 1; off < 256; off <<= 1){
        int u = (t >= off) ? s[t-off] : 0;
        __syncthreads();
        s[t] += u;
        __syncthreads();
    }
    if (i < N_TOTAL) startv[i] = s[t] - v;
    if (t == 255) bs[blockIdx.x] = s[255];
}

__global__ __launch_bounds__(256) void k_scan2(const int* __restrict__ bs, int* boff){
    __shared__ int s[256];
    int t = threadIdx.x;
    int i0 = t*3;
    int a = (i0   < 758) ? bs[i0]   : 0;
    int b = (i0+1 < 758) ? bs[i0+1] : 0;
    int c = (i0+2 < 758) ? bs[i0+2] : 0;
    int tot = a+b+c;
    s[t] = tot; __syncthreads();
    for (int off = 1; off < 256; off <<= 1){
        int u = (t >= off) ? s[t-off] : 0;
        __syncthreads();
        s[t] += u;
        __syncthreads();
    }
    int ex = s[t] - tot;
    if (i0   < 758) boff[i0]   = ex;
    if (i0+1 < 758) boff[i0+1] = ex + a;
    if (i0+2 < 758) boff[i0+2] = ex + a + b;
}

__global__ __launch_bounds__(256) void k_scan3(int* startv, const int* __restrict__ boff, int* cursor){
    int i = blockIdx.x*256 + threadIdx.x;
    if (i < N_TOTAL){ startv[i] += boff[i >> 8]; cursor[i] = 0; }
}

__global__ __launch_bounds__(256) void k_fill(const int* __restrict__ row, const int* __restrict__ col,
                                              const float* __restrict__ w, const float* __restrict__ dinv,
                                              const int* __restrict__ startv, int* cursor,
                                              int* __restrict__ csr_src, float* __restrict__ csr_norm){
    int e = blockIdx.x*256 + threadIdx.x;
    if (e < NE){
        int r = row[e], c = col[e];
        int pos  = atomicAdd(&cursor[c], 1);
        int slot = startv[c] + pos;
        csr_src[slot]  = r;
        csr_norm[slot] = dinv[r]*w[e]*dinv[c];
    }
}

// ---------------- transpose x [B][32][1516] -> xh fp16 [N][32] ----------------
__global__ __launch_bounds__(256) void k_prep1(const float* __restrict__ x, __half* __restrict__ xh){
    int idx = blockIdx.x*256 + threadIdx.x;
    if (idx >= N_TOTAL) return;
    int b = idx / NNODES, nn = idx - b*NNODES;
    const float* xp = x + (size_t)b*CIN*NNODES + nn;
    uint u[16];
    #pragma unroll
    for (int c2 = 0; c2 < 16; ++c2){
        float a0 = xp[(size_t)(2*c2)*NNODES];
        float a1 = xp[(size_t)(2*c2+1)*NNODES];
        u[c2] = f2u(a0, a1);
    }
    uint4* dst = (uint4*)(xh + (size_t)idx*CIN);
    dst[0] = make_uint4(u[0], u[1], u[2],  u[3]);
    dst[1] = make_uint4(u[4], u[5], u[6],  u[7]);
    dst[2] = make_uint4(u[8], u[9], u[10], u[11]);
    dst[3] = make_uint4(u[12],u[13],u[14], u[15]);
}

// ---------------- CSR gather, MLP-optimized ----------------
// F/4 lanes per node, 4 fp16 feats per lane; edge loop unrolled 4x
// -> up to 16 outstanding random loads per wave (vs 1 in the serial version).
template<int F>
__global__ __launch_bounds__(256) void k_gatherH(const __half* __restrict__ h,
                                                 const float* __restrict__ dinv,
                                                 const int* __restrict__ startv,
                                                 const int* __restrict__ cnt,
                                                 const int* __restrict__ csr_src,
                                                 const float* __restrict__ csr_norm,
                                                 __half* __restrict__ agg){
    constexpr int LPN = F/4;                       // lanes per node
    int node = blockIdx.x*(256/LPN) + threadIdx.x/LPN;
    int q    = (threadIdx.x % LPN)*4;              // first half index
    const __half* hq = h + q;
    float di = dinv[node];
    float w0 = di*di;
    uint2 us = *(const uint2*)(hq + (size_t)node*F);
    float2 sl = u2f(us.x), sh2 = u2f(us.y);
    float a0 = w0*sl.x, a1 = w0*sl.y, a2 = w0*sh2.x, a3 = w0*sh2.y;

    int s = startv[node];
    int e = s + cnt[node];
    for (; s + 4 <= e; s += 4){
        int   i0 = csr_src[s],   i1 = csr_src[s+1], i2 = csr_src[s+2], i3 = csr_src[s+3];
        float n0 = csr_norm[s],  n1 = csr_norm[s+1], n2 = csr_norm[s+2], n3 = csr_norm[s+3];
        uint2 u0 = *(const uint2*)(hq + (size_t)i0*F);
        uint2 u1 = *(const uint2*)(hq + (size_t)i1*F);
        uint2 u2v= *(const uint2*)(hq + (size_t)i2*F);
        uint2 u3 = *(const uint2*)(hq + (size_t)i3*F);
        float2 p0 = u2f(u0.x), p1 = u2f(u0.y);
        a0 += n0*p0.x; a1 += n0*p0.y; a2 += n0*p1.x; a3 += n0*p1.y;
        float2 q0 = u2f(u1.x), q1 = u2f(u1.y);
        a0 += n1*q0.x; a1 += n1*q0.y; a2 += n1*q1.x; a3 += n1*q1.y;
        float2 r0 = u2f(u2v.x), r1 = u2f(u2v.y);
        a0 += n2*r0.x; a1 += n2*r0.y; a2 += n2*r1.x; a3 += n2*r1.y;
        float2 t0 = u2f(u3.x), t1 = u2f(u3.y);
        a0 += n3*t0.x; a1 += n3*t0.y; a2 += n3*t1.x; a3 += n3*t1.y;
    }
    for (; s < e; ++s){
        int   i0 = csr_src[s];
        float n0 = csr_norm[s];
        uint2 u0 = *(const uint2*)(hq + (size_t)i0*F);
        float2 p0 = u2f(u0.x), p1 = u2f(u0.y);
        a0 += n0*p0.x; a1 += n0*p0.y; a2 += n0*p1.x; a3 += n0*p1.y;
    }
    *(uint2*)(agg + (size_t)node*F + q) = make_uint2(f2u(a0,a1), f2u(a2,a3));
}

// ---------------- dense GEMM: out[n][64] = agg[n][CINP](fp16) @ W[64][CINP]^T + b ----------------
template<int CINP>
__global__ __launch_bounds__(256) void k_gemmH(const __half* __restrict__ hin,
                                               const float* __restrict__ W,
                                               const float* __restrict__ bias,
                                               float* __restrict__ out){
    constexpr int SH = CINP + 4;
    constexpr int SW = 68;
    __shared__ float sh_h[64*SH];
    __shared__ float sh_w[64*SW];
    __shared__ float s_b[64];
    int t = threadIdx.x;
    int nodeBase = blockIdx.x * 64;

    if (t < 64) s_b[t] = bias[t];
    #pragma unroll
    for (int r = 0; r < CINP/16; ++r){
        int flat = (r*256 + t)*4;
        int o = flat / CINP, k = flat - o*CINP;
        float4 v = *(const float4*)(W + flat);
        *(float4*)(&sh_w[o*SW + k]) = v;
    }
    constexpr int GPR = CINP/8;
    #pragma unroll
    for (int r = 0; r < CINP/32; ++r){
        int g = r*256 + t;
        int rowi = g / GPR, kq = (g % GPR)*8;
        uint4 u = *(const uint4*)(hin + (size_t)(nodeBase + rowi)*CINP + kq);
        float2 f0 = u2f(u.x), f1 = u2f(u.y), f2v = u2f(u.z), f3 = u2f(u.w);
        float* d = &sh_h[rowi*SH + kq];
        *(float4*)(d)   = make_float4(f0.x, f0.y, f1.x, f1.y);
        *(float4*)(d+4) = make_float4(f2v.x, f2v.y, f3.x, f3.y);
    }
    __syncthreads();

    int nl = t >> 2, q = t & 3;
    float acc[16];
    #pragma unroll
    for (int i = 0; i < 16; ++i) acc[i] = 0.f;
    const float* hrow = &sh_h[nl*SH];
    #pragma unroll
    for (int k = 0; k < CINP; k += 4){
        float4 hv = *(const float4*)(hrow + k);
        #pragma unroll
        for (int o = 0; o < 16; ++o){
            float4 wv = *(const float4*)(&sh_w[(q*16+o)*SW + k]);
            acc[o] += hv.x*wv.x + hv.y*wv.y + hv.z*wv.z + hv.w*wv.w;
        }
    }
    float* dst = out + (size_t)(nodeBase + nl)*64 + q*16;
    #pragma unroll
    for (int o = 0; o < 4; ++o)
        *(float4*)(dst + o*4) = make_float4(acc[o*4] + s_b[q*16+o*4],
                                            acc[o*4+1] + s_b[q*16+o*4+1],
                                            acc[o*4+2] + s_b[q*16+o*4+2],
                                            acc[o*4+3] + s_b[q*16+o*4+3]);
}

// ---------------- BN stats over node axis ----------------
__global__ __launch_bounds__(256) void k_bn_reduce(const float* __restrict__ x, float* gsum, float* gsq){
    int t = threadIdx.x;
    int f = t & 63, g4 = t >> 6;
    float s = 0.f, q = 0.f;
    for (int i = blockIdx.x*4 + g4; i < N_TOTAL; i += gridDim.x*4){
        float v = x[(size_t)i*64 + f];
        s += v; q += v*v;
    }
    __shared__ float sh[2][4][64];
    sh[0][g4][f] = s; sh[1][g4][f] = q;
    __syncthreads();
    if (t < 64){
        float ss = sh[0][0][t] + sh[0][1][t] + sh[0][2][t] + sh[0][3][t];
        float qq = sh[1][0][t] + sh[1][1][t] + sh[1][2][t] + sh[1][3][t];
        atomicAdd(&gsum[t], ss);
        atomicAdd(&gsq[t],  qq);
    }
}

__global__ void k_bn_final(const float* __restrict__ gsum, const float* __restrict__ gsq,
                           const float* __restrict__ g, const float* __restrict__ be,
                           float* scale, float* shift){
    int f = threadIdx.x;
    if (f < 64){
        float mean = gsum[f] / (float)N_TOTAL;
        float var  = gsq[f] / (float)N_TOTAL - mean*mean;
        float sc   = g[f] / sqrtf(var + EPS);
        scale[f] = sc;
        shift[f] = be[f] - mean*sc;
    }
}

// ---------------- fused BN+ReLU + fp16 convert ----------------
__global__ __launch_bounds__(256) void k_bnrelu_h(const float* __restrict__ x,
                                                  const float* __restrict__ scale,
                                                  const float* __restrict__ shift,
                                                  __half* __restrict__ out){
    __shared__ float ssc[64], ssh[64];
    int t = threadIdx.x;
    if (t < 64){ ssc[t] = scale[t]; ssh[t] = shift[t]; }
    __syncthreads();
    int idx = blockIdx.x*256 + t;
    size_t i8 = (size_t)idx*8;
    int f = (int)(i8 & 63);
    float4 a = *(const float4*)(x + i8);
    float4 b = *(const float4*)(x + i8 + 4);
    float r0 = fmaxf(0.f, a.x*ssc[f]   + ssh[f]);
    float r1 = fmaxf(0.f, a.y*ssc[f+1] + ssh[f+1]);
    float r2 = fmaxf(0.f, a.z*ssc[f+2] + ssh[f+2]);
    float r3 = fmaxf(0.f, a.w*ssc[f+3] + ssh[f+3]);
    float r4 = fmaxf(0.f, b.x*ssc[f+4] + ssh[f+4]);
    float r5 = fmaxf(0.f, b.y*ssc[f+5] + ssh[f+5]);
    float r6 = fmaxf(0.f, b.z*ssc[f+6] + ssh[f+6]);
    float r7 = fmaxf(0.f, b.w*ssc[f+7] + ssh[f+7]);
    *(uint4*)(out + i8) = make_uint4(f2u(r0,r1), f2u(r2,r3), f2u(r4,r5), f2u(r6,r7));
}

// ---------------- FC1: C[128][128] = A(fp16)[128][97024] @ Wl1[128][97024]^T ----------------
__global__ __launch_bounds__(256) void k_fc1(const __half* __restrict__ A,
                                             const float* __restrict__ Wl1,
                                             float* __restrict__ part){
    __shared__ float sA[128*36];
    __shared__ float sW[128*36];
    int t = threadIdx.x;
    int tr = t >> 4, tc = t & 15;
    float acc[8][8] = {};
    for (int ti = 0; ti < 4; ++ti){
        int tile  = blockIdx.x*4 + ti;
        int kbase = tile*32;
        __syncthreads();
        #pragma unroll
        for (int r = 0; r < 2; ++r){
            int g = r*256 + t;
            int rowi = g >> 2, kq = (g & 3)*8;
            uint4 u = *(const uint4*)(A + (size_t)rowi*FIN + kbase + kq);
            float2 f0 = u2f(u.x), f1 = u2f(u.y), f2v = u2f(u.z), f3 = u2f(u.w);
            float* d = &sA[rowi*36 + kq];
            *(float4*)(d)   = make_float4(f0.x, f0.y, f1.x, f1.y);
            *(float4*)(d+4) = make_float4(f2v.x, f2v.y, f3.x, f3.y);
        }
        #pragma unroll
        for (int r = 0; r < 4; ++r){
            int g = r*256 + t;
            int rowi = g >> 3, kq = (g & 7)*4;
            float4 w = *(const float4*)(Wl1 + (size_t)rowi*FIN + kbase + kq);
            *(float4*)(&sW[rowi*36 + kq]) = w;
        }
        __syncthreads();
        #pragma unroll 2
        for (int k = 0; k < 32; k += 2){
            float2 a2[8], w2[8];
            #pragma unroll
            for (int i = 0; i < 8; ++i) a2[i] = *(const float2*)(&sA[(tr+16*i)*36 + k]);
            #pragma unroll
            for (int j = 0; j < 8; ++j) w2[j] = *(const float2*)(&sW[(tc+16*j)*36 + k]);
            #pragma unroll
            for (int i = 0; i < 8; ++i)
                #pragma unroll
                for (int j = 0; j < 8; ++j)
                    acc[i][j] += a2[i].x*w2[j].x + a2[i].y*w2[j].y;
        }
    }
    float* p = part + (size_t)blockIdx.x*16384;
    #pragma unroll
    for (int i = 0; i < 8; ++i)
        #pragma unroll
        for (int j = 0; j < 8; ++j)
            p[(tr+16*i)*128 + tc+16*j] = acc[i][j];
}

__global__ __launch_bounds__(256) void k_fc1_reduce(const float* __restrict__ part,
                                                    const float* __restrict__ bl1,
                                                    float* __restrict__ C){
    int idx = blockIdx.x*256 + threadIdx.x;   // 16384
    float s = 0.f;
    for (int kc = 0; kc < 758; ++kc) s += part[(size_t)kc*16384 + idx];
    C[idx] = s + bl1[idx & 127];
}

__global__ void k_fc_stats(const float* __restrict__ C, const float* __restrict__ g,
                           const float* __restrict__ be, float* scale2, float* shift2){
    int j = threadIdx.x;
    if (j < 128){
        float s = 0.f, q = 0.f;
        for (int b = 0; b < 128; ++b){ float v = C[b*128 + j]; s += v; q += v*v; }
        float mean = s / 128.f;
        float var  = q / 128.f - mean*mean;
        float sc   = g[j] / sqrtf(var + EPS);
        scale2[j] = sc;
        shift2[j] = be[j] - mean*sc;
    }
}

__global__ __launch_bounds__(256) void k_fc2(const float* __restrict__ C, const float* __restrict__ scale2,
                                             const float* __restrict__ shift2, const float* __restrict__ Wl3,
                                             const float* __restrict__ bl3, float* __restrict__ out){
    int id = blockIdx.x*256 + threadIdx.x;
    if (id < 1280){
        int b = id / 10, c = id - b*10;
        float acc = bl3[c];
        for (int j = 0; j < 128; ++j){
            float hv = fmaxf(0.f, C[b*128 + j]*scale2[j] + shift2[j]);
            acc += hv * Wl3[c*128 + j];
        }
        out[id] = acc;
    }
}

// ---------------- launch ----------------
extern "C" void kernel_launch(void* const* d_in, const int* in_sizes, int n_in,
                              void* d_out, int out_size, void* d_ws, size_t ws_size,
                              hipStream_t stream){
    const float* x   = (const float*)d_in[0];
    const int*   ei  = (const int*)  d_in[1];
    const float* ew  = (const float*)d_in[2];
    const float* W1  = (const float*)d_in[3];
    const float* b1  = (const float*)d_in[4];
    const float* W2  = (const float*)d_in[5];
    const float* b2  = (const float*)d_in[6];
    const float* W3  = (const float*)d_in[7];
    const float* b3  = (const float*)d_in[8];
    const float* g1  = (const float*)d_in[9];
    const float* be1 = (const float*)d_in[10];
    const float* g2  = (const float*)d_in[11];
    const float* be2 = (const float*)d_in[12];
    const float* g3  = (const float*)d_in[13];
    const float* be3 = (const float*)d_in[14];
    const float* Wl1 = (const float*)d_in[15];
    const float* bl1 = (const float*)d_in[16];
    const float* gl1 = (const float*)d_in[17];
    const float* bel1= (const float*)d_in[18];
    const float* Wl3 = (const float*)d_in[19];
    const float* bl3 = (const float*)d_in[20];
    const int* row = ei;
    const int* col = ei + NE;

    char* p = (char*)d_ws;
    auto alloc = [&](size_t bytes)->char*{
        char* r = p; p += (bytes + 255) & ~(size_t)255; return r;
    };
    float*  bufA     = (float*)alloc((size_t)N_TOTAL*64*4);
    float*  bufB     = (float*)alloc((size_t)758*16384*4);
    __half* hh       = (__half*)alloc((size_t)N_TOTAL*64*2);
    __half* xh       = (__half*)alloc((size_t)N_TOTAL*32*2);
    float*  deg      = (float*)alloc(N_TOTAL*4);
    float*  dinv     = (float*)alloc(N_TOTAL*4);
    int*    cnt      = (int*)  alloc(N_TOTAL*4);
    int*    startv   = (int*)  alloc(N_TOTAL*4);
    int*    cursor   = (int*)  alloc(N_TOTAL*4);
    int*    bs       = (int*)  alloc(4096);
    int*    boff     = (int*)  alloc(4096);
    int*    csr_src  = (int*)  alloc((size_t)NE*4);
    float*  csr_norm = (float*)alloc((size_t)NE*4);
    float*  gsum     = (float*)alloc(256);
    float*  gsq      = (float*)alloc(256);
    float*  scale1   = (float*)alloc(256);
    float*  shift1   = (float*)alloc(256);
    float*  scale2l  = (float*)alloc(256);
    float*  shift2l  = (float*)alloc(256);
    float*  scale3   = (float*)alloc(256);
    float*  shift3   = (float*)alloc(256);
    float*  Cfc      = (float*)alloc(65536);
    float*  scaleF   = (float*)alloc(512);
    float*  shiftF   = (float*)alloc(512);
    __half* agg32    = (__half*)bufB;
    __half* agg64    = (__half*)bufB;

    const int NB_N = 758;
    const int NB_E = 12128;
    k_init <<<NB_N, 256, 0, stream>>>(deg, cnt);
    k_deg  <<<NB_E, 256, 0, stream>>>(col, ew, deg, cnt);
    k_dinv <<<NB_N, 256, 0, stream>>>(deg, dinv);
    k_scan1<<<NB_N, 256, 0, stream>>>(cnt, startv, bs);
    k_scan2<<<1,    256, 0, stream>>>(bs, boff);
    k_scan3<<<NB_N, 256, 0, stream>>>(startv, boff, cursor);
    k_fill <<<NB_E, 256, 0, stream>>>(row, col, ew, dinv, startv, cursor, csr_src, csr_norm);
    k_prep1<<<NB_N, 256, 0, stream>>>(x, xh);

    // ---- layer 1 (aggregate-first, 32-dim fp16; 8 lanes/node) ----
    k_gatherH<32><<<6064,  256, 0, stream>>>(xh, dinv, startv, cnt, csr_src, csr_norm, agg32);
    k_gemmH<32>  <<<3032,  256, 0, stream>>>(agg32, W1, b1, bufA);
    hipMemsetAsync(gsum, 0, 512, stream);
    k_bn_reduce  <<<1024,  256, 0, stream>>>(bufA, gsum, gsq);
    k_bn_final   <<<1, 64, 0, stream>>>(gsum, gsq, g1, be1, scale1, shift1);
    // ---- layer 2 (16 lanes/node) ----
    k_bnrelu_h   <<<6064,  256, 0, stream>>>(bufA, scale1, shift1, hh);
    k_gatherH<64><<<12128, 256, 0, stream>>>(hh, dinv, startv, cnt, csr_src, csr_norm, agg64);
    k_gemmH<64>  <<<3032,  256, 0, stream>>>(agg64, W2, b2, bufA);
    hipMemsetAsync(gsum, 0, 512, stream);
    k_bn_reduce  <<<1024,  256, 0, stream>>>(bufA, gsum, gsq);
    k_bn_final   <<<1, 64, 0, stream>>>(gsum, gsq, g2, be2, scale2l, shift2l);
    // ---- layer 3 ----
    k_bnrelu_h   <<<6064,  256, 0, stream>>>(bufA, scale2l, shift2l, hh);
    k_gatherH<64><<<12128, 256, 0, stream>>>(hh, dinv, startv, cnt, csr_src, csr_norm, agg64);
    k_gemmH<64>  <<<3032,  256, 0, stream>>>(agg64, W3, b3, bufA);
    hipMemsetAsync(gsum, 0, 512, stream);
    k_bn_reduce  <<<1024,  256, 0, stream>>>(bufA, gsum, gsq);
    k_bn_final   <<<1, 64, 0, stream>>>(gsum, gsq, g3, be3, scale3, shift3);

    // ---- FC head ----
    k_bnrelu_h  <<<6064, 256, 0, stream>>>(bufA, scale3, shift3, hh);
    k_fc1       <<<758,  256, 0, stream>>>(hh, Wl1, bufB);
    k_fc1_reduce<<<64,   256, 0, stream>>>(bufB, bl1, Cfc);
    k_fc_stats  <<<1,    128, 0, stream>>>(Cfc, gl1, bel1, scaleF, shiftF);
    k_fc2       <<<5,    256, 0, stream>>>(Cfc, scaleF, shiftF, Wl3, bl3, (float*)d_out);
}

// Round 5
// 1034.995 us; speedup vs baseline: 2.0590x; 1.2268x over previous
//
#include <hip/hip_runtime.h>
#include <hip/hip_fp16.h>

#define N_TOTAL 194048
#define NE      3104768
#define HID     64
#define NNODES  1516
#define CIN     32
#define FIN     97024
#define EPS     1e-5f

__device__ inline uint f2u(float a, float b){
    __half2 h = __floats2half2_rn(a, b);
    return *(const uint*)&h;
}
__device__ inline float2 u2f(uint u){
    __half2 h = *(const __half2*)&u;
    return __half22float2(h);
}

// ---------------- CSR build: 1 atomic per edge ----------------
// pos[e] = rank of edge e among edges with same dest (atomic return)
__global__ __launch_bounds__(256) void k_cnt(const int* __restrict__ col,
                                             int* cnt, int* __restrict__ pos){
    int e0 = (blockIdx.x*256 + threadIdx.x)*4;
    int4 c = *(const int4*)(col + e0);
    int p0 = atomicAdd(&cnt[c.x], 1);
    int p1 = atomicAdd(&cnt[c.y], 1);
    int p2 = atomicAdd(&cnt[c.z], 1);
    int p3 = atomicAdd(&cnt[c.w], 1);
    *(int4*)(pos + e0) = make_int4(p0, p1, p2, p3);
}

__global__ __launch_bounds__(256) void k_scan1(const int* __restrict__ cnt, int* startv, int* bs){
    __shared__ int s[256];
    int t = threadIdx.x;
    int i = blockIdx.x*256 + t;
    int v = (i < N_TOTAL) ? cnt[i] : 0;
    s[t] = v; __syncthreads();
    for (int off = 1; off < 256; off <<= 1){
        int u = (t >= off) ? s[t-off] : 0;
        __syncthreads();
        s[t] += u;
        __syncthreads();
    }
    if (i < N_TOTAL) startv[i] = s[t] - v;
    if (t == 255) bs[blockIdx.x] = s[255];
}

__global__ __launch_bounds__(256) void k_scan2(const int* __restrict__ bs, int* boff){
    __shared__ int s[256];
    int t = threadIdx.x;
    int i0 = t*3;
    int a = (i0   < 758) ? bs[i0]   : 0;
    int b = (i0+1 < 758) ? bs[i0+1] : 0;
    int c = (i0+2 < 758) ? bs[i0+2] : 0;
    int tot = a+b+c;
    s[t] = tot; __syncthreads();
    for (int off = 1; off < 256; off <<= 1){
        int u = (t >= off) ? s[t-off] : 0;
        __syncthreads();
        s[t] += u;
        __syncthreads();
    }
    int ex = s[t] - tot;
    if (i0   < 758) boff[i0]   = ex;
    if (i0+1 < 758) boff[i0+1] = ex + a;
    if (i0+2 < 758) boff[i0+2] = ex + a + b;
}

__global__ __launch_bounds__(256) void k_scan3(int* startv, const int* __restrict__ boff){
    int i = blockIdx.x*256 + threadIdx.x;
    if (i < N_TOTAL) startv[i] += boff[i >> 8];
}

// scatter (src, w) pairs into CSR slots — no atomics
__global__ __launch_bounds__(256) void k_scatter(const int* __restrict__ row, const int* __restrict__ col,
                                                 const float* __restrict__ w, const int* __restrict__ pos,
                                                 const int* __restrict__ startv, int2* __restrict__ pairs){
    int e0 = (blockIdx.x*256 + threadIdx.x)*4;
    int4   r = *(const int4*)  (row + e0);
    int4   c = *(const int4*)  (col + e0);
    float4 v = *(const float4*)(w   + e0);
    int4   p = *(const int4*)  (pos + e0);
    int s0 = startv[c.x] + p.x;
    int s1 = startv[c.y] + p.y;
    int s2 = startv[c.z] + p.z;
    int s3 = startv[c.w] + p.w;
    pairs[s0] = make_int2(r.x, __float_as_int(v.x));
    pairs[s1] = make_int2(r.y, __float_as_int(v.y));
    pairs[s2] = make_int2(r.z, __float_as_int(v.z));
    pairs[s3] = make_int2(r.w, __float_as_int(v.w));
}

// deg = 1 + segment-sum of raw w; dinv = deg^-1/2  (atomic-free)
__global__ __launch_bounds__(256) void k_degdinv(const int2* __restrict__ pairs,
                                                 const int* __restrict__ startv,
                                                 const int* __restrict__ cnt,
                                                 float* __restrict__ dinv){
    int i = blockIdx.x*256 + threadIdx.x;
    if (i < N_TOTAL){
        int s0 = startv[i], c = cnt[i];
        float d = 1.0f;
        for (int s = s0; s < s0 + c; ++s) d += __int_as_float(pairs[s].y);
        dinv[i] = 1.0f/sqrtf(d);
    }
}

// fold dinv[src] into pair weight: pair.w = dinv[src]*w  (coalesced; random dinv read is L2-resident)
__global__ __launch_bounds__(256) void k_norm(int2* __restrict__ pairs, const float* __restrict__ dinv){
    int s0 = (blockIdx.x*256 + threadIdx.x)*4;
    int4 a = *(const int4*)(pairs + s0);       // pairs[s0], pairs[s0+1]
    int4 b = *(const int4*)(pairs + s0 + 2);   // pairs[s0+2], pairs[s0+3]
    float d0 = dinv[a.x], d1 = dinv[a.z], d2 = dinv[b.x], d3 = dinv[b.z];
    a.y = __float_as_int(__int_as_float(a.y) * d0);
    a.w = __float_as_int(__int_as_float(a.w) * d1);
    b.y = __float_as_int(__int_as_float(b.y) * d2);
    b.w = __float_as_int(__int_as_float(b.w) * d3);
    *(int4*)(pairs + s0)     = a;
    *(int4*)(pairs + s0 + 2) = b;
}

// ---------------- transpose x [B][32][1516] -> xh fp16 [N][32] ----------------
__global__ __launch_bounds__(256) void k_prep1(const float* __restrict__ x, __half* __restrict__ xh){
    int idx = blockIdx.x*256 + threadIdx.x;
    if (idx >= N_TOTAL) return;
    int b = idx / NNODES, nn = idx - b*NNODES;
    const float* xp = x + (size_t)b*CIN*NNODES + nn;
    uint u[16];
    #pragma unroll
    for (int c2 = 0; c2 < 16; ++c2){
        float a0 = xp[(size_t)(2*c2)*NNODES];
        float a1 = xp[(size_t)(2*c2+1)*NNODES];
        u[c2] = f2u(a0, a1);
    }
    uint4* dst = (uint4*)(xh + (size_t)idx*CIN);
    dst[0] = make_uint4(u[0], u[1], u[2],  u[3]);
    dst[1] = make_uint4(u[4], u[5], u[6],  u[7]);
    dst[2] = make_uint4(u[8], u[9], u[10], u[11]);
    dst[3] = make_uint4(u[12],u[13],u[14], u[15]);
}

// ---------------- CSR gather, MLP-optimized, pair payload ----------------
// agg[c] = dinv[c] * sum( (dinv[src]*w) * h[src] ) + dinv[c]^2 * h[c]
template<int F>
__global__ __launch_bounds__(256) void k_gatherH(const __half* __restrict__ h,
                                                 const float* __restrict__ dinv,
                                                 const int* __restrict__ startv,
                                                 const int* __restrict__ cnt,
                                                 const int2* __restrict__ pairs,
                                                 __half* __restrict__ agg){
    constexpr int LPN = F/4;                       // lanes per node
    int node = blockIdx.x*(256/LPN) + threadIdx.x/LPN;
    int q    = (threadIdx.x % LPN)*4;              // first half index
    const __half* hq = h + q;
    float a0 = 0.f, a1 = 0.f, a2 = 0.f, a3 = 0.f;

    int s = startv[node];
    int e = s + cnt[node];
    for (; s + 4 <= e; s += 4){
        int2 p0 = pairs[s], p1 = pairs[s+1], p2 = pairs[s+2], p3 = pairs[s+3];
        uint2 u0 = *(const uint2*)(hq + (size_t)p0.x*F);
        uint2 u1 = *(const uint2*)(hq + (size_t)p1.x*F);
        uint2 u2v= *(const uint2*)(hq + (size_t)p2.x*F);
        uint2 u3 = *(const uint2*)(hq + (size_t)p3.x*F);
        float n0 = __int_as_float(p0.y), n1 = __int_as_float(p1.y);
        float n2 = __int_as_float(p2.y), n3 = __int_as_float(p3.y);
        float2 v0 = u2f(u0.x), v1 = u2f(u0.y);
        a0 += n0*v0.x; a1 += n0*v0.y; a2 += n0*v1.x; a3 += n0*v1.y;
        float2 w0 = u2f(u1.x), w1 = u2f(u1.y);
        a0 += n1*w0.x; a1 += n1*w0.y; a2 += n1*w1.x; a3 += n1*w1.y;
        float2 x0 = u2f(u2v.x), x1 = u2f(u2v.y);
        a0 += n2*x0.x; a1 += n2*x0.y; a2 += n2*x1.x; a3 += n2*x1.y;
        float2 y0 = u2f(u3.x), y1 = u2f(u3.y);
        a0 += n3*y0.x; a1 += n3*y0.y; a2 += n3*y1.x; a3 += n3*y1.y;
    }
    for (; s < e; ++s){
        int2 p0 = pairs[s];
        uint2 u0 = *(const uint2*)(hq + (size_t)p0.x*F);
        float n0 = __int_as_float(p0.y);
        float2 v0 = u2f(u0.x), v1 = u2f(u0.y);
        a0 += n0*v0.x; a1 += n0*v0.y; a2 += n0*v1.x; a3 += n0*v1.y;
    }
    float di = dinv[node];
    float d2s = di*di;
    uint2 us = *(const uint2*)(hq + (size_t)node*F);
    float2 sl = u2f(us.x), sh2 = u2f(us.y);
    a0 = di*a0 + d2s*sl.x;
    a1 = di*a1 + d2s*sl.y;
    a2 = di*a2 + d2s*sh2.x;
    a3 = di*a3 + d2s*sh2.y;
    *(uint2*)(agg + (size_t)node*F + q) = make_uint2(f2u(a0,a1), f2u(a2,a3));
}

// ---------------- dense GEMM: out[n][64] = agg[n][CINP](fp16) @ W[64][CINP]^T + b ----------------
template<int CINP>
__global__ __launch_bounds__(256) void k_gemmH(const __half* __restrict__ hin,
                                               const float* __restrict__ W,
                                               const float* __restrict__ bias,
                                               float* __restrict__ out){
    constexpr int SH = CINP + 4;
    constexpr int SW = 68;
    __shared__ float sh_h[64*SH];
    __shared__ float sh_w[64*SW];
    __shared__ float s_b[64];
    int t = threadIdx.x;
    int nodeBase = blockIdx.x * 64;

    if (t < 64) s_b[t] = bias[t];
    #pragma unroll
    for (int r = 0; r < CINP/16; ++r){
        int flat = (r*256 + t)*4;
        int o = flat / CINP, k = flat - o*CINP;
        float4 v = *(const float4*)(W + flat);
        *(float4*)(&sh_w[o*SW + k]) = v;
    }
    constexpr int GPR = CINP/8;
    #pragma unroll
    for (int r = 0; r < CINP/32; ++r){
        int g = r*256 + t;
        int rowi = g / GPR, kq = (g % GPR)*8;
        uint4 u = *(const uint4*)(hin + (size_t)(nodeBase + rowi)*CINP + kq);
        float2 f0 = u2f(u.x), f1 = u2f(u.y), f2v = u2f(u.z), f3 = u2f(u.w);
        float* d = &sh_h[rowi*SH + kq];
        *(float4*)(d)   = make_float4(f0.x, f0.y, f1.x, f1.y);
        *(float4*)(d+4) = make_float4(f2v.x, f2v.y, f3.x, f3.y);
    }
    __syncthreads();

    int nl = t >> 2, q = t & 3;
    float acc[16];
    #pragma unroll
    for (int i = 0; i < 16; ++i) acc[i] = 0.f;
    const float* hrow = &sh_h[nl*SH];
    #pragma unroll
    for (int k = 0; k < CINP; k += 4){
        float4 hv = *(const float4*)(hrow + k);
        #pragma unroll
        for (int o = 0; o < 16; ++o){
            float4 wv = *(const float4*)(&sh_w[(q*16+o)*SW + k]);
            acc[o] += hv.x*wv.x + hv.y*wv.y + hv.z*wv.z + hv.w*wv.w;
        }
    }
    float* dst = out + (size_t)(nodeBase + nl)*64 + q*16;
    #pragma unroll
    for (int o = 0; o < 4; ++o)
        *(float4*)(dst + o*4) = make_float4(acc[o*4] + s_b[q*16+o*4],
                                            acc[o*4+1] + s_b[q*16+o*4+1],
                                            acc[o*4+2] + s_b[q*16+o*4+2],
                                            acc[o*4+3] + s_b[q*16+o*4+3]);
}

// ---------------- BN stats over node axis ----------------
__global__ __launch_bounds__(256) void k_bn_reduce(const float* __restrict__ x, float* gsum, float* gsq){
    int t = threadIdx.x;
    int f = t & 63, g4 = t >> 6;
    float s = 0.f, q = 0.f;
    for (int i = blockIdx.x*4 + g4; i < N_TOTAL; i += gridDim.x*4){
        float v = x[(size_t)i*64 + f];
        s += v; q += v*v;
    }
    __shared__ float sh[2][4][64];
    sh[0][g4][f] = s; sh[1][g4][f] = q;
    __syncthreads();
    if (t < 64){
        float ss = sh[0][0][t] + sh[0][1][t] + sh[0][2][t] + sh[0][3][t];
        float qq = sh[1][0][t] + sh[1][1][t] + sh[1][2][t] + sh[1][3][t];
        atomicAdd(&gsum[t], ss);
        atomicAdd(&gsq[t],  qq);
    }
}

__global__ void k_bn_final(const float* __restrict__ gsum, const float* __restrict__ gsq,
                           const float* __restrict__ g, const float* __restrict__ be,
                           float* scale, float* shift){
    int f = threadIdx.x;
    if (f < 64){
        float mean = gsum[f] / (float)N_TOTAL;
        float var  = gsq[f] / (float)N_TOTAL - mean*mean;
        float sc   = g[f] / sqrtf(var + EPS);
        scale[f] = sc;
        shift[f] = be[f] - mean*sc;
    }
}

// ---------------- fused BN+ReLU + fp16 convert ----------------
__global__ __launch_bounds__(256) void k_bnrelu_h(const float* __restrict__ x,
                                                  const float* __restrict__ scale,
                                                  const float* __restrict__ shift,
                                                  __half* __restrict__ out){
    __shared__ float ssc[64], ssh[64];
    int t = threadIdx.x;
    if (t < 64){ ssc[t] = scale[t]; ssh[t] = shift[t]; }
    __syncthreads();
    int idx = blockIdx.x*256 + t;
    size_t i8 = (size_t)idx*8;
    int f = (int)(i8 & 63);
    float4 a = *(const float4*)(x + i8);
    float4 b = *(const float4*)(x + i8 + 4);
    float r0 = fmaxf(0.f, a.x*ssc[f]   + ssh[f]);
    float r1 = fmaxf(0.f, a.y*ssc[f+1] + ssh[f+1]);
    float r2 = fmaxf(0.f, a.z*ssc[f+2] + ssh[f+2]);
    float r3 = fmaxf(0.f, a.w*ssc[f+3] + ssh[f+3]);
    float r4 = fmaxf(0.f, b.x*ssc[f+4] + ssh[f+4]);
    float r5 = fmaxf(0.f, b.y*ssc[f+5] + ssh[f+5]);
    float r6 = fmaxf(0.f, b.z*ssc[f+6] + ssh[f+6]);
    float r7 = fmaxf(0.f, b.w*ssc[f+7] + ssh[f+7]);
    *(uint4*)(out + i8) = make_uint4(f2u(r0,r1), f2u(r2,r3), f2u(r4,r5), f2u(r6,r7));
}

// ---------------- FC1: C[128][128] = A(fp16)[128][97024] @ Wl1[128][97024]^T ----------------
__global__ __launch_bounds__(256) void k_fc1(const __half* __restrict__ A,
                                             const float* __restrict__ Wl1,
                                             float* __restrict__ part){
    __shared__ float sA[128*36];
    __shared__ float sW[128*36];
    int t = threadIdx.x;
    int tr = t >> 4, tc = t & 15;
    float acc[8][8] = {};
    for (int ti = 0; ti < 4; ++ti){
        int tile  = blockIdx.x*4 + ti;
        int kbase = tile*32;
        __syncthreads();
        #pragma unroll
        for (int r = 0; r < 2; ++r){
            int g = r*256 + t;
            int rowi = g >> 2, kq = (g & 3)*8;
            uint4 u = *(const uint4*)(A + (size_t)rowi*FIN + kbase + kq);
            float2 f0 = u2f(u.x), f1 = u2f(u.y), f2v = u2f(u.z), f3 = u2f(u.w);
            float* d = &sA[rowi*36 + kq];
            *(float4*)(d)   = make_float4(f0.x, f0.y, f1.x, f1.y);
            *(float4*)(d+4) = make_float4(f2v.x, f2v.y, f3.x, f3.y);
        }
        #pragma unroll
        for (int r = 0; r < 4; ++r){
            int g = r*256 + t;
            int rowi = g >> 3, kq = (g & 7)*4;
            float4 w = *(const float4*)(Wl1 + (size_t)rowi*FIN + kbase + kq);
            *(float4*)(&sW[rowi*36 + kq]) = w;
        }
        __syncthreads();
        #pragma unroll 2
        for (int k = 0; k < 32; k += 2){
            float2 a2[8], w2[8];
            #pragma unroll
            for (int i = 0; i < 8; ++i) a2[i] = *(const float2*)(&sA[(tr+16*i)*36 + k]);
            #pragma unroll
            for (int j = 0; j < 8; ++j) w2[j] = *(const float2*)(&sW[(tc+16*j)*36 + k]);
            #pragma unroll
            for (int i = 0; i < 8; ++i)
                #pragma unroll
                for (int j = 0; j < 8; ++j)
                    acc[i][j] += a2[i].x*w2[j].x + a2[i].y*w2[j].y;
        }
    }
    float* p = part + (size_t)blockIdx.x*16384;
    #pragma unroll
    for (int i = 0; i < 8; ++i)
        #pragma unroll
        for (int j = 0; j < 8; ++j)
            p[(tr+16*i)*128 + tc+16*j] = acc[i][j];
}

__global__ __launch_bounds__(256) void k_fc1_reduce(const float* __restrict__ part,
                                                    const float* __restrict__ bl1,
                                                    float* __restrict__ C){
    int idx = blockIdx.x*256 + threadIdx.x;   // 16384
    float s = 0.f;
    for (int kc = 0; kc < 758; ++kc) s += part[(size_t)kc*16384 + idx];
    C[idx] = s + bl1[idx & 127];
}

__global__ void k_fc_stats(const float* __restrict__ C, const float* __restrict__ g,
                           const float* __restrict__ be, float* scale2, float* shift2){
    int j = threadIdx.x;
    if (j < 128){
        float s = 0.f, q = 0.f;
        for (int b = 0; b < 128; ++b){ float v = C[b*128 + j]; s += v; q += v*v; }
        float mean = s / 128.f;
        float var  = q / 128.f - mean*mean;
        float sc   = g[j] / sqrtf(var + EPS);
        scale2[j] = sc;
        shift2[j] = be[j] - mean*sc;
    }
}

__global__ __launch_bounds__(256) void k_fc2(const float* __restrict__ C, const float* __restrict__ scale2,
                                             const float* __restrict__ shift2, const float* __restrict__ Wl3,
                                             const float* __restrict__ bl3, float* __restrict__ out){
    int id = blockIdx.x*256 + threadIdx.x;
    if (id < 1280){
        int b = id / 10, c = id - b*10;
        float acc = bl3[c];
        for (int j = 0; j < 128; ++j){
            float hv = fmaxf(0.f, C[b*128 + j]*scale2[j] + shift2[j]);
            acc += hv * Wl3[c*128 + j];
        }
        out[id] = acc;
    }
}

// ---------------- launch ----------------
extern "C" void kernel_launch(void* const* d_in, const int* in_sizes, int n_in,
                              void* d_out, int out_size, void* d_ws, size_t ws_size,
                              hipStream_t stream){
    const float* x   = (const float*)d_in[0];
    const int*   ei  = (const int*)  d_in[1];
    const float* ew  = (const float*)d_in[2];
    const float* W1  = (const float*)d_in[3];
    const float* b1  = (const float*)d_in[4];
    const float* W2  = (const float*)d_in[5];
    const float* b2  = (const float*)d_in[6];
    const float* W3  = (const float*)d_in[7];
    const float* b3  = (const float*)d_in[8];
    const float* g1  = (const float*)d_in[9];
    const float* be1 = (const float*)d_in[10];
    const float* g2  = (const float*)d_in[11];
    const float* be2 = (const float*)d_in[12];
    const float* g3  = (const float*)d_in[13];
    const float* be3 = (const float*)d_in[14];
    const float* Wl1 = (const float*)d_in[15];
    const float* bl1 = (const float*)d_in[16];
    const float* gl1 = (const float*)d_in[17];
    const float* bel1= (const float*)d_in[18];
    const float* Wl3 = (const float*)d_in[19];
    const float* bl3 = (const float*)d_in[20];
    const int* row = ei;
    const int* col = ei + NE;

    char* p = (char*)d_ws;
    auto alloc = [&](size_t bytes)->char*{
        char* r = p; p += (bytes + 255) & ~(size_t)255; return r;
    };
    float*  bufA     = (float*)alloc((size_t)N_TOTAL*64*4);
    float*  bufB     = (float*)alloc((size_t)758*16384*4);
    __half* hh       = (__half*)alloc((size_t)N_TOTAL*64*2);
    __half* xh       = (__half*)alloc((size_t)N_TOTAL*32*2);
    float*  dinv     = (float*)alloc(N_TOTAL*4);
    int*    cnt      = (int*)  alloc(N_TOTAL*4);
    int*    startv   = (int*)  alloc(N_TOTAL*4);
    int*    pos      = (int*)  alloc((size_t)NE*4);
    int2*   pairs    = (int2*) alloc((size_t)NE*8);
    int*    bs       = (int*)  alloc(4096);
    int*    boff     = (int*)  alloc(4096);
    float*  gsum     = (float*)alloc(256);
    float*  gsq      = (float*)alloc(256);
    float*  scale1   = (float*)alloc(256);
    float*  shift1   = (float*)alloc(256);
    float*  scale2l  = (float*)alloc(256);
    float*  shift2l  = (float*)alloc(256);
    float*  scale3   = (float*)alloc(256);
    float*  shift3   = (float*)alloc(256);
    float*  Cfc      = (float*)alloc(65536);
    float*  scaleF   = (float*)alloc(512);
    float*  shiftF   = (float*)alloc(512);
    __half* agg32    = (__half*)bufB;
    __half* agg64    = (__half*)bufB;

    const int NB_N  = 758;     // N_TOTAL/256
    const int NB_E4 = 3032;    // NE/4/256
    hipMemsetAsync(cnt, 0, N_TOTAL*4, stream);
    k_cnt    <<<NB_E4, 256, 0, stream>>>(col, cnt, pos);
    k_scan1  <<<NB_N,  256, 0, stream>>>(cnt, startv, bs);
    k_scan2  <<<1,     256, 0, stream>>>(bs, boff);
    k_scan3  <<<NB_N,  256, 0, stream>>>(startv, boff);
    k_scatter<<<NB_E4, 256, 0, stream>>>(row, col, ew, pos, startv, pairs);
    k_degdinv<<<NB_N,  256, 0, stream>>>(pairs, startv, cnt, dinv);
    k_norm   <<<NB_E4, 256, 0, stream>>>(pairs, dinv);
    k_prep1  <<<NB_N,  256, 0, stream>>>(x, xh);

    // ---- layer 1 (aggregate-first, 32-dim fp16; 8 lanes/node) ----
    k_gatherH<32><<<6064,  256, 0, stream>>>(xh, dinv, startv, cnt, pairs, agg32);
    k_gemmH<32>  <<<3032,  256, 0, stream>>>(agg32, W1, b1, bufA);
    hipMemsetAsync(gsum, 0, 512, stream);
    k_bn_reduce  <<<1024,  256, 0, stream>>>(bufA, gsum, gsq);
    k_bn_final   <<<1, 64, 0, stream>>>(gsum, gsq, g1, be1, scale1, shift1);
    // ---- layer 2 (16 lanes/node) ----
    k_bnrelu_h   <<<6064,  256, 0, stream>>>(bufA, scale1, shift1, hh);
    k_gatherH<64><<<12128, 256, 0, stream>>>(hh, dinv, startv, cnt, pairs, agg64);
    k_gemmH<64>  <<<3032,  256, 0, stream>>>(agg64, W2, b2, bufA);
    hipMemsetAsync(gsum, 0, 512, stream);
    k_bn_reduce  <<<1024,  256, 0, stream>>>(bufA, gsum, gsq);
    k_bn_final   <<<1, 64, 0, stream>>>(gsum, gsq, g2, be2, scale2l, shift2l);
    // ---- layer 3 ----
    k_bnrelu_h   <<<6064,  256, 0, stream>>>(bufA, scale2l, shift2l, hh);
    k_gatherH<64><<<12128, 256, 0, stream>>>(hh, dinv, startv, cnt, pairs, agg64);
    k_gemmH<64>  <<<3032,  256, 0, stream>>>(agg64, W3, b3, bufA);
    hipMemsetAsync(gsum, 0, 512, stream);
    k_bn_reduce  <<<1024,  256, 0, stream>>>(bufA, gsum, gsq);
    k_bn_final   <<<1, 64, 0, stream>>>(gsum, gsq, g3, be3, scale3, shift3);

    // ---- FC head ----
    k_bnrelu_h  <<<6064, 256, 0, stream>>>(bufA, scale3, shift3, hh);
    k_fc1       <<<758,  256, 0, stream>>>(hh, Wl1, bufB);
    k_fc1_reduce<<<64,   256, 0, stream>>>(bufB, bl1, Cfc);
    k_fc_stats  <<<1,    128, 0, stream>>>(Cfc, gl1, bel1, scaleF, shiftF);
    k_fc2       <<<5,    256, 0, stream>>>(Cfc, scaleF, shiftF, Wl3, bl3, (float*)d_out);
}

// Round 6
// 895.965 us; speedup vs baseline: 2.3785x; 1.1552x over previous
//
#include <hip/hip_runtime.h>
#include <hip/hip_fp16.h>

#define N_TOTAL 194048
#define NE      3104768
#define HID     64
#define NNODES  1516
#define CIN     32
#define FIN     97024
#define EPS     1e-5f
#define NBUCK   758          // N_TOTAL / 256
#define NBLKC   1024         // edge-chunk blocks
#define CHUNK   3032         // NE / NBLKC

__device__ inline uint f2u(float a, float b){
    __half2 h = __floats2half2_rn(a, b);
    return *(const uint*)&h;
}
__device__ inline float2 u2f(uint u){
    __half2 h = *(const __half2*)&u;
    return __half22float2(h);
}

// ================= bucketed CSR build (no global atomics) =================
// Pass A: per-block LDS histogram over 758 buckets -> blkhist[bucket][block]
__global__ __launch_bounds__(256) void k_bktA(const int* __restrict__ col,
                                              int* __restrict__ blkhist){
    __shared__ int hist[NBUCK];
    int t = threadIdx.x;
    for (int i = t; i < NBUCK; i += 256) hist[i] = 0;
    __syncthreads();
    int base = blockIdx.x*CHUNK;
    for (int e = base + t; e < base + CHUNK; e += 256)
        atomicAdd(&hist[col[e] >> 8], 1);
    __syncthreads();
    for (int i = t; i < NBUCK; i += 256)
        blkhist[i*NBLKC + blockIdx.x] = hist[i];
}

// Pass B1: per bucket, exclusive scan over the 1024 block counts
__global__ __launch_bounds__(256) void k_bktB1(const int* __restrict__ blkhist,
                                               int* __restrict__ blkoff,
                                               int* __restrict__ btot){
    int b = blockIdx.x, t = threadIdx.x;
    const int* src = blkhist + (size_t)b*NBLKC;
    int4 v = *(const int4*)(src + t*4);
    int s0 = v.x, s1 = s0 + v.y, s2 = s1 + v.z, s3 = s2 + v.w;
    __shared__ int s[256];
    s[t] = s3; __syncthreads();
    for (int off = 1; off < 256; off <<= 1){
        int u = (t >= off) ? s[t-off] : 0;
        __syncthreads();
        s[t] += u;
        __syncthreads();
    }
    int ex = s[t] - s3;
    int* dst = blkoff + (size_t)b*NBLKC + t*4;
    dst[0] = ex; dst[1] = ex + s0; dst[2] = ex + s1; dst[3] = ex + s2;
    if (t == 255) btot[b] = ex + s3;
}

// Pass B2: exclusive scan of 758 bucket totals -> bucketStart (3 elems/thread)
__global__ __launch_bounds__(256) void k_bktB2(const int* __restrict__ btot, int* __restrict__ bstart){
    __shared__ int s[256];
    int t = threadIdx.x;
    int i0 = t*3;
    int a = (i0   < NBUCK) ? btot[i0]   : 0;
    int b = (i0+1 < NBUCK) ? btot[i0+1] : 0;
    int c = (i0+2 < NBUCK) ? btot[i0+2] : 0;
    int tot = a+b+c;
    s[t] = tot; __syncthreads();
    for (int off = 1; off < 256; off <<= 1){
        int u = (t >= off) ? s[t-off] : 0;
        __syncthreads();
        s[t] += u;
        __syncthreads();
    }
    int ex = s[t] - tot;
    if (i0   < NBUCK) bstart[i0]   = ex;
    if (i0+1 < NBUCK) bstart[i0+1] = ex + a;
    if (i0+2 < NBUCK) bstart[i0+2] = ex + a + b;
}

// Pass C: scatter edges into bucket-grouped packed form; LDS rank counters
__global__ __launch_bounds__(256) void k_bktC(const int* __restrict__ row, const int* __restrict__ col,
                                              const float* __restrict__ w,
                                              const int* __restrict__ blkoff,
                                              const int* __restrict__ bstart,
                                              int2* __restrict__ pairsB){
    __shared__ int lbase[NBUCK];
    __shared__ int lrank[NBUCK];
    int t = threadIdx.x;
    for (int i = t; i < NBUCK; i += 256){
        lbase[i] = bstart[i] + blkoff[(size_t)i*NBLKC + blockIdx.x];
        lrank[i] = 0;
    }
    __syncthreads();
    int base = blockIdx.x*CHUNK;
    for (int e = base + t; e < base + CHUNK; e += 256){
        int c = col[e];
        int b = c >> 8;
        int rk = atomicAdd(&lrank[b], 1);
        pairsB[lbase[b] + rk] = make_int2(row[e] | ((c & 255) << 18), __float_as_int(w[e]));
    }
}

// Pass D: per-bucket fine CSR: node counts/offsets/deg via LDS, write final pairs
__global__ __launch_bounds__(256) void k_bktD(const int2* __restrict__ pairsB,
                                              const int* __restrict__ bstart,
                                              const int* __restrict__ btot,
                                              int* __restrict__ startv, int* __restrict__ cnt,
                                              float* __restrict__ dinv,
                                              int2* __restrict__ pairs){
    __shared__ int   nh[256];
    __shared__ float ws[256];
    __shared__ int   noff[256];
    __shared__ int   sc[256];
    int b = blockIdx.x, t = threadIdx.x;
    nh[t] = 0; ws[t] = 0.f;
    __syncthreads();
    int s0 = bstart[b];
    int n  = btot[b];
    for (int e = s0 + t; e < s0 + n; e += 256){
        int2 p = pairsB[e];
        int lo = (p.x >> 18) & 255;
        atomicAdd(&nh[lo], 1);
        atomicAdd(&ws[lo], __int_as_float(p.y));
    }
    __syncthreads();
    int my = nh[t];
    sc[t] = my; __syncthreads();
    for (int off = 1; off < 256; off <<= 1){
        int u = (t >= off) ? sc[t-off] : 0;
        __syncthreads();
        sc[t] += u;
        __syncthreads();
    }
    int ex = sc[t] - my;
    noff[t] = s0 + ex;
    int node = b*256 + t;
    startv[node] = s0 + ex;
    cnt[node]    = my;
    dinv[node]   = rsqrtf(1.0f + ws[t]);
    nh[t] = 0;                 // reuse as rank counters
    __syncthreads();
    for (int e = s0 + t; e < s0 + n; e += 256){
        int2 p = pairsB[e];
        int lo = (p.x >> 18) & 255;
        int rk = atomicAdd(&nh[lo], 1);
        pairs[noff[lo] + rk] = make_int2(p.x & 0x3FFFF, p.y);
    }
}

// fold dinv[src] into pair weight: pair.w = dinv[src]*w
__global__ __launch_bounds__(256) void k_norm(int2* __restrict__ pairs, const float* __restrict__ dinv){
    int s0 = (blockIdx.x*256 + threadIdx.x)*4;
    int4 a = *(const int4*)(pairs + s0);
    int4 b = *(const int4*)(pairs + s0 + 2);
    float d0 = dinv[a.x], d1 = dinv[a.z], d2 = dinv[b.x], d3 = dinv[b.z];
    a.y = __float_as_int(__int_as_float(a.y) * d0);
    a.w = __float_as_int(__int_as_float(a.w) * d1);
    b.y = __float_as_int(__int_as_float(b.y) * d2);
    b.w = __float_as_int(__int_as_float(b.w) * d3);
    *(int4*)(pairs + s0)     = a;
    *(int4*)(pairs + s0 + 2) = b;
}

// ---------------- transpose x [B][32][1516] -> xh fp16 [N][32] ----------------
__global__ __launch_bounds__(256) void k_prep1(const float* __restrict__ x, __half* __restrict__ xh){
    int idx = blockIdx.x*256 + threadIdx.x;
    if (idx >= N_TOTAL) return;
    int b = idx / NNODES, nn = idx - b*NNODES;
    const float* xp = x + (size_t)b*CIN*NNODES + nn;
    uint u[16];
    #pragma unroll
    for (int c2 = 0; c2 < 16; ++c2){
        float a0 = xp[(size_t)(2*c2)*NNODES];
        float a1 = xp[(size_t)(2*c2+1)*NNODES];
        u[c2] = f2u(a0, a1);
    }
    uint4* dst = (uint4*)(xh + (size_t)idx*CIN);
    dst[0] = make_uint4(u[0], u[1], u[2],  u[3]);
    dst[1] = make_uint4(u[4], u[5], u[6],  u[7]);
    dst[2] = make_uint4(u[8], u[9], u[10], u[11]);
    dst[3] = make_uint4(u[12],u[13],u[14], u[15]);
}

// ---------------- CSR gather, MLP-optimized, pair payload ----------------
template<int F>
__global__ __launch_bounds__(256) void k_gatherH(const __half* __restrict__ h,
                                                 const float* __restrict__ dinv,
                                                 const int* __restrict__ startv,
                                                 const int* __restrict__ cnt,
                                                 const int2* __restrict__ pairs,
                                                 __half* __restrict__ agg){
    constexpr int LPN = F/4;
    int node = blockIdx.x*(256/LPN) + threadIdx.x/LPN;
    int q    = (threadIdx.x % LPN)*4;
    const __half* hq = h + q;
    float a0 = 0.f, a1 = 0.f, a2 = 0.f, a3 = 0.f;

    int s = startv[node];
    int e = s + cnt[node];
    for (; s + 4 <= e; s += 4){
        int2 p0 = pairs[s], p1 = pairs[s+1], p2 = pairs[s+2], p3 = pairs[s+3];
        uint2 u0 = *(const uint2*)(hq + (size_t)p0.x*F);
        uint2 u1 = *(const uint2*)(hq + (size_t)p1.x*F);
        uint2 u2v= *(const uint2*)(hq + (size_t)p2.x*F);
        uint2 u3 = *(const uint2*)(hq + (size_t)p3.x*F);
        float n0 = __int_as_float(p0.y), n1 = __int_as_float(p1.y);
        float n2 = __int_as_float(p2.y), n3 = __int_as_float(p3.y);
        float2 v0 = u2f(u0.x), v1 = u2f(u0.y);
        a0 += n0*v0.x; a1 += n0*v0.y; a2 += n0*v1.x; a3 += n0*v1.y;
        float2 w0 = u2f(u1.x), w1 = u2f(u1.y);
        a0 += n1*w0.x; a1 += n1*w0.y; a2 += n1*w1.x; a3 += n1*w1.y;
        float2 x0 = u2f(u2v.x), x1 = u2f(u2v.y);
        a0 += n2*x0.x; a1 += n2*x0.y; a2 += n2*x1.x; a3 += n2*x1.y;
        float2 y0 = u2f(u3.x), y1 = u2f(u3.y);
        a0 += n3*y0.x; a1 += n3*y0.y; a2 += n3*y1.x; a3 += n3*y1.y;
    }
    for (; s < e; ++s){
        int2 p0 = pairs[s];
        uint2 u0 = *(const uint2*)(hq + (size_t)p0.x*F);
        float n0 = __int_as_float(p0.y);
        float2 v0 = u2f(u0.x), v1 = u2f(u0.y);
        a0 += n0*v0.x; a1 += n0*v0.y; a2 += n0*v1.x; a3 += n0*v1.y;
    }
    float di = dinv[node];
    float d2s = di*di;
    uint2 us = *(const uint2*)(hq + (size_t)node*F);
    float2 sl = u2f(us.x), sh2 = u2f(us.y);
    a0 = di*a0 + d2s*sl.x;
    a1 = di*a1 + d2s*sl.y;
    a2 = di*a2 + d2s*sh2.x;
    a3 = di*a3 + d2s*sh2.y;
    *(uint2*)(agg + (size_t)node*F + q) = make_uint2(f2u(a0,a1), f2u(a2,a3));
}

// ---------------- dense GEMM: out fp16 [n][64] = agg[n][CINP](fp16) @ W^T + b ----------------
template<int CINP>
__global__ __launch_bounds__(256) void k_gemmH(const __half* __restrict__ hin,
                                               const float* __restrict__ W,
                                               const float* __restrict__ bias,
                                               __half* __restrict__ out){
    constexpr int SH = CINP + 4;
    constexpr int SW = 68;
    __shared__ float sh_h[64*SH];
    __shared__ float sh_w[64*SW];
    __shared__ float s_b[64];
    int t = threadIdx.x;
    int nodeBase = blockIdx.x * 64;

    if (t < 64) s_b[t] = bias[t];
    #pragma unroll
    for (int r = 0; r < CINP/16; ++r){
        int flat = (r*256 + t)*4;
        int o = flat / CINP, k = flat - o*CINP;
        float4 v = *(const float4*)(W + flat);
        *(float4*)(&sh_w[o*SW + k]) = v;
    }
    constexpr int GPR = CINP/8;
    #pragma unroll
    for (int r = 0; r < CINP/32; ++r){
        int g = r*256 + t;
        int rowi = g / GPR, kq = (g % GPR)*8;
        uint4 u = *(const uint4*)(hin + (size_t)(nodeBase + rowi)*CINP + kq);
        float2 f0 = u2f(u.x), f1 = u2f(u.y), f2v = u2f(u.z), f3 = u2f(u.w);
        float* d = &sh_h[rowi*SH + kq];
        *(float4*)(d)   = make_float4(f0.x, f0.y, f1.x, f1.y);
        *(float4*)(d+4) = make_float4(f2v.x, f2v.y, f3.x, f3.y);
    }
    __syncthreads();

    int nl = t >> 2, q = t & 3;
    float acc[16];
    #pragma unroll
    for (int i = 0; i < 16; ++i) acc[i] = 0.f;
    const float* hrow = &sh_h[nl*SH];
    #pragma unroll
    for (int k = 0; k < CINP; k += 4){
        float4 hv = *(const float4*)(hrow + k);
        #pragma unroll
        for (int o = 0; o < 16; ++o){
            float4 wv = *(const float4*)(&sh_w[(q*16+o)*SW + k]);
            acc[o] += hv.x*wv.x + hv.y*wv.y + hv.z*wv.z + hv.w*wv.w;
        }
    }
    uint u[8];
    #pragma unroll
    for (int o2 = 0; o2 < 8; ++o2)
        u[o2] = f2u(acc[2*o2] + s_b[q*16 + 2*o2], acc[2*o2+1] + s_b[q*16 + 2*o2+1]);
    uint4* dst = (uint4*)(out + (size_t)(nodeBase + nl)*64 + q*16);
    dst[0] = make_uint4(u[0], u[1], u[2], u[3]);
    dst[1] = make_uint4(u[4], u[5], u[6], u[7]);
}

// ---------------- BN stats over node axis (fp16 input) ----------------
__global__ __launch_bounds__(256) void k_bn_reduce(const __half* __restrict__ x, float* gsum, float* gsq){
    int t = threadIdx.x;
    int f = t & 63, g4 = t >> 6;
    float s = 0.f, q = 0.f;
    for (int i = blockIdx.x*4 + g4; i < N_TOTAL; i += gridDim.x*4){
        float v = __half2float(x[(size_t)i*64 + f]);
        s += v; q += v*v;
    }
    __shared__ float sh[2][4][64];
    sh[0][g4][f] = s; sh[1][g4][f] = q;
    __syncthreads();
    if (t < 64){
        float ss = sh[0][0][t] + sh[0][1][t] + sh[0][2][t] + sh[0][3][t];
        float qq = sh[1][0][t] + sh[1][1][t] + sh[1][2][t] + sh[1][3][t];
        atomicAdd(&gsum[t], ss);
        atomicAdd(&gsq[t],  qq);
    }
}

__global__ void k_bn_final(const float* __restrict__ gsum, const float* __restrict__ gsq,
                           const float* __restrict__ g, const float* __restrict__ be,
                           float* scale, float* shift){
    int f = threadIdx.x;
    if (f < 64){
        float mean = gsum[f] / (float)N_TOTAL;
        float var  = gsq[f] / (float)N_TOTAL - mean*mean;
        float sc   = g[f] / sqrtf(var + EPS);
        scale[f] = sc;
        shift[f] = be[f] - mean*sc;
    }
}

// ---------------- fused BN+ReLU (fp16 in -> fp16 out) ----------------
__global__ __launch_bounds__(256) void k_bnrelu_h(const __half* __restrict__ x,
                                                  const float* __restrict__ scale,
                                                  const float* __restrict__ shift,
                                                  __half* __restrict__ out){
    __shared__ float ssc[64], ssh[64];
    int t = threadIdx.x;
    if (t < 64){ ssc[t] = scale[t]; ssh[t] = shift[t]; }
    __syncthreads();
    int idx = blockIdx.x*256 + t;
    size_t i8 = (size_t)idx*8;
    int f = (int)(i8 & 63);
    uint4 u = *(const uint4*)(x + i8);
    float2 a0 = u2f(u.x), a1 = u2f(u.y), a2 = u2f(u.z), a3 = u2f(u.w);
    float r0 = fmaxf(0.f, a0.x*ssc[f]   + ssh[f]);
    float r1 = fmaxf(0.f, a0.y*ssc[f+1] + ssh[f+1]);
    float r2 = fmaxf(0.f, a1.x*ssc[f+2] + ssh[f+2]);
    float r3 = fmaxf(0.f, a1.y*ssc[f+3] + ssh[f+3]);
    float r4 = fmaxf(0.f, a2.x*ssc[f+4] + ssh[f+4]);
    float r5 = fmaxf(0.f, a2.y*ssc[f+5] + ssh[f+5]);
    float r6 = fmaxf(0.f, a3.x*ssc[f+6] + ssh[f+6]);
    float r7 = fmaxf(0.f, a3.y*ssc[f+7] + ssh[f+7]);
    *(uint4*)(out + i8) = make_uint4(f2u(r0,r1), f2u(r2,r3), f2u(r4,r5), f2u(r6,r7));
}

// ---------------- FC1: C[128][128] = A(fp16)[128][97024] @ Wl1[128][97024]^T ----------------
__global__ __launch_bounds__(256) void k_fc1(const __half* __restrict__ A,
                                             const float* __restrict__ Wl1,
                                             float* __restrict__ part){
    __shared__ float sA[128*36];
    __shared__ float sW[128*36];
    int t = threadIdx.x;
    int tr = t >> 4, tc = t & 15;
    float acc[8][8] = {};
    for (int ti = 0; ti < 4; ++ti){
        int tile  = blockIdx.x*4 + ti;
        int kbase = tile*32;
        __syncthreads();
        #pragma unroll
        for (int r = 0; r < 2; ++r){
            int g = r*256 + t;
            int rowi = g >> 2, kq = (g & 3)*8;
            uint4 u = *(const uint4*)(A + (size_t)rowi*FIN + kbase + kq);
            float2 f0 = u2f(u.x), f1 = u2f(u.y), f2v = u2f(u.z), f3 = u2f(u.w);
            float* d = &sA[rowi*36 + kq];
            *(float4*)(d)   = make_float4(f0.x, f0.y, f1.x, f1.y);
            *(float4*)(d+4) = make_float4(f2v.x, f2v.y, f3.x, f3.y);
        }
        #pragma unroll
        for (int r = 0; r < 4; ++r){
            int g = r*256 + t;
            int rowi = g >> 3, kq = (g & 7)*4;
            float4 w = *(const float4*)(Wl1 + (size_t)rowi*FIN + kbase + kq);
            *(float4*)(&sW[rowi*36 + kq]) = w;
        }
        __syncthreads();
        #pragma unroll 2
        for (int k = 0; k < 32; k += 2){
            float2 a2[8], w2[8];
            #pragma unroll
            for (int i = 0; i < 8; ++i) a2[i] = *(const float2*)(&sA[(tr+16*i)*36 + k]);
            #pragma unroll
            for (int j = 0; j < 8; ++j) w2[j] = *(const float2*)(&sW[(tc+16*j)*36 + k]);
            #pragma unroll
            for (int i = 0; i < 8; ++i)
                #pragma unroll
                for (int j = 0; j < 8; ++j)
                    acc[i][j] += a2[i].x*w2[j].x + a2[i].y*w2[j].y;
        }
    }
    float* p = part + (size_t)blockIdx.x*16384;
    #pragma unroll
    for (int i = 0; i < 8; ++i)
        #pragma unroll
        for (int j = 0; j < 8; ++j)
            p[(tr+16*i)*128 + tc+16*j] = acc[i][j];
}

__global__ __launch_bounds__(256) void k_fc1_reduce(const float* __restrict__ part,
                                                    const float* __restrict__ bl1,
                                                    float* __restrict__ C){
    int idx = blockIdx.x*256 + threadIdx.x;   // 16384
    float s = 0.f;
    for (int kc = 0; kc < 758; ++kc) s += part[(size_t)kc*16384 + idx];
    C[idx] = s + bl1[idx & 127];
}

__global__ void k_fc_stats(const float* __restrict__ C, const float* __restrict__ g,
                           const float* __restrict__ be, float* scale2, float* shift2){
    int j = threadIdx.x;
    if (j < 128){
        float s = 0.f, q = 0.f;
        for (int b = 0; b < 128; ++b){ float v = C[b*128 + j]; s += v; q += v*v; }
        float mean = s / 128.f;
        float var  = q / 128.f - mean*mean;
        float sc   = g[j] / sqrtf(var + EPS);
        scale2[j] = sc;
        shift2[j] = be[j] - mean*sc;
    }
}

__global__ __launch_bounds__(256) void k_fc2(const float* __restrict__ C, const float* __restrict__ scale2,
                                             const float* __restrict__ shift2, const float* __restrict__ Wl3,
                                             const float* __restrict__ bl3, float* __restrict__ out){
    int id = blockIdx.x*256 + threadIdx.x;
    if (id < 1280){
        int b = id / 10, c = id - b*10;
        float acc = bl3[c];
        for (int j = 0; j < 128; ++j){
            float hv = fmaxf(0.f, C[b*128 + j]*scale2[j] + shift2[j]);
            acc += hv * Wl3[c*128 + j];
        }
        out[id] = acc;
    }
}

// ---------------- launch ----------------
extern "C" void kernel_launch(void* const* d_in, const int* in_sizes, int n_in,
                              void* d_out, int out_size, void* d_ws, size_t ws_size,
                              hipStream_t stream){
    const float* x   = (const float*)d_in[0];
    const int*   ei  = (const int*)  d_in[1];
    const float* ew  = (const float*)d_in[2];
    const float* W1  = (const float*)d_in[3];
    const float* b1  = (const float*)d_in[4];
    const float* W2  = (const float*)d_in[5];
    const float* b2  = (const float*)d_in[6];
    const float* W3  = (const float*)d_in[7];
    const float* b3  = (const float*)d_in[8];
    const float* g1  = (const float*)d_in[9];
    const float* be1 = (const float*)d_in[10];
    const float* g2  = (const float*)d_in[11];
    const float* be2 = (const float*)d_in[12];
    const float* g3  = (const float*)d_in[13];
    const float* be3 = (const float*)d_in[14];
    const float* Wl1 = (const float*)d_in[15];
    const float* bl1 = (const float*)d_in[16];
    const float* gl1 = (const float*)d_in[17];
    const float* bel1= (const float*)d_in[18];
    const float* Wl3 = (const float*)d_in[19];
    const float* bl3 = (const float*)d_in[20];
    const int* row = ei;
    const int* col = ei + NE;

    char* p = (char*)d_ws;
    auto alloc = [&](size_t bytes)->char*{
        char* r = p; p += (bytes + 255) & ~(size_t)255; return r;
    };
    float*  bufB     = (float*)alloc((size_t)758*16384*4);      // agg scratch / FC1 partials
    __half* hpre     = (__half*)alloc((size_t)N_TOTAL*64*2);    // conv out fp16 (pre-BN)
    __half* hh       = (__half*)alloc((size_t)N_TOTAL*64*2);    // post-BN-relu fp16
    __half* xh       = (__half*)alloc((size_t)N_TOTAL*32*2);    // transposed input fp16
    float*  dinv     = (float*)alloc(N_TOTAL*4);
    int*    cnt      = (int*)  alloc(N_TOTAL*4);
    int*    startv   = (int*)  alloc(N_TOTAL*4);
    int2*   pairsB   = (int2*) alloc((size_t)NE*8);
    int2*   pairs    = (int2*) alloc((size_t)NE*8);
    int*    blkhist  = (int*)  alloc((size_t)NBUCK*NBLKC*4);
    int*    blkoff   = (int*)  alloc((size_t)NBUCK*NBLKC*4);
    int*    btot     = (int*)  alloc(NBUCK*4);
    int*    bstart   = (int*)  alloc(NBUCK*4);
    float*  gsum     = (float*)alloc(256);
    float*  gsq      = (float*)alloc(256);
    float*  scale1   = (float*)alloc(256);
    float*  shift1   = (float*)alloc(256);
    float*  scale2l  = (float*)alloc(256);
    float*  shift2l  = (float*)alloc(256);
    float*  scale3   = (float*)alloc(256);
    float*  shift3   = (float*)alloc(256);
    float*  Cfc      = (float*)alloc(65536);
    float*  scaleF   = (float*)alloc(512);
    float*  shiftF   = (float*)alloc(512);
    __half* agg32    = (__half*)bufB;
    __half* agg64    = (__half*)bufB;

    const int NB_N  = 758;     // N_TOTAL/256
    const int NB_E4 = 3032;    // NE/4/256
    k_bktA <<<NBLKC, 256, 0, stream>>>(col, blkhist);
    k_bktB1<<<NBUCK, 256, 0, stream>>>(blkhist, blkoff, btot);
    k_bktB2<<<1,     256, 0, stream>>>(btot, bstart);
    k_bktC <<<NBLKC, 256, 0, stream>>>(row, col, ew, blkoff, bstart, pairsB);
    k_bktD <<<NBUCK, 256, 0, stream>>>(pairsB, bstart, btot, startv, cnt, dinv, pairs);
    k_norm <<<NB_E4, 256, 0, stream>>>(pairs, dinv);
    k_prep1<<<NB_N,  256, 0, stream>>>(x, xh);

    // ---- layer 1 (aggregate-first, 32-dim fp16; 8 lanes/node) ----
    k_gatherH<32><<<6064,  256, 0, stream>>>(xh, dinv, startv, cnt, pairs, agg32);
    k_gemmH<32>  <<<3032,  256, 0, stream>>>(agg32, W1, b1, hpre);
    hipMemsetAsync(gsum, 0, 512, stream);
    k_bn_reduce  <<<1024,  256, 0, stream>>>(hpre, gsum, gsq);
    k_bn_final   <<<1, 64, 0, stream>>>(gsum, gsq, g1, be1, scale1, shift1);
    // ---- layer 2 (16 lanes/node) ----
    k_bnrelu_h   <<<6064,  256, 0, stream>>>(hpre, scale1, shift1, hh);
    k_gatherH<64><<<12128, 256, 0, stream>>>(hh, dinv, startv, cnt, pairs, agg64);
    k_gemmH<64>  <<<3032,  256, 0, stream>>>(agg64, W2, b2, hpre);
    hipMemsetAsync(gsum, 0, 512, stream);
    k_bn_reduce  <<<1024,  256, 0, stream>>>(hpre, gsum, gsq);
    k_bn_final   <<<1, 64, 0, stream>>>(gsum, gsq, g2, be2, scale2l, shift2l);
    // ---- layer 3 ----
    k_bnrelu_h   <<<6064,  256, 0, stream>>>(hpre, scale2l, shift2l, hh);
    k_gatherH<64><<<12128, 256, 0, stream>>>(hh, dinv, startv, cnt, pairs, agg64);
    k_gemmH<64>  <<<3032,  256, 0, stream>>>(agg64, W3, b3, hpre);
    hipMemsetAsync(gsum, 0, 512, stream);
    k_bn_reduce  <<<1024,  256, 0, stream>>>(hpre, gsum, gsq);
    k_bn_final   <<<1, 64, 0, stream>>>(gsum, gsq, g3, be3, scale3, shift3);

    // ---- FC head ----
    k_bnrelu_h  <<<6064, 256, 0, stream>>>(hpre, scale3, shift3, hh);
    k_fc1       <<<758,  256, 0, stream>>>(hh, Wl1, bufB);
    k_fc1_reduce<<<64,   256, 0, stream>>>(bufB, bl1, Cfc);
    k_fc_stats  <<<1,    128, 0, stream>>>(Cfc, gl1, bel1, scaleF, shiftF);
    k_fc2       <<<5,    256, 0, stream>>>(Cfc, scaleF, shiftF, Wl3, bl3, (float*)d_out);
}

// Round 7
// 703.542 us; speedup vs baseline: 3.0290x; 1.2735x over previous
//
#include <hip/hip_runtime.h>
#include <hip/hip_fp16.h>

#define N_TOTAL 194048
#define NE      3104768
#define HID     64
#define NNODES  1516
#define CIN     32
#define FIN     97024
#define EPS     1e-5f
#define NBUCK   758          // N_TOTAL / 256
#define NBLKC   1024         // edge-chunk blocks
#define CHUNK   3032         // NE / NBLKC

using f16x8 = __attribute__((ext_vector_type(8))) _Float16;
using f32x4 = __attribute__((ext_vector_type(4))) float;

__device__ inline uint f2u(float a, float b){
    __half2 h = __floats2half2_rn(a, b);
    return *(const uint*)&h;
}
__device__ inline float2 u2f(uint u){
    __half2 h = *(const __half2*)&u;
    return __half22float2(h);
}

// ================= bucketed CSR build (no global atomics) =================
__global__ __launch_bounds__(256) void k_bktA(const int* __restrict__ col,
                                              int* __restrict__ blkhist){
    __shared__ int hist[NBUCK];
    int t = threadIdx.x;
    for (int i = t; i < NBUCK; i += 256) hist[i] = 0;
    __syncthreads();
    int base = blockIdx.x*CHUNK;
    for (int e = base + t; e < base + CHUNK; e += 256)
        atomicAdd(&hist[col[e] >> 8], 1);
    __syncthreads();
    for (int i = t; i < NBUCK; i += 256)
        blkhist[i*NBLKC + blockIdx.x] = hist[i];
}

__global__ __launch_bounds__(256) void k_bktB1(const int* __restrict__ blkhist,
                                               int* __restrict__ blkoff,
                                               int* __restrict__ btot){
    int b = blockIdx.x, t = threadIdx.x;
    const int* src = blkhist + (size_t)b*NBLKC;
    int4 v = *(const int4*)(src + t*4);
    int s0 = v.x, s1 = s0 + v.y, s2 = s1 + v.z, s3 = s2 + v.w;
    __shared__ int s[256];
    s[t] = s3; __syncthreads();
    for (int off = 1; off < 256; off <<= 1){
        int u = (t >= off) ? s[t-off] : 0;
        __syncthreads();
        s[t] += u;
        __syncthreads();
    }
    int ex = s[t] - s3;
    int* dst = blkoff + (size_t)b*NBLKC + t*4;
    dst[0] = ex; dst[1] = ex + s0; dst[2] = ex + s1; dst[3] = ex + s2;
    if (t == 255) btot[b] = ex + s3;
}

__global__ __launch_bounds__(256) void k_bktB2(const int* __restrict__ btot, int* __restrict__ bstart){
    __shared__ int s[256];
    int t = threadIdx.x;
    int i0 = t*3;
    int a = (i0   < NBUCK) ? btot[i0]   : 0;
    int b = (i0+1 < NBUCK) ? btot[i0+1] : 0;
    int c = (i0+2 < NBUCK) ? btot[i0+2] : 0;
    int tot = a+b+c;
    s[t] = tot; __syncthreads();
    for (int off = 1; off < 256; off <<= 1){
        int u = (t >= off) ? s[t-off] : 0;
        __syncthreads();
        s[t] += u;
        __syncthreads();
    }
    int ex = s[t] - tot;
    if (i0   < NBUCK) bstart[i0]   = ex;
    if (i0+1 < NBUCK) bstart[i0+1] = ex + a;
    if (i0+2 < NBUCK) bstart[i0+2] = ex + a + b;
}

__global__ __launch_bounds__(256) void k_bktC(const int* __restrict__ row, const int* __restrict__ col,
                                              const float* __restrict__ w,
                                              const int* __restrict__ blkoff,
                                              const int* __restrict__ bstart,
                                              int2* __restrict__ pairsB){
    __shared__ int lbase[NBUCK];
    __shared__ int lrank[NBUCK];
    int t = threadIdx.x;
    for (int i = t; i < NBUCK; i += 256){
        lbase[i] = bstart[i] + blkoff[(size_t)i*NBLKC + blockIdx.x];
        lrank[i] = 0;
    }
    __syncthreads();
    int base = blockIdx.x*CHUNK;
    for (int e = base + t; e < base + CHUNK; e += 256){
        int c = col[e];
        int b = c >> 8;
        int rk = atomicAdd(&lrank[b], 1);
        pairsB[lbase[b] + rk] = make_int2(row[e] | ((c & 255) << 18), __float_as_int(w[e]));
    }
}

__global__ __launch_bounds__(256) void k_bktD(const int2* __restrict__ pairsB,
                                              const int* __restrict__ bstart,
                                              const int* __restrict__ btot,
                                              int* __restrict__ startv, int* __restrict__ cnt,
                                              float* __restrict__ dinv,
                                              int2* __restrict__ pairs){
    __shared__ int   nh[256];
    __shared__ float ws[256];
    __shared__ int   noff[256];
    __shared__ int   sc[256];
    int b = blockIdx.x, t = threadIdx.x;
    nh[t] = 0; ws[t] = 0.f;
    __syncthreads();
    int s0 = bstart[b];
    int n  = btot[b];
    for (int e = s0 + t; e < s0 + n; e += 256){
        int2 p = pairsB[e];
        int lo = (p.x >> 18) & 255;
        atomicAdd(&nh[lo], 1);
        atomicAdd(&ws[lo], __int_as_float(p.y));
    }
    __syncthreads();
    int my = nh[t];
    sc[t] = my; __syncthreads();
    for (int off = 1; off < 256; off <<= 1){
        int u = (t >= off) ? sc[t-off] : 0;
        __syncthreads();
        sc[t] += u;
        __syncthreads();
    }
    int ex = sc[t] - my;
    noff[t] = s0 + ex;
    int node = b*256 + t;
    startv[node] = s0 + ex;
    cnt[node]    = my;
    dinv[node]   = rsqrtf(1.0f + ws[t]);
    nh[t] = 0;
    __syncthreads();
    for (int e = s0 + t; e < s0 + n; e += 256){
        int2 p = pairsB[e];
        int lo = (p.x >> 18) & 255;
        int rk = atomicAdd(&nh[lo], 1);
        pairs[noff[lo] + rk] = make_int2(p.x & 0x3FFFF, p.y);
    }
}

__global__ __launch_bounds__(256) void k_norm(int2* __restrict__ pairs, const float* __restrict__ dinv){
    int s0 = (blockIdx.x*256 + threadIdx.x)*4;
    int4 a = *(const int4*)(pairs + s0);
    int4 b = *(const int4*)(pairs + s0 + 2);
    float d0 = dinv[a.x], d1 = dinv[a.z], d2 = dinv[b.x], d3 = dinv[b.z];
    a.y = __float_as_int(__int_as_float(a.y) * d0);
    a.w = __float_as_int(__int_as_float(a.w) * d1);
    b.y = __float_as_int(__int_as_float(b.y) * d2);
    b.w = __float_as_int(__int_as_float(b.w) * d3);
    *(int4*)(pairs + s0)     = a;
    *(int4*)(pairs + s0 + 2) = b;
}

// ---------------- transpose x [B][32][1516] -> xh fp16 [N][32] ----------------
__global__ __launch_bounds__(256) void k_prep1(const float* __restrict__ x, __half* __restrict__ xh){
    int idx = blockIdx.x*256 + threadIdx.x;
    if (idx >= N_TOTAL) return;
    int b = idx / NNODES, nn = idx - b*NNODES;
    const float* xp = x + (size_t)b*CIN*NNODES + nn;
    uint u[16];
    #pragma unroll
    for (int c2 = 0; c2 < 16; ++c2){
        float a0 = xp[(size_t)(2*c2)*NNODES];
        float a1 = xp[(size_t)(2*c2+1)*NNODES];
        u[c2] = f2u(a0, a1);
    }
    uint4* dst = (uint4*)(xh + (size_t)idx*CIN);
    dst[0] = make_uint4(u[0], u[1], u[2],  u[3]);
    dst[1] = make_uint4(u[4], u[5], u[6],  u[7]);
    dst[2] = make_uint4(u[8], u[9], u[10], u[11]);
    dst[3] = make_uint4(u[12],u[13],u[14], u[15]);
}

// ---------------- W fp32 -> fp16 ----------------
__global__ __launch_bounds__(256) void k_prepW(const float* __restrict__ W1, const float* __restrict__ W2,
                                               const float* __restrict__ W3,
                                               __half* __restrict__ Wh1, __half* __restrict__ Wh2,
                                               __half* __restrict__ Wh3){
    int t = blockIdx.x*256 + threadIdx.x;
    if (t < 2048) Wh1[t] = __float2half(W1[t]);
    if (t < 4096){ Wh2[t] = __float2half(W2[t]); Wh3[t] = __float2half(W3[t]); }
}

// ---------------- CSR gather, MLP-optimized, optional fused BN+ReLU ----------------
template<bool BN>
__device__ inline void acc4(float n, uint2 u, const float4& sc, const float4& sh,
                            float& a0, float& a1, float& a2, float& a3){
    float2 lo = u2f(u.x), hi = u2f(u.y);
    float v0, v1, v2, v3;
    if (BN){
        v0 = fmaxf(0.f, lo.x*sc.x + sh.x); v1 = fmaxf(0.f, lo.y*sc.y + sh.y);
        v2 = fmaxf(0.f, hi.x*sc.z + sh.z); v3 = fmaxf(0.f, hi.y*sc.w + sh.w);
    } else { v0 = lo.x; v1 = lo.y; v2 = hi.x; v3 = hi.y; }
    a0 += n*v0; a1 += n*v1; a2 += n*v2; a3 += n*v3;
}

template<int F, bool BN>
__global__ __launch_bounds__(256) void k_gatherH(const __half* __restrict__ h,
                                                 const float* __restrict__ dinv,
                                                 const int* __restrict__ startv,
                                                 const int* __restrict__ cnt,
                                                 const int2* __restrict__ pairs,
                                                 const float* __restrict__ scale,
                                                 const float* __restrict__ shift,
                                                 __half* __restrict__ agg){
    constexpr int LPN = F/4;
    int node = blockIdx.x*(256/LPN) + threadIdx.x/LPN;
    int q    = (threadIdx.x % LPN)*4;
    const __half* hq = h + q;
    float4 sc = make_float4(0,0,0,0), sh = make_float4(0,0,0,0);
    if (BN){ sc = *(const float4*)(scale + q); sh = *(const float4*)(shift + q); }
    float a0 = 0.f, a1 = 0.f, a2 = 0.f, a3 = 0.f;

    int s = startv[node];
    int e = s + cnt[node];
    for (; s + 4 <= e; s += 4){
        int2 p0 = pairs[s], p1 = pairs[s+1], p2 = pairs[s+2], p3 = pairs[s+3];
        uint2 u0 = *(const uint2*)(hq + (size_t)p0.x*F);
        uint2 u1 = *(const uint2*)(hq + (size_t)p1.x*F);
        uint2 u2v= *(const uint2*)(hq + (size_t)p2.x*F);
        uint2 u3 = *(const uint2*)(hq + (size_t)p3.x*F);
        acc4<BN>(__int_as_float(p0.y), u0,  sc, sh, a0, a1, a2, a3);
        acc4<BN>(__int_as_float(p1.y), u1,  sc, sh, a0, a1, a2, a3);
        acc4<BN>(__int_as_float(p2.y), u2v, sc, sh, a0, a1, a2, a3);
        acc4<BN>(__int_as_float(p3.y), u3,  sc, sh, a0, a1, a2, a3);
    }
    for (; s < e; ++s){
        int2 p0 = pairs[s];
        uint2 u0 = *(const uint2*)(hq + (size_t)p0.x*F);
        acc4<BN>(__int_as_float(p0.y), u0, sc, sh, a0, a1, a2, a3);
    }
    float di = dinv[node];
    a0 *= di; a1 *= di; a2 *= di; a3 *= di;
    uint2 us = *(const uint2*)(hq + (size_t)node*F);
    acc4<BN>(di*di, us, sc, sh, a0, a1, a2, a3);   // self-loop term
    *(uint2*)(agg + (size_t)node*F + q) = make_uint2(f2u(a0,a1), f2u(a2,a3));
}

// ---------------- MFMA GEMM: out fp16 [n][64] = agg[n][K](fp16) @ Wh[64][K]^T + b ----------------
// 4 waves/block; wave computes 16 nodes x 64 outs via 4 col-tiles of 16x16x32 MFMA.
// A: lane row=l&15, k=(l>>4)*8..+7 ; B[k][col]=Wh[col][k] -> lane reads Wh row (l&15).
// C/D: col=lane&15, row=(lane>>4)*4+reg  [HW-verified mapping]
template<int K>
__global__ __launch_bounds__(256) void k_gemmMF(const __half* __restrict__ hin,
                                                const __half* __restrict__ Wh,
                                                const float* __restrict__ bias,
                                                __half* __restrict__ out){
    __shared__ __align__(16) __half lds[4][16][72];
    int t = threadIdx.x;
    int wv = t >> 6, l = t & 63;
    int lr = l & 15, lk = (l >> 4) * 8;
    int node0 = blockIdx.x*64 + wv*16;

    f16x8 a0 = *(const f16x8*)(hin + (size_t)(node0 + lr)*K + lk);
    f16x8 a1;
    if (K == 64) a1 = *(const f16x8*)(hin + (size_t)(node0 + lr)*K + 32 + lk);

    f32x4 acc[4];
    #pragma unroll
    for (int tt = 0; tt < 4; ++tt){
        f16x8 b0 = *(const f16x8*)(Wh + (size_t)(tt*16 + lr)*K + lk);
        acc[tt] = (f32x4){0.f, 0.f, 0.f, 0.f};
        acc[tt] = __builtin_amdgcn_mfma_f32_16x16x32_f16(a0, b0, acc[tt], 0, 0, 0);
        if (K == 64){
            f16x8 b1 = *(const f16x8*)(Wh + (size_t)(tt*16 + lr)*K + 32 + lk);
            acc[tt] = __builtin_amdgcn_mfma_f32_16x16x32_f16(a1, b1, acc[tt], 0, 0, 0);
        }
    }
    // bias + fp16, transpose via per-wave LDS tile, coalesced stores
    #pragma unroll
    for (int tt = 0; tt < 4; ++tt){
        float bb = bias[tt*16 + lr];
        #pragma unroll
        for (int r = 0; r < 4; ++r)
            lds[wv][(l>>4)*4 + r][tt*16 + lr] = __float2half(acc[tt][r] + bb);
    }
    int rr = l >> 2, cc = (l & 3)*16;
    uint4 v0 = *(const uint4*)(&lds[wv][rr][cc]);
    uint4 v1 = *(const uint4*)(&lds[wv][rr][cc + 8]);
    *(uint4*)(out + (size_t)(node0 + rr)*64 + cc)     = v0;
    *(uint4*)(out + (size_t)(node0 + rr)*64 + cc + 8) = v1;
}

// ---------------- BN stats over node axis (fp16 input) ----------------
__global__ __launch_bounds__(256) void k_bn_reduce(const __half* __restrict__ x, float* gsum, float* gsq){
    int t = threadIdx.x;
    int f = t & 63, g4 = t >> 6;
    float s = 0.f, q = 0.f;
    for (int i = blockIdx.x*4 + g4; i < N_TOTAL; i += gridDim.x*4){
        float v = __half2float(x[(size_t)i*64 + f]);
        s += v; q += v*v;
    }
    __shared__ float sh[2][4][64];
    sh[0][g4][f] = s; sh[1][g4][f] = q;
    __syncthreads();
    if (t < 64){
        float ss = sh[0][0][t] + sh[0][1][t] + sh[0][2][t] + sh[0][3][t];
        float qq = sh[1][0][t] + sh[1][1][t] + sh[1][2][t] + sh[1][3][t];
        atomicAdd(&gsum[t], ss);
        atomicAdd(&gsq[t],  qq);
    }
}

__global__ void k_bn_final(const float* __restrict__ gsum, const float* __restrict__ gsq,
                           const float* __restrict__ g, const float* __restrict__ be,
                           float* scale, float* shift){
    int f = threadIdx.x;
    if (f < 64){
        float mean = gsum[f] / (float)N_TOTAL;
        float var  = gsq[f] / (float)N_TOTAL - mean*mean;
        float sc   = g[f] / sqrtf(var + EPS);
        scale[f] = sc;
        shift[f] = be[f] - mean*sc;
    }
}

// ---------------- fused BN+ReLU (fp16 in -> fp16 out), used once before FC1 ----------------
__global__ __launch_bounds__(256) void k_bnrelu_h(const __half* __restrict__ x,
                                                  const float* __restrict__ scale,
                                                  const float* __restrict__ shift,
                                                  __half* __restrict__ out){
    __shared__ float ssc[64], ssh[64];
    int t = threadIdx.x;
    if (t < 64){ ssc[t] = scale[t]; ssh[t] = shift[t]; }
    __syncthreads();
    int idx = blockIdx.x*256 + t;
    size_t i8 = (size_t)idx*8;
    int f = (int)(i8 & 63);
    uint4 u = *(const uint4*)(x + i8);
    float2 a0 = u2f(u.x), a1 = u2f(u.y), a2 = u2f(u.z), a3 = u2f(u.w);
    float r0 = fmaxf(0.f, a0.x*ssc[f]   + ssh[f]);
    float r1 = fmaxf(0.f, a0.y*ssc[f+1] + ssh[f+1]);
    float r2 = fmaxf(0.f, a1.x*ssc[f+2] + ssh[f+2]);
    float r3 = fmaxf(0.f, a1.y*ssc[f+3] + ssh[f+3]);
    float r4 = fmaxf(0.f, a2.x*ssc[f+4] + ssh[f+4]);
    float r5 = fmaxf(0.f, a2.y*ssc[f+5] + ssh[f+5]);
    float r6 = fmaxf(0.f, a3.x*ssc[f+6] + ssh[f+6]);
    float r7 = fmaxf(0.f, a3.y*ssc[f+7] + ssh[f+7]);
    *(uint4*)(out + i8) = make_uint4(f2u(r0,r1), f2u(r2,r3), f2u(r4,r5), f2u(r6,r7));
}

// ---------------- FC1: C[128][128] = A(fp16)[128][97024] @ Wl1[128][97024]^T ----------------
__global__ __launch_bounds__(256) void k_fc1(const __half* __restrict__ A,
                                             const float* __restrict__ Wl1,
                                             float* __restrict__ part){
    __shared__ float sA[128*36];
    __shared__ float sW[128*36];
    int t = threadIdx.x;
    int tr = t >> 4, tc = t & 15;
    float acc[8][8] = {};
    for (int ti = 0; ti < 4; ++ti){
        int tile  = blockIdx.x*4 + ti;
        int kbase = tile*32;
        __syncthreads();
        #pragma unroll
        for (int r = 0; r < 2; ++r){
            int g = r*256 + t;
            int rowi = g >> 2, kq = (g & 3)*8;
            uint4 u = *(const uint4*)(A + (size_t)rowi*FIN + kbase + kq);
            float2 f0 = u2f(u.x), f1 = u2f(u.y), f2v = u2f(u.z), f3 = u2f(u.w);
            float* d = &sA[rowi*36 + kq];
            *(float4*)(d)   = make_float4(f0.x, f0.y, f1.x, f1.y);
            *(float4*)(d+4) = make_float4(f2v.x, f2v.y, f3.x, f3.y);
        }
        #pragma unroll
        for (int r = 0; r < 4; ++r){
            int g = r*256 + t;
            int rowi = g >> 3, kq = (g & 7)*4;
            float4 w = *(const float4*)(Wl1 + (size_t)rowi*FIN + kbase + kq);
            *(float4*)(&sW[rowi*36 + kq]) = w;
        }
        __syncthreads();
        #pragma unroll 2
        for (int k = 0; k < 32; k += 2){
            float2 a2[8], w2[8];
            #pragma unroll
            for (int i = 0; i < 8; ++i) a2[i] = *(const float2*)(&sA[(tr+16*i)*36 + k]);
            #pragma unroll
            for (int j = 0; j < 8; ++j) w2[j] = *(const float2*)(&sW[(tc+16*j)*36 + k]);
            #pragma unroll
            for (int i = 0; i < 8; ++i)
                #pragma unroll
                for (int j = 0; j < 8; ++j)
                    acc[i][j] += a2[i].x*w2[j].x + a2[i].y*w2[j].y;
        }
    }
    float* p = part + (size_t)blockIdx.x*16384;
    #pragma unroll
    for (int i = 0; i < 8; ++i)
        #pragma unroll
        for (int j = 0; j < 8; ++j)
            p[(tr+16*i)*128 + tc+16*j] = acc[i][j];
}

__global__ __launch_bounds__(256) void k_fc1_reduce(const float* __restrict__ part,
                                                    const float* __restrict__ bl1,
                                                    float* __restrict__ C){
    int idx = blockIdx.x*256 + threadIdx.x;   // 16384
    float s = 0.f;
    for (int kc = 0; kc < 758; ++kc) s += part[(size_t)kc*16384 + idx];
    C[idx] = s + bl1[idx & 127];
}

__global__ void k_fc_stats(const float* __restrict__ C, const float* __restrict__ g,
                           const float* __restrict__ be, float* scale2, float* shift2){
    int j = threadIdx.x;
    if (j < 128){
        float s = 0.f, q = 0.f;
        for (int b = 0; b < 128; ++b){ float v = C[b*128 + j]; s += v; q += v*v; }
        float mean = s / 128.f;
        float var  = q / 128.f - mean*mean;
        float sc   = g[j] / sqrtf(var + EPS);
        scale2[j] = sc;
        shift2[j] = be[j] - mean*sc;
    }
}

__global__ __launch_bounds__(256) void k_fc2(const float* __restrict__ C, const float* __restrict__ scale2,
                                             const float* __restrict__ shift2, const float* __restrict__ Wl3,
                                             const float* __restrict__ bl3, float* __restrict__ out){
    int id = blockIdx.x*256 + threadIdx.x;
    if (id < 1280){
        int b = id / 10, c = id - b*10;
        float acc = bl3[c];
        for (int j = 0; j < 128; ++j){
            float hv = fmaxf(0.f, C[b*128 + j]*scale2[j] + shift2[j]);
            acc += hv * Wl3[c*128 + j];
        }
        out[id] = acc;
    }
}

// ---------------- launch ----------------
extern "C" void kernel_launch(void* const* d_in, const int* in_sizes, int n_in,
                              void* d_out, int out_size, void* d_ws, size_t ws_size,
                              hipStream_t stream){
    const float* x   = (const float*)d_in[0];
    const int*   ei  = (const int*)  d_in[1];
    const float* ew  = (const float*)d_in[2];
    const float* W1  = (const float*)d_in[3];
    const float* b1  = (const float*)d_in[4];
    const float* W2  = (const float*)d_in[5];
    const float* b2  = (const float*)d_in[6];
    const float* W3  = (const float*)d_in[7];
    const float* b3  = (const float*)d_in[8];
    const float* g1  = (const float*)d_in[9];
    const float* be1 = (const float*)d_in[10];
    const float* g2  = (const float*)d_in[11];
    const float* be2 = (const float*)d_in[12];
    const float* g3  = (const float*)d_in[13];
    const float* be3 = (const float*)d_in[14];
    const float* Wl1 = (const float*)d_in[15];
    const float* bl1 = (const float*)d_in[16];
    const float* gl1 = (const float*)d_in[17];
    const float* bel1= (const float*)d_in[18];
    const float* Wl3 = (const float*)d_in[19];
    const float* bl3 = (const float*)d_in[20];
    const int* row = ei;
    const int* col = ei + NE;

    char* p = (char*)d_ws;
    auto alloc = [&](size_t bytes)->char*{
        char* r = p; p += (bytes + 255) & ~(size_t)255; return r;
    };
    float*  bufB     = (float*)alloc((size_t)758*16384*4);      // agg scratch / FC1 partials
    __half* hpre     = (__half*)alloc((size_t)N_TOTAL*64*2);    // conv out fp16 (pre-BN)
    __half* hh       = (__half*)alloc((size_t)N_TOTAL*64*2);    // post-BN-relu fp16 (FC1 input)
    __half* xh       = (__half*)alloc((size_t)N_TOTAL*32*2);    // transposed input fp16
    float*  dinv     = (float*)alloc(N_TOTAL*4);
    int*    cnt      = (int*)  alloc(N_TOTAL*4);
    int*    startv   = (int*)  alloc(N_TOTAL*4);
    int2*   pairsB   = (int2*) alloc((size_t)NE*8);
    int2*   pairs    = (int2*) alloc((size_t)NE*8);
    int*    blkhist  = (int*)  alloc((size_t)NBUCK*NBLKC*4);
    int*    blkoff   = (int*)  alloc((size_t)NBUCK*NBLKC*4);
    int*    btot     = (int*)  alloc(NBUCK*4);
    int*    bstart   = (int*)  alloc(NBUCK*4);
    __half* Wh1      = (__half*)alloc(2048*2);
    __half* Wh2      = (__half*)alloc(4096*2);
    __half* Wh3      = (__half*)alloc(4096*2);
    float*  gsum     = (float*)alloc(256);
    float*  gsq      = (float*)alloc(256);
    float*  scale1   = (float*)alloc(256);
    float*  shift1   = (float*)alloc(256);
    float*  scale2l  = (float*)alloc(256);
    float*  shift2l  = (float*)alloc(256);
    float*  scale3   = (float*)alloc(256);
    float*  shift3   = (float*)alloc(256);
    float*  Cfc      = (float*)alloc(65536);
    float*  scaleF   = (float*)alloc(512);
    float*  shiftF   = (float*)alloc(512);
    __half* agg32    = (__half*)bufB;
    __half* agg64    = (__half*)bufB;

    const int NB_N  = 758;     // N_TOTAL/256
    const int NB_E4 = 3032;    // NE/4/256
    k_prepW<<<16,    256, 0, stream>>>(W1, W2, W3, Wh1, Wh2, Wh3);
    k_bktA <<<NBLKC, 256, 0, stream>>>(col, blkhist);
    k_bktB1<<<NBUCK, 256, 0, stream>>>(blkhist, blkoff, btot);
    k_bktB2<<<1,     256, 0, stream>>>(btot, bstart);
    k_bktC <<<NBLKC, 256, 0, stream>>>(row, col, ew, blkoff, bstart, pairsB);
    k_bktD <<<NBUCK, 256, 0, stream>>>(pairsB, bstart, btot, startv, cnt, dinv, pairs);
    k_norm <<<NB_E4, 256, 0, stream>>>(pairs, dinv);
    k_prep1<<<NB_N,  256, 0, stream>>>(x, xh);

    // ---- layer 1 (aggregate-first, 32-dim fp16) ----
    k_gatherH<32,false><<<6064, 256, 0, stream>>>(xh, dinv, startv, cnt, pairs, nullptr, nullptr, agg32);
    k_gemmMF<32>       <<<3032, 256, 0, stream>>>(agg32, Wh1, b1, hpre);
    hipMemsetAsync(gsum, 0, 512, stream);
    k_bn_reduce        <<<1024, 256, 0, stream>>>(hpre, gsum, gsq);
    k_bn_final         <<<1, 64, 0, stream>>>(gsum, gsq, g1, be1, scale1, shift1);
    // ---- layer 2 (BN1+ReLU fused into gather) ----
    k_gatherH<64,true> <<<12128, 256, 0, stream>>>(hpre, dinv, startv, cnt, pairs, scale1, shift1, agg64);
    k_gemmMF<64>       <<<3032,  256, 0, stream>>>(agg64, Wh2, b2, hpre);
    hipMemsetAsync(gsum, 0, 512, stream);
    k_bn_reduce        <<<1024,  256, 0, stream>>>(hpre, gsum, gsq);
    k_bn_final         <<<1, 64, 0, stream>>>(gsum, gsq, g2, be2, scale2l, shift2l);
    // ---- layer 3 ----
    k_gatherH<64,true> <<<12128, 256, 0, stream>>>(hpre, dinv, startv, cnt, pairs, scale2l, shift2l, agg64);
    k_gemmMF<64>       <<<3032,  256, 0, stream>>>(agg64, Wh3, b3, hpre);
    hipMemsetAsync(gsum, 0, 512, stream);
    k_bn_reduce        <<<1024,  256, 0, stream>>>(hpre, gsum, gsq);
    k_bn_final         <<<1, 64, 0, stream>>>(gsum, gsq, g3, be3, scale3, shift3);

    // ---- FC head ----
    k_bnrelu_h  <<<6064, 256, 0, stream>>>(hpre, scale3, shift3, hh);
    k_fc1       <<<758,  256, 0, stream>>>(hh, Wl1, bufB);
    k_fc1_reduce<<<64,   256, 0, stream>>>(bufB, bl1, Cfc);
    k_fc_stats  <<<1,    128, 0, stream>>>(Cfc, gl1, bel1, scaleF, shiftF);
    k_fc2       <<<5,    256, 0, stream>>>(Cfc, scaleF, shiftF, Wl3, bl3, (float*)d_out);
}

// Round 8
// 586.700 us; speedup vs baseline: 3.6323x; 1.1992x over previous
//
#include <hip/hip_runtime.h>
#include <hip/hip_fp16.h>

#define N_TOTAL 194048
#define NE      3104768
#define HID     64
#define NNODES  1516
#define CIN     32
#define FIN     97024
#define EPS     1e-5f
#define NBUCK   758          // N_TOTAL / 256
#define NBLKC   1024         // edge-chunk blocks
#define CHUNK   3032         // NE / NBLKC

using f16x8 = __attribute__((ext_vector_type(8))) _Float16;
using f32x4 = __attribute__((ext_vector_type(4))) float;

__device__ inline uint f2u(float a, float b){
    __half2 h = __floats2half2_rn(a, b);
    return *(const uint*)&h;
}
__device__ inline float2 u2f(uint u){
    __half2 h = *(const __half2*)&u;
    return __half22float2(h);
}

// ================= bucketed CSR build (no global atomics) =================
__global__ __launch_bounds__(256) void k_bktA(const int* __restrict__ col,
                                              int* __restrict__ blkhist){
    __shared__ int hist[NBUCK];
    int t = threadIdx.x;
    for (int i = t; i < NBUCK; i += 256) hist[i] = 0;
    __syncthreads();
    int base = blockIdx.x*CHUNK;
    for (int e = base + t; e < base + CHUNK; e += 256)
        atomicAdd(&hist[col[e] >> 8], 1);
    __syncthreads();
    for (int i = t; i < NBUCK; i += 256)
        blkhist[i*NBLKC + blockIdx.x] = hist[i];
}

__global__ __launch_bounds__(256) void k_bktB1(const int* __restrict__ blkhist,
                                               int* __restrict__ blkoff,
                                               int* __restrict__ btot){
    int b = blockIdx.x, t = threadIdx.x;
    const int* src = blkhist + (size_t)b*NBLKC;
    int4 v = *(const int4*)(src + t*4);
    int s0 = v.x, s1 = s0 + v.y, s2 = s1 + v.z, s3 = s2 + v.w;
    __shared__ int s[256];
    s[t] = s3; __syncthreads();
    for (int off = 1; off < 256; off <<= 1){
        int u = (t >= off) ? s[t-off] : 0;
        __syncthreads();
        s[t] += u;
        __syncthreads();
    }
    int ex = s[t] - s3;
    int* dst = blkoff + (size_t)b*NBLKC + t*4;
    dst[0] = ex; dst[1] = ex + s0; dst[2] = ex + s1; dst[3] = ex + s2;
    if (t == 255) btot[b] = ex + s3;
}

__global__ __launch_bounds__(256) void k_bktB2(const int* __restrict__ btot, int* __restrict__ bstart){
    __shared__ int s[256];
    int t = threadIdx.x;
    int i0 = t*3;
    int a = (i0   < NBUCK) ? btot[i0]   : 0;
    int b = (i0+1 < NBUCK) ? btot[i0+1] : 0;
    int c = (i0+2 < NBUCK) ? btot[i0+2] : 0;
    int tot = a+b+c;
    s[t] = tot; __syncthreads();
    for (int off = 1; off < 256; off <<= 1){
        int u = (t >= off) ? s[t-off] : 0;
        __syncthreads();
        s[t] += u;
        __syncthreads();
    }
    int ex = s[t] - tot;
    if (i0   < NBUCK) bstart[i0]   = ex;
    if (i0+1 < NBUCK) bstart[i0+1] = ex + a;
    if (i0+2 < NBUCK) bstart[i0+2] = ex + a + b;
}

__global__ __launch_bounds__(256) void k_bktC(const int* __restrict__ row, const int* __restrict__ col,
                                              const float* __restrict__ w,
                                              const int* __restrict__ blkoff,
                                              const int* __restrict__ bstart,
                                              int2* __restrict__ pairsB){
    __shared__ int lbase[NBUCK];
    __shared__ int lrank[NBUCK];
    int t = threadIdx.x;
    for (int i = t; i < NBUCK; i += 256){
        lbase[i] = bstart[i] + blkoff[(size_t)i*NBLKC + blockIdx.x];
        lrank[i] = 0;
    }
    __syncthreads();
    int base = blockIdx.x*CHUNK;
    for (int e = base + t; e < base + CHUNK; e += 256){
        int c = col[e];
        int b = c >> 8;
        int rk = atomicAdd(&lrank[b], 1);
        pairsB[lbase[b] + rk] = make_int2(row[e] | ((c & 255) << 18), __float_as_int(w[e]));
    }
}

__global__ __launch_bounds__(256) void k_bktD(const int2* __restrict__ pairsB,
                                              const int* __restrict__ bstart,
                                              const int* __restrict__ btot,
                                              int* __restrict__ startv, int* __restrict__ cnt,
                                              float* __restrict__ dinv,
                                              int2* __restrict__ pairs){
    __shared__ int   nh[256];
    __shared__ float ws[256];
    __shared__ int   noff[256];
    __shared__ int   sc[256];
    int b = blockIdx.x, t = threadIdx.x;
    nh[t] = 0; ws[t] = 0.f;
    __syncthreads();
    int s0 = bstart[b];
    int n  = btot[b];
    for (int e = s0 + t; e < s0 + n; e += 256){
        int2 p = pairsB[e];
        int lo = (p.x >> 18) & 255;
        atomicAdd(&nh[lo], 1);
        atomicAdd(&ws[lo], __int_as_float(p.y));
    }
    __syncthreads();
    int my = nh[t];
    sc[t] = my; __syncthreads();
    for (int off = 1; off < 256; off <<= 1){
        int u = (t >= off) ? sc[t-off] : 0;
        __syncthreads();
        sc[t] += u;
        __syncthreads();
    }
    int ex = sc[t] - my;
    noff[t] = s0 + ex;
    int node = b*256 + t;
    startv[node] = s0 + ex;
    cnt[node]    = my;
    dinv[node]   = rsqrtf(1.0f + ws[t]);
    nh[t] = 0;
    __syncthreads();
    for (int e = s0 + t; e < s0 + n; e += 256){
        int2 p = pairsB[e];
        int lo = (p.x >> 18) & 255;
        int rk = atomicAdd(&nh[lo], 1);
        pairs[noff[lo] + rk] = make_int2(p.x & 0x3FFFF, p.y);
    }
}

__global__ __launch_bounds__(256) void k_norm(int2* __restrict__ pairs, const float* __restrict__ dinv){
    int s0 = (blockIdx.x*256 + threadIdx.x)*4;
    int4 a = *(const int4*)(pairs + s0);
    int4 b = *(const int4*)(pairs + s0 + 2);
    float d0 = dinv[a.x], d1 = dinv[a.z], d2 = dinv[b.x], d3 = dinv[b.z];
    a.y = __float_as_int(__int_as_float(a.y) * d0);
    a.w = __float_as_int(__int_as_float(a.w) * d1);
    b.y = __float_as_int(__int_as_float(b.y) * d2);
    b.w = __float_as_int(__int_as_float(b.w) * d3);
    *(int4*)(pairs + s0)     = a;
    *(int4*)(pairs + s0 + 2) = b;
}

// ---------------- transpose x [B][32][1516] -> xh fp16 [N][32] ----------------
__global__ __launch_bounds__(256) void k_prep1(const float* __restrict__ x, __half* __restrict__ xh){
    int idx = blockIdx.x*256 + threadIdx.x;
    if (idx >= N_TOTAL) return;
    int b = idx / NNODES, nn = idx - b*NNODES;
    const float* xp = x + (size_t)b*CIN*NNODES + nn;
    uint u[16];
    #pragma unroll
    for (int c2 = 0; c2 < 16; ++c2){
        float a0 = xp[(size_t)(2*c2)*NNODES];
        float a1 = xp[(size_t)(2*c2+1)*NNODES];
        u[c2] = f2u(a0, a1);
    }
    uint4* dst = (uint4*)(xh + (size_t)idx*CIN);
    dst[0] = make_uint4(u[0], u[1], u[2],  u[3]);
    dst[1] = make_uint4(u[4], u[5], u[6],  u[7]);
    dst[2] = make_uint4(u[8], u[9], u[10], u[11]);
    dst[3] = make_uint4(u[12],u[13],u[14], u[15]);
}

// ---------------- W fp32 -> fp16 ----------------
__global__ __launch_bounds__(256) void k_prepW(const float* __restrict__ W1, const float* __restrict__ W2,
                                               const float* __restrict__ W3,
                                               __half* __restrict__ Wh1, __half* __restrict__ Wh2,
                                               __half* __restrict__ Wh3){
    int t = blockIdx.x*256 + threadIdx.x;
    if (t < 2048) Wh1[t] = __float2half(W1[t]);
    if (t < 4096){ Wh2[t] = __float2half(W2[t]); Wh3[t] = __float2half(W3[t]); }
}

// ---------------- CSR gather, MLP-optimized, optional fused BN+ReLU ----------------
template<bool BN>
__device__ inline void acc4(float n, uint2 u, const float4& sc, const float4& sh,
                            float& a0, float& a1, float& a2, float& a3){
    float2 lo = u2f(u.x), hi = u2f(u.y);
    float v0, v1, v2, v3;
    if (BN){
        v0 = fmaxf(0.f, lo.x*sc.x + sh.x); v1 = fmaxf(0.f, lo.y*sc.y + sh.y);
        v2 = fmaxf(0.f, hi.x*sc.z + sh.z); v3 = fmaxf(0.f, hi.y*sc.w + sh.w);
    } else { v0 = lo.x; v1 = lo.y; v2 = hi.x; v3 = hi.y; }
    a0 += n*v0; a1 += n*v1; a2 += n*v2; a3 += n*v3;
}

template<int F, bool BN>
__global__ __launch_bounds__(256) void k_gatherH(const __half* __restrict__ h,
                                                 const float* __restrict__ dinv,
                                                 const int* __restrict__ startv,
                                                 const int* __restrict__ cnt,
                                                 const int2* __restrict__ pairs,
                                                 const float* __restrict__ scale,
                                                 const float* __restrict__ shift,
                                                 __half* __restrict__ agg){
    constexpr int LPN = F/4;
    int node = blockIdx.x*(256/LPN) + threadIdx.x/LPN;
    int q    = (threadIdx.x % LPN)*4;
    const __half* hq = h + q;
    float4 sc = make_float4(0,0,0,0), sh = make_float4(0,0,0,0);
    if (BN){ sc = *(const float4*)(scale + q); sh = *(const float4*)(shift + q); }
    float a0 = 0.f, a1 = 0.f, a2 = 0.f, a3 = 0.f;

    int s = startv[node];
    int e = s + cnt[node];
    for (; s + 4 <= e; s += 4){
        int2 p0 = pairs[s], p1 = pairs[s+1], p2 = pairs[s+2], p3 = pairs[s+3];
        uint2 u0 = *(const uint2*)(hq + (size_t)p0.x*F);
        uint2 u1 = *(const uint2*)(hq + (size_t)p1.x*F);
        uint2 u2v= *(const uint2*)(hq + (size_t)p2.x*F);
        uint2 u3 = *(const uint2*)(hq + (size_t)p3.x*F);
        acc4<BN>(__int_as_float(p0.y), u0,  sc, sh, a0, a1, a2, a3);
        acc4<BN>(__int_as_float(p1.y), u1,  sc, sh, a0, a1, a2, a3);
        acc4<BN>(__int_as_float(p2.y), u2v, sc, sh, a0, a1, a2, a3);
        acc4<BN>(__int_as_float(p3.y), u3,  sc, sh, a0, a1, a2, a3);
    }
    for (; s < e; ++s){
        int2 p0 = pairs[s];
        uint2 u0 = *(const uint2*)(hq + (size_t)p0.x*F);
        acc4<BN>(__int_as_float(p0.y), u0, sc, sh, a0, a1, a2, a3);
    }
    float di = dinv[node];
    a0 *= di; a1 *= di; a2 *= di; a3 *= di;
    uint2 us = *(const uint2*)(hq + (size_t)node*F);
    acc4<BN>(di*di, us, sc, sh, a0, a1, a2, a3);   // self-loop term
    *(uint2*)(agg + (size_t)node*F + q) = make_uint2(f2u(a0,a1), f2u(a2,a3));
}

// ---------------- MFMA GEMM: out fp16 [n][64] = agg[n][K](fp16) @ Wh[64][K]^T + b ----------------
template<int K>
__global__ __launch_bounds__(256) void k_gemmMF(const __half* __restrict__ hin,
                                                const __half* __restrict__ Wh,
                                                const float* __restrict__ bias,
                                                __half* __restrict__ out){
    __shared__ __align__(16) __half lds[4][16][72];
    int t = threadIdx.x;
    int wv = t >> 6, l = t & 63;
    int lr = l & 15, lk = (l >> 4) * 8;
    int node0 = blockIdx.x*64 + wv*16;

    f16x8 a0 = *(const f16x8*)(hin + (size_t)(node0 + lr)*K + lk);
    f16x8 a1;
    if (K == 64) a1 = *(const f16x8*)(hin + (size_t)(node0 + lr)*K + 32 + lk);

    f32x4 acc[4];
    #pragma unroll
    for (int tt = 0; tt < 4; ++tt){
        f16x8 b0 = *(const f16x8*)(Wh + (size_t)(tt*16 + lr)*K + lk);
        acc[tt] = (f32x4){0.f, 0.f, 0.f, 0.f};
        acc[tt] = __builtin_amdgcn_mfma_f32_16x16x32_f16(a0, b0, acc[tt], 0, 0, 0);
        if (K == 64){
            f16x8 b1 = *(const f16x8*)(Wh + (size_t)(tt*16 + lr)*K + 32 + lk);
            acc[tt] = __builtin_amdgcn_mfma_f32_16x16x32_f16(a1, b1, acc[tt], 0, 0, 0);
        }
    }
    #pragma unroll
    for (int tt = 0; tt < 4; ++tt){
        float bb = bias[tt*16 + lr];
        #pragma unroll
        for (int r = 0; r < 4; ++r)
            lds[wv][(l>>4)*4 + r][tt*16 + lr] = __float2half(acc[tt][r] + bb);
    }
    int rr = l >> 2, cc = (l & 3)*16;
    uint4 v0 = *(const uint4*)(&lds[wv][rr][cc]);
    uint4 v1 = *(const uint4*)(&lds[wv][rr][cc + 8]);
    *(uint4*)(out + (size_t)(node0 + rr)*64 + cc)     = v0;
    *(uint4*)(out + (size_t)(node0 + rr)*64 + cc + 8) = v1;
}

// ---------------- BN stats over node axis (fp16 input) ----------------
__global__ __launch_bounds__(256) void k_bn_reduce(const __half* __restrict__ x, float* gsum, float* gsq){
    int t = threadIdx.x;
    int f = t & 63, g4 = t >> 6;
    float s = 0.f, q = 0.f;
    for (int i = blockIdx.x*4 + g4; i < N_TOTAL; i += gridDim.x*4){
        float v = __half2float(x[(size_t)i*64 + f]);
        s += v; q += v*v;
    }
    __shared__ float sh[2][4][64];
    sh[0][g4][f] = s; sh[1][g4][f] = q;
    __syncthreads();
    if (t < 64){
        float ss = sh[0][0][t] + sh[0][1][t] + sh[0][2][t] + sh[0][3][t];
        float qq = sh[1][0][t] + sh[1][1][t] + sh[1][2][t] + sh[1][3][t];
        atomicAdd(&gsum[t], ss);
        atomicAdd(&gsq[t],  qq);
    }
}

__global__ void k_bn_final(const float* __restrict__ gsum, const float* __restrict__ gsq,
                           const float* __restrict__ g, const float* __restrict__ be,
                           float* scale, float* shift){
    int f = threadIdx.x;
    if (f < 64){
        float mean = gsum[f] / (float)N_TOTAL;
        float var  = gsq[f] / (float)N_TOTAL - mean*mean;
        float sc   = g[f] / sqrtf(var + EPS);
        scale[f] = sc;
        shift[f] = be[f] - mean*sc;
    }
}

// ---------------- FC1: C = relu(bn(A)) @ Wl1^T, split-K; BN fused into A staging ----------------
__global__ __launch_bounds__(256) void k_fc1(const __half* __restrict__ A,
                                             const float* __restrict__ Wl1,
                                             const float* __restrict__ scale,
                                             const float* __restrict__ shift,
                                             float* __restrict__ part){
    __shared__ float sA[128*36];
    __shared__ float sW[128*36];
    __shared__ float s_sc[64], s_sh[64];
    int t = threadIdx.x;
    if (t < 64){ s_sc[t] = scale[t]; s_sh[t] = shift[t]; }
    int tr = t >> 4, tc = t & 15;
    float acc[8][8] = {};
    for (int ti = 0; ti < 4; ++ti){
        int tile  = blockIdx.x*4 + ti;
        int kbase = tile*32;
        int fb    = (tile & 1) << 5;
        __syncthreads();     // LDS reuse + s_sc visibility on first iter
        #pragma unroll
        for (int r = 0; r < 2; ++r){
            int g = r*256 + t;
            int rowi = g >> 2, kq = (g & 3)*8;
            uint4 u = *(const uint4*)(A + (size_t)rowi*FIN + kbase + kq);
            float2 f0 = u2f(u.x), f1 = u2f(u.y), f2v = u2f(u.z), f3 = u2f(u.w);
            int f = fb + kq;
            float v0 = fmaxf(0.f, f0.x*s_sc[f]   + s_sh[f]);
            float v1 = fmaxf(0.f, f0.y*s_sc[f+1] + s_sh[f+1]);
            float v2 = fmaxf(0.f, f1.x*s_sc[f+2] + s_sh[f+2]);
            float v3 = fmaxf(0.f, f1.y*s_sc[f+3] + s_sh[f+3]);
            float v4 = fmaxf(0.f, f2v.x*s_sc[f+4] + s_sh[f+4]);
            float v5 = fmaxf(0.f, f2v.y*s_sc[f+5] + s_sh[f+5]);
            float v6 = fmaxf(0.f, f3.x*s_sc[f+6] + s_sh[f+6]);
            float v7 = fmaxf(0.f, f3.y*s_sc[f+7] + s_sh[f+7]);
            float* d = &sA[rowi*36 + kq];
            *(float4*)(d)   = make_float4(v0, v1, v2, v3);
            *(float4*)(d+4) = make_float4(v4, v5, v6, v7);
        }
        #pragma unroll
        for (int r = 0; r < 4; ++r){
            int g = r*256 + t;
            int rowi = g >> 3, kq = (g & 7)*4;
            float4 w = *(const float4*)(Wl1 + (size_t)rowi*FIN + kbase + kq);
            *(float4*)(&sW[rowi*36 + kq]) = w;
        }
        __syncthreads();
        #pragma unroll 2
        for (int k = 0; k < 32; k += 2){
            float2 a2[8], w2[8];
            #pragma unroll
            for (int i = 0; i < 8; ++i) a2[i] = *(const float2*)(&sA[(tr+16*i)*36 + k]);
            #pragma unroll
            for (int j = 0; j < 8; ++j) w2[j] = *(const float2*)(&sW[(tc+16*j)*36 + k]);
            #pragma unroll
            for (int i = 0; i < 8; ++i)
                #pragma unroll
                for (int j = 0; j < 8; ++j)
                    acc[i][j] += a2[i].x*w2[j].x + a2[i].y*w2[j].y;
        }
    }
    float* p = part + (size_t)blockIdx.x*16384;
    #pragma unroll
    for (int i = 0; i < 8; ++i)
        #pragma unroll
        for (int j = 0; j < 8; ++j)
            p[(tr+16*i)*128 + tc+16*j] = acc[i][j];
}

// ---- two-stage split-K reduce (full occupancy, coalesced) ----
__global__ __launch_bounds__(256) void k_fc1_red1(const float* __restrict__ part,
                                                  float* __restrict__ part2){
    int idx = (blockIdx.x & 63)*256 + threadIdx.x;   // 0..16383
    int seg = blockIdx.x >> 6;                        // 0..15
    int k0 = seg*48;
    int k1 = k0 + 48 < 758 ? k0 + 48 : 758;
    float s = 0.f;
    for (int kc = k0; kc < k1; ++kc) s += part[(size_t)kc*16384 + idx];
    part2[(size_t)seg*16384 + idx] = s;
}

__global__ __launch_bounds__(256) void k_fc1_red2(const float* __restrict__ part2,
                                                  const float* __restrict__ bl1,
                                                  float* __restrict__ C){
    int idx = blockIdx.x*256 + threadIdx.x;
    float s = 0.f;
    #pragma unroll
    for (int i = 0; i < 16; ++i) s += part2[(size_t)i*16384 + idx];
    C[idx] = s + bl1[idx & 127];
}

__global__ void k_fc_stats(const float* __restrict__ C, const float* __restrict__ g,
                           const float* __restrict__ be, float* scale2, float* shift2){
    int j = threadIdx.x;
    if (j < 128){
        float s = 0.f, q = 0.f;
        for (int b = 0; b < 128; ++b){ float v = C[b*128 + j]; s += v; q += v*v; }
        float mean = s / 128.f;
        float var  = q / 128.f - mean*mean;
        float sc   = g[j] / sqrtf(var + EPS);
        scale2[j] = sc;
        shift2[j] = be[j] - mean*sc;
    }
}

__global__ __launch_bounds__(256) void k_fc2(const float* __restrict__ C, const float* __restrict__ scale2,
                                             const float* __restrict__ shift2, const float* __restrict__ Wl3,
                                             const float* __restrict__ bl3, float* __restrict__ out){
    int id = blockIdx.x*256 + threadIdx.x;
    if (id < 1280){
        int b = id / 10, c = id - b*10;
        float acc = bl3[c];
        for (int j = 0; j < 128; ++j){
            float hv = fmaxf(0.f, C[b*128 + j]*scale2[j] + shift2[j]);
            acc += hv * Wl3[c*128 + j];
        }
        out[id] = acc;
    }
}

// ---------------- launch ----------------
extern "C" void kernel_launch(void* const* d_in, const int* in_sizes, int n_in,
                              void* d_out, int out_size, void* d_ws, size_t ws_size,
                              hipStream_t stream){
    const float* x   = (const float*)d_in[0];
    const int*   ei  = (const int*)  d_in[1];
    const float* ew  = (const float*)d_in[2];
    const float* W1  = (const float*)d_in[3];
    const float* b1  = (const float*)d_in[4];
    const float* W2  = (const float*)d_in[5];
    const float* b2  = (const float*)d_in[6];
    const float* W3  = (const float*)d_in[7];
    const float* b3  = (const float*)d_in[8];
    const float* g1  = (const float*)d_in[9];
    const float* be1 = (const float*)d_in[10];
    const float* g2  = (const float*)d_in[11];
    const float* be2 = (const float*)d_in[12];
    const float* g3  = (const float*)d_in[13];
    const float* be3 = (const float*)d_in[14];
    const float* Wl1 = (const float*)d_in[15];
    const float* bl1 = (const float*)d_in[16];
    const float* gl1 = (const float*)d_in[17];
    const float* bel1= (const float*)d_in[18];
    const float* Wl3 = (const float*)d_in[19];
    const float* bl3 = (const float*)d_in[20];
    const int* row = ei;
    const int* col = ei + NE;

    char* p = (char*)d_ws;
    auto alloc = [&](size_t bytes)->char*{
        char* r = p; p += (bytes + 255) & ~(size_t)255; return r;
    };
    float*  bufB     = (float*)alloc((size_t)758*16384*4);      // agg scratch / FC1 partials
    float*  part2    = (float*)alloc((size_t)16*16384*4);
    __half* hpre     = (__half*)alloc((size_t)N_TOTAL*64*2);    // conv out fp16 (pre-BN)
    __half* xh       = (__half*)alloc((size_t)N_TOTAL*32*2);    // transposed input fp16
    float*  dinv     = (float*)alloc(N_TOTAL*4);
    int*    cnt      = (int*)  alloc(N_TOTAL*4);
    int*    startv   = (int*)  alloc(N_TOTAL*4);
    int2*   pairsB   = (int2*) alloc((size_t)NE*8);
    int2*   pairs    = (int2*) alloc((size_t)NE*8);
    int*    blkhist  = (int*)  alloc((size_t)NBUCK*NBLKC*4);
    int*    blkoff   = (int*)  alloc((size_t)NBUCK*NBLKC*4);
    int*    btot     = (int*)  alloc(NBUCK*4);
    int*    bstart   = (int*)  alloc(NBUCK*4);
    __half* Wh1      = (__half*)alloc(2048*2);
    __half* Wh2      = (__half*)alloc(4096*2);
    __half* Wh3      = (__half*)alloc(4096*2);
    float*  gsum     = (float*)alloc(256);
    float*  gsq      = (float*)alloc(256);
    float*  scale1   = (float*)alloc(256);
    float*  shift1   = (float*)alloc(256);
    float*  scale2l  = (float*)alloc(256);
    float*  shift2l  = (float*)alloc(256);
    float*  scale3   = (float*)alloc(256);
    float*  shift3   = (float*)alloc(256);
    float*  Cfc      = (float*)alloc(65536);
    float*  scaleF   = (float*)alloc(512);
    float*  shiftF   = (float*)alloc(512);
    __half* agg32    = (__half*)bufB;
    __half* agg64    = (__half*)bufB;

    const int NB_N  = 758;     // N_TOTAL/256
    const int NB_E4 = 3032;    // NE/4/256
    k_prepW<<<16,    256, 0, stream>>>(W1, W2, W3, Wh1, Wh2, Wh3);
    k_bktA <<<NBLKC, 256, 0, stream>>>(col, blkhist);
    k_bktB1<<<NBUCK, 256, 0, stream>>>(blkhist, blkoff, btot);
    k_bktB2<<<1,     256, 0, stream>>>(btot, bstart);
    k_bktC <<<NBLKC, 256, 0, stream>>>(row, col, ew, blkoff, bstart, pairsB);
    k_bktD <<<NBUCK, 256, 0, stream>>>(pairsB, bstart, btot, startv, cnt, dinv, pairs);
    k_norm <<<NB_E4, 256, 0, stream>>>(pairs, dinv);
    k_prep1<<<NB_N,  256, 0, stream>>>(x, xh);

    // ---- layer 1 (aggregate-first, 32-dim fp16) ----
    k_gatherH<32,false><<<6064, 256, 0, stream>>>(xh, dinv, startv, cnt, pairs, nullptr, nullptr, agg32);
    k_gemmMF<32>       <<<3032, 256, 0, stream>>>(agg32, Wh1, b1, hpre);
    hipMemsetAsync(gsum, 0, 512, stream);
    k_bn_reduce        <<<1024, 256, 0, stream>>>(hpre, gsum, gsq);
    k_bn_final         <<<1, 64, 0, stream>>>(gsum, gsq, g1, be1, scale1, shift1);
    // ---- layer 2 (BN1+ReLU fused into gather) ----
    k_gatherH<64,true> <<<12128, 256, 0, stream>>>(hpre, dinv, startv, cnt, pairs, scale1, shift1, agg64);
    k_gemmMF<64>       <<<3032,  256, 0, stream>>>(agg64, Wh2, b2, hpre);
    hipMemsetAsync(gsum, 0, 512, stream);
    k_bn_reduce        <<<1024,  256, 0, stream>>>(hpre, gsum, gsq);
    k_bn_final         <<<1, 64, 0, stream>>>(gsum, gsq, g2, be2, scale2l, shift2l);
    // ---- layer 3 ----
    k_gatherH<64,true> <<<12128, 256, 0, stream>>>(hpre, dinv, startv, cnt, pairs, scale2l, shift2l, agg64);
    k_gemmMF<64>       <<<3032,  256, 0, stream>>>(agg64, Wh3, b3, hpre);
    hipMemsetAsync(gsum, 0, 512, stream);
    k_bn_reduce        <<<1024,  256, 0, stream>>>(hpre, gsum, gsq);
    k_bn_final         <<<1, 64, 0, stream>>>(gsum, gsq, g3, be3, scale3, shift3);

    // ---- FC head (BN3+ReLU fused into FC1 A-staging) ----
    k_fc1      <<<758,  256, 0, stream>>>(hpre, Wl1, scale3, shift3, bufB);
    k_fc1_red1 <<<1024, 256, 0, stream>>>(bufB, part2);
    k_fc1_red2 <<<64,   256, 0, stream>>>(part2, bl1, Cfc);
    k_fc_stats <<<1,    128, 0, stream>>>(Cfc, gl1, bel1, scaleF, shiftF);
    k_fc2      <<<5,    256, 0, stream>>>(Cfc, scaleF, shiftF, Wl3, bl3, (float*)d_out);
}

// Round 9
// 532.581 us; speedup vs baseline: 4.0014x; 1.1016x over previous
//
#include <hip/hip_runtime.h>
#include <hip/hip_fp16.h>

#define N_TOTAL 194048
#define NE      3104768
#define HID     64
#define NNODES  1516
#define CIN     32
#define FIN     97024
#define EPS     1e-5f
#define NBUCK   758          // N_TOTAL / 256
#define NBLKC   256          // edge-chunk blocks
#define CHUNK   12128        // NE / NBLKC
#define FBLK    379          // FIN / 256
#define FCHUNK  256

using f16x8 = __attribute__((ext_vector_type(8))) _Float16;
using f32x4 = __attribute__((ext_vector_type(4))) float;

__device__ inline uint f2u(float a, float b){
    __half2 h = __floats2half2_rn(a, b);
    return *(const uint*)&h;
}
__device__ inline float2 u2f(uint u){
    __half2 h = *(const __half2*)&u;
    return __half22float2(h);
}

// ================= bucketed CSR build (no global atomics) =================
__global__ __launch_bounds__(256) void k_bktA(const int* __restrict__ col,
                                              int* __restrict__ blkhist){
    __shared__ int hist[NBUCK];
    int t = threadIdx.x;
    for (int i = t; i < NBUCK; i += 256) hist[i] = 0;
    __syncthreads();
    int base = blockIdx.x*CHUNK;
    for (int e = base + t; e < base + CHUNK; e += 256)
        atomicAdd(&hist[col[e] >> 8], 1);
    __syncthreads();
    for (int i = t; i < NBUCK; i += 256)
        blkhist[i*NBLKC + blockIdx.x] = hist[i];
}

// one block per bucket: scan its 256 block-counts
__global__ __launch_bounds__(256) void k_bktB1(const int* __restrict__ blkhist,
                                               int* __restrict__ blkoff,
                                               int* __restrict__ btot){
    int b = blockIdx.x, t = threadIdx.x;
    int v = blkhist[b*NBLKC + t];
    __shared__ int s[256];
    s[t] = v; __syncthreads();
    for (int off = 1; off < 256; off <<= 1){
        int u = (t >= off) ? s[t-off] : 0;
        __syncthreads();
        s[t] += u;
        __syncthreads();
    }
    blkoff[b*NBLKC + t] = s[t] - v;
    if (t == 255) btot[b] = s[255];
}

__global__ __launch_bounds__(256) void k_bktB2(const int* __restrict__ btot, int* __restrict__ bstart){
    __shared__ int s[256];
    int t = threadIdx.x;
    int i0 = t*3;
    int a = (i0   < NBUCK) ? btot[i0]   : 0;
    int b = (i0+1 < NBUCK) ? btot[i0+1] : 0;
    int c = (i0+2 < NBUCK) ? btot[i0+2] : 0;
    int tot = a+b+c;
    s[t] = tot; __syncthreads();
    for (int off = 1; off < 256; off <<= 1){
        int u = (t >= off) ? s[t-off] : 0;
        __syncthreads();
        s[t] += u;
        __syncthreads();
    }
    int ex = s[t] - tot;
    if (i0   < NBUCK) bstart[i0]   = ex;
    if (i0+1 < NBUCK) bstart[i0+1] = ex + a;
    if (i0+2 < NBUCK) bstart[i0+2] = ex + a + b;
}

__global__ __launch_bounds__(256) void k_bktC(const int* __restrict__ row, const int* __restrict__ col,
                                              const float* __restrict__ w,
                                              const int* __restrict__ blkoff,
                                              const int* __restrict__ bstart,
                                              int2* __restrict__ pairsB){
    __shared__ int lbase[NBUCK];
    __shared__ int lrank[NBUCK];
    int t = threadIdx.x;
    for (int i = t; i < NBUCK; i += 256){
        lbase[i] = bstart[i] + blkoff[(size_t)i*NBLKC + blockIdx.x];
        lrank[i] = 0;
    }
    __syncthreads();
    int base = blockIdx.x*CHUNK;
    for (int e = base + t; e < base + CHUNK; e += 256){
        int c = col[e];
        int b = c >> 8;
        int rk = atomicAdd(&lrank[b], 1);
        pairsB[lbase[b] + rk] = make_int2(row[e] | ((c & 255) << 18), __float_as_int(w[e]));
    }
}

__global__ __launch_bounds__(256) void k_bktD(const int2* __restrict__ pairsB,
                                              const int* __restrict__ bstart,
                                              const int* __restrict__ btot,
                                              int* __restrict__ startv, int* __restrict__ cnt,
                                              float* __restrict__ dinv,
                                              int2* __restrict__ pairs){
    __shared__ int   nh[256];
    __shared__ float ws[256];
    __shared__ int   noff[256];
    __shared__ int   sc[256];
    int b = blockIdx.x, t = threadIdx.x;
    nh[t] = 0; ws[t] = 0.f;
    __syncthreads();
    int s0 = bstart[b];
    int n  = btot[b];
    for (int e = s0 + t; e < s0 + n; e += 256){
        int2 p = pairsB[e];
        int lo = (p.x >> 18) & 255;
        atomicAdd(&nh[lo], 1);
        atomicAdd(&ws[lo], __int_as_float(p.y));
    }
    __syncthreads();
    int my = nh[t];
    sc[t] = my; __syncthreads();
    for (int off = 1; off < 256; off <<= 1){
        int u = (t >= off) ? sc[t-off] : 0;
        __syncthreads();
        sc[t] += u;
        __syncthreads();
    }
    int ex = sc[t] - my;
    noff[t] = s0 + ex;
    int node = b*256 + t;
    startv[node] = s0 + ex;
    cnt[node]    = my;
    dinv[node]   = rsqrtf(1.0f + ws[t]);
    nh[t] = 0;
    __syncthreads();
    for (int e = s0 + t; e < s0 + n; e += 256){
        int2 p = pairsB[e];
        int lo = (p.x >> 18) & 255;
        int rk = atomicAdd(&nh[lo], 1);
        pairs[noff[lo] + rk] = make_int2(p.x & 0x3FFFF, p.y);
    }
}

__global__ __launch_bounds__(256) void k_norm(int2* __restrict__ pairs, const float* __restrict__ dinv){
    int s0 = (blockIdx.x*256 + threadIdx.x)*4;
    int4 a = *(const int4*)(pairs + s0);
    int4 b = *(const int4*)(pairs + s0 + 2);
    float d0 = dinv[a.x], d1 = dinv[a.z], d2 = dinv[b.x], d3 = dinv[b.z];
    a.y = __float_as_int(__int_as_float(a.y) * d0);
    a.w = __float_as_int(__int_as_float(a.w) * d1);
    b.y = __float_as_int(__int_as_float(b.y) * d2);
    b.w = __float_as_int(__int_as_float(b.w) * d3);
    *(int4*)(pairs + s0)     = a;
    *(int4*)(pairs + s0 + 2) = b;
}

// ---------------- transpose x [B][32][1516] -> xh fp16 [N][32] ----------------
__global__ __launch_bounds__(256) void k_prep1(const float* __restrict__ x, __half* __restrict__ xh){
    int idx = blockIdx.x*256 + threadIdx.x;
    if (idx >= N_TOTAL) return;
    int b = idx / NNODES, nn = idx - b*NNODES;
    const float* xp = x + (size_t)b*CIN*NNODES + nn;
    uint u[16];
    #pragma unroll
    for (int c2 = 0; c2 < 16; ++c2){
        float a0 = xp[(size_t)(2*c2)*NNODES];
        float a1 = xp[(size_t)(2*c2+1)*NNODES];
        u[c2] = f2u(a0, a1);
    }
    uint4* dst = (uint4*)(xh + (size_t)idx*CIN);
    dst[0] = make_uint4(u[0], u[1], u[2],  u[3]);
    dst[1] = make_uint4(u[4], u[5], u[6],  u[7]);
    dst[2] = make_uint4(u[8], u[9], u[10], u[11]);
    dst[3] = make_uint4(u[12],u[13],u[14], u[15]);
}

// ---------------- W fp32 -> fp16 (layer weights) ----------------
__global__ __launch_bounds__(256) void k_prepW(const float* __restrict__ W1, const float* __restrict__ W2,
                                               const float* __restrict__ W3,
                                               __half* __restrict__ Wh1, __half* __restrict__ Wh2,
                                               __half* __restrict__ Wh3){
    int t = blockIdx.x*256 + threadIdx.x;
    if (t < 2048) Wh1[t] = __float2half(W1[t]);
    if (t < 4096){ Wh2[t] = __float2half(W2[t]); Wh3[t] = __float2half(W3[t]); }
}

// ---------------- CSR gather, MLP-optimized, optional fused BN+ReLU ----------------
template<bool BN>
__device__ inline void acc4(float n, uint2 u, const float4& sc, const float4& sh,
                            float& a0, float& a1, float& a2, float& a3){
    float2 lo = u2f(u.x), hi = u2f(u.y);
    float v0, v1, v2, v3;
    if (BN){
        v0 = fmaxf(0.f, lo.x*sc.x + sh.x); v1 = fmaxf(0.f, lo.y*sc.y + sh.y);
        v2 = fmaxf(0.f, hi.x*sc.z + sh.z); v3 = fmaxf(0.f, hi.y*sc.w + sh.w);
    } else { v0 = lo.x; v1 = lo.y; v2 = hi.x; v3 = hi.y; }
    a0 += n*v0; a1 += n*v1; a2 += n*v2; a3 += n*v3;
}

template<int F, bool BN>
__global__ __launch_bounds__(256) void k_gatherH(const __half* __restrict__ h,
                                                 const float* __restrict__ dinv,
                                                 const int* __restrict__ startv,
                                                 const int* __restrict__ cnt,
                                                 const int2* __restrict__ pairs,
                                                 const float* __restrict__ scale,
                                                 const float* __restrict__ shift,
                                                 __half* __restrict__ agg){
    constexpr int LPN = F/4;
    int node = blockIdx.x*(256/LPN) + threadIdx.x/LPN;
    int q    = (threadIdx.x % LPN)*4;
    const __half* hq = h + q;
    float4 sc = make_float4(0,0,0,0), sh = make_float4(0,0,0,0);
    if (BN){ sc = *(const float4*)(scale + q); sh = *(const float4*)(shift + q); }
    float a0 = 0.f, a1 = 0.f, a2 = 0.f, a3 = 0.f;

    int s = startv[node];
    int e = s + cnt[node];
    for (; s + 4 <= e; s += 4){
        int2 p0 = pairs[s], p1 = pairs[s+1], p2 = pairs[s+2], p3 = pairs[s+3];
        uint2 u0 = *(const uint2*)(hq + (size_t)p0.x*F);
        uint2 u1 = *(const uint2*)(hq + (size_t)p1.x*F);
        uint2 u2v= *(const uint2*)(hq + (size_t)p2.x*F);
        uint2 u3 = *(const uint2*)(hq + (size_t)p3.x*F);
        acc4<BN>(__int_as_float(p0.y), u0,  sc, sh, a0, a1, a2, a3);
        acc4<BN>(__int_as_float(p1.y), u1,  sc, sh, a0, a1, a2, a3);
        acc4<BN>(__int_as_float(p2.y), u2v, sc, sh, a0, a1, a2, a3);
        acc4<BN>(__int_as_float(p3.y), u3,  sc, sh, a0, a1, a2, a3);
    }
    for (; s < e; ++s){
        int2 p0 = pairs[s];
        uint2 u0 = *(const uint2*)(hq + (size_t)p0.x*F);
        acc4<BN>(__int_as_float(p0.y), u0, sc, sh, a0, a1, a2, a3);
    }
    float di = dinv[node];
    a0 *= di; a1 *= di; a2 *= di; a3 *= di;
    uint2 us = *(const uint2*)(hq + (size_t)node*F);
    acc4<BN>(di*di, us, sc, sh, a0, a1, a2, a3);   // self-loop term
    *(uint2*)(agg + (size_t)node*F + q) = make_uint2(f2u(a0,a1), f2u(a2,a3));
}

// ---------------- MFMA GEMM: out fp16 [n][64] = agg[n][K](fp16) @ Wh[64][K]^T + b ----------------
template<int K>
__global__ __launch_bounds__(256) void k_gemmMF(const __half* __restrict__ hin,
                                                const __half* __restrict__ Wh,
                                                const float* __restrict__ bias,
                                                __half* __restrict__ out){
    __shared__ __align__(16) __half lds[4][16][72];
    int t = threadIdx.x;
    int wv = t >> 6, l = t & 63;
    int lr = l & 15, lk = (l >> 4) * 8;
    int node0 = blockIdx.x*64 + wv*16;

    f16x8 a0 = *(const f16x8*)(hin + (size_t)(node0 + lr)*K + lk);
    f16x8 a1;
    if (K == 64) a1 = *(const f16x8*)(hin + (size_t)(node0 + lr)*K + 32 + lk);

    f32x4 acc[4];
    #pragma unroll
    for (int tt = 0; tt < 4; ++tt){
        f16x8 b0 = *(const f16x8*)(Wh + (size_t)(tt*16 + lr)*K + lk);
        acc[tt] = (f32x4){0.f, 0.f, 0.f, 0.f};
        acc[tt] = __builtin_amdgcn_mfma_f32_16x16x32_f16(a0, b0, acc[tt], 0, 0, 0);
        if (K == 64){
            f16x8 b1 = *(const f16x8*)(Wh + (size_t)(tt*16 + lr)*K + 32 + lk);
            acc[tt] = __builtin_amdgcn_mfma_f32_16x16x32_f16(a1, b1, acc[tt], 0, 0, 0);
        }
    }
    #pragma unroll
    for (int tt = 0; tt < 4; ++tt){
        float bb = bias[tt*16 + lr];
        #pragma unroll
        for (int r = 0; r < 4; ++r)
            lds[wv][(l>>4)*4 + r][tt*16 + lr] = __float2half(acc[tt][r] + bb);
    }
    int rr = l >> 2, cc = (l & 3)*16;
    uint4 v0 = *(const uint4*)(&lds[wv][rr][cc]);
    uint4 v1 = *(const uint4*)(&lds[wv][rr][cc + 8]);
    *(uint4*)(out + (size_t)(node0 + rr)*64 + cc)     = v0;
    *(uint4*)(out + (size_t)(node0 + rr)*64 + cc + 8) = v1;
}

// ---------------- BN stats over node axis (fp16 input) ----------------
__global__ __launch_bounds__(256) void k_bn_reduce(const __half* __restrict__ x, float* gsum, float* gsq){
    int t = threadIdx.x;
    int f = t & 63, g4 = t >> 6;
    float s = 0.f, q = 0.f;
    for (int i = blockIdx.x*4 + g4; i < N_TOTAL; i += gridDim.x*4){
        float v = __half2float(x[(size_t)i*64 + f]);
        s += v; q += v*v;
    }
    __shared__ float sh[2][4][64];
    sh[0][g4][f] = s; sh[1][g4][f] = q;
    __syncthreads();
    if (t < 64){
        float ss = sh[0][0][t] + sh[0][1][t] + sh[0][2][t] + sh[0][3][t];
        float qq = sh[1][0][t] + sh[1][1][t] + sh[1][2][t] + sh[1][3][t];
        atomicAdd(&gsum[t], ss);
        atomicAdd(&gsq[t],  qq);
    }
}

__global__ void k_bn_final(const float* __restrict__ gsum, const float* __restrict__ gsq,
                           const float* __restrict__ g, const float* __restrict__ be,
                           float* scale, float* shift){
    int f = threadIdx.x;
    if (f < 64){
        float mean = gsum[f] / (float)N_TOTAL;
        float var  = gsq[f] / (float)N_TOTAL - mean*mean;
        float sc   = g[f] / sqrtf(var + EPS);
        scale[f] = sc;
        shift[f] = be[f] - mean*sc;
    }
}

// ---------------- FC1 on MFMA: C = relu(bn(A))(fp16) @ Wl1^T, split-K ----------------
// 379 blocks, K-chunk 256. W fp32 staged->fp16 LDS (stride 264: 2-way banks).
// BN+ReLU applied in-register on A fragments. 4 waves x 32 M-rows each.
__device__ inline f16x8 bn8(f16x8 v, const float4& s0, const float4& s1,
                            const float4& h0, const float4& h1){
    uint4 u = *(uint4*)&v;
    float2 p0 = u2f(u.x), p1 = u2f(u.y), p2 = u2f(u.z), p3 = u2f(u.w);
    float r0 = fmaxf(0.f, p0.x*s0.x + h0.x);
    float r1 = fmaxf(0.f, p0.y*s0.y + h0.y);
    float r2 = fmaxf(0.f, p1.x*s0.z + h0.z);
    float r3 = fmaxf(0.f, p1.y*s0.w + h0.w);
    float r4 = fmaxf(0.f, p2.x*s1.x + h1.x);
    float r5 = fmaxf(0.f, p2.y*s1.y + h1.y);
    float r6 = fmaxf(0.f, p3.x*s1.z + h1.z);
    float r7 = fmaxf(0.f, p3.y*s1.w + h1.w);
    uint4 o = make_uint4(f2u(r0,r1), f2u(r2,r3), f2u(r4,r5), f2u(r6,r7));
    return *(f16x8*)&o;
}

__global__ __launch_bounds__(256) void k_fc1MF(const __half* __restrict__ A,
                                               const float* __restrict__ Wl1,
                                               const float* __restrict__ scale,
                                               const float* __restrict__ shift,
                                               float* __restrict__ part){
    __shared__ __align__(16) __half Bh[128][264];
    int t = threadIdx.x;
    int kbase = blockIdx.x * FCHUNK;
    // stage Wl1 fp32 -> fp16 LDS (coalesced: wave reads 1 KB runs)
    #pragma unroll
    for (int i = 0; i < 32; ++i){
        int flat = i*1024 + t*4;
        int r = flat >> 8, k = flat & 255;
        float4 w = *(const float4*)(Wl1 + (size_t)r*FIN + kbase + k);
        *(uint2*)(&Bh[r][k]) = make_uint2(f2u(w.x, w.y), f2u(w.z, w.w));
    }

    int wv = t >> 6, l = t & 63;
    int lr = l & 15, lk = (l >> 4)*8;
    // BN coefs for this lane's two k-phases (feature = (kk&1)*32 + lk + j)
    float4 sc_e0 = *(const float4*)(scale + lk),      sc_e1 = *(const float4*)(scale + lk + 4);
    float4 sc_o0 = *(const float4*)(scale + 32 + lk), sc_o1 = *(const float4*)(scale + 36 + lk);
    float4 sh_e0 = *(const float4*)(shift + lk),      sh_e1 = *(const float4*)(shift + lk + 4);
    float4 sh_o0 = *(const float4*)(shift + 32 + lk), sh_o1 = *(const float4*)(shift + 36 + lk);

    const __half* Ar0 = A + (size_t)(wv*32 + lr)*FIN + kbase + lk;
    const __half* Ar1 = A + (size_t)(wv*32 + 16 + lr)*FIN + kbase + lk;

    f32x4 acc[2][8];
    #pragma unroll
    for (int m = 0; m < 2; ++m)
        #pragma unroll
        for (int n = 0; n < 8; ++n) acc[m][n] = (f32x4){0.f, 0.f, 0.f, 0.f};

    __syncthreads();
    #pragma unroll
    for (int kk = 0; kk < 8; ++kk){
        int ko = kk*32;
        f16x8 a0 = *(const f16x8*)(Ar0 + ko);
        f16x8 a1 = *(const f16x8*)(Ar1 + ko);
        if (kk & 1){
            a0 = bn8(a0, sc_o0, sc_o1, sh_o0, sh_o1);
            a1 = bn8(a1, sc_o0, sc_o1, sh_o0, sh_o1);
        } else {
            a0 = bn8(a0, sc_e0, sc_e1, sh_e0, sh_e1);
            a1 = bn8(a1, sc_e0, sc_e1, sh_e0, sh_e1);
        }
        #pragma unroll
        for (int n = 0; n < 8; ++n){
            f16x8 b = *(const f16x8*)(&Bh[n*16 + lr][ko + lk]);
            acc[0][n] = __builtin_amdgcn_mfma_f32_16x16x32_f16(a0, b, acc[0][n], 0, 0, 0);
            acc[1][n] = __builtin_amdgcn_mfma_f32_16x16x32_f16(a1, b, acc[1][n], 0, 0, 0);
        }
    }
    // store partials: C/D mapping col=l&15, row=(l>>4)*4+r
    float* pp = part + (size_t)blockIdx.x*16384;
    #pragma unroll
    for (int m = 0; m < 2; ++m)
        #pragma unroll
        for (int n = 0; n < 8; ++n)
            #pragma unroll
            for (int r = 0; r < 4; ++r)
                pp[(wv*32 + m*16 + (l>>4)*4 + r)*128 + n*16 + lr] = acc[m][n][r];
}

// ---- two-stage split-K reduce (full occupancy, coalesced) ----
__global__ __launch_bounds__(256) void k_fc1_red1(const float* __restrict__ part,
                                                  float* __restrict__ part2){
    int idx = (blockIdx.x & 63)*256 + threadIdx.x;   // 0..16383
    int seg = blockIdx.x >> 6;                        // 0..15
    int k0 = seg*24;
    int k1 = k0 + 24 < FBLK ? k0 + 24 : FBLK;
    float s = 0.f;
    for (int kc = k0; kc < k1; ++kc) s += part[(size_t)kc*16384 + idx];
    part2[(size_t)seg*16384 + idx] = s;
}

__global__ __launch_bounds__(256) void k_fc1_red2(const float* __restrict__ part2,
                                                  const float* __restrict__ bl1,
                                                  float* __restrict__ C){
    int idx = blockIdx.x*256 + threadIdx.x;
    float s = 0.f;
    #pragma unroll
    for (int i = 0; i < 16; ++i) s += part2[(size_t)i*16384 + idx];
    C[idx] = s + bl1[idx & 127];
}

__global__ void k_fc_stats(const float* __restrict__ C, const float* __restrict__ g,
                           const float* __restrict__ be, float* scale2, float* shift2){
    int j = threadIdx.x;
    if (j < 128){
        float s = 0.f, q = 0.f;
        for (int b = 0; b < 128; ++b){ float v = C[b*128 + j]; s += v; q += v*v; }
        float mean = s / 128.f;
        float var  = q / 128.f - mean*mean;
        float sc   = g[j] / sqrtf(var + EPS);
        scale2[j] = sc;
        shift2[j] = be[j] - mean*sc;
    }
}

__global__ __launch_bounds__(256) void k_fc2(const float* __restrict__ C, const float* __restrict__ scale2,
                                             const float* __restrict__ shift2, const float* __restrict__ Wl3,
                                             const float* __restrict__ bl3, float* __restrict__ out){
    int id = blockIdx.x*256 + threadIdx.x;
    if (id < 1280){
        int b = id / 10, c = id - b*10;
        float acc = bl3[c];
        for (int j = 0; j < 128; ++j){
            float hv = fmaxf(0.f, C[b*128 + j]*scale2[j] + shift2[j]);
            acc += hv * Wl3[c*128 + j];
        }
        out[id] = acc;
    }
}

// ---------------- launch ----------------
extern "C" void kernel_launch(void* const* d_in, const int* in_sizes, int n_in,
                              void* d_out, int out_size, void* d_ws, size_t ws_size,
                              hipStream_t stream){
    const float* x   = (const float*)d_in[0];
    const int*   ei  = (const int*)  d_in[1];
    const float* ew  = (const float*)d_in[2];
    const float* W1  = (const float*)d_in[3];
    const float* b1  = (const float*)d_in[4];
    const float* W2  = (const float*)d_in[5];
    const float* b2  = (const float*)d_in[6];
    const float* W3  = (const float*)d_in[7];
    const float* b3  = (const float*)d_in[8];
    const float* g1  = (const float*)d_in[9];
    const float* be1 = (const float*)d_in[10];
    const float* g2  = (const float*)d_in[11];
    const float* be2 = (const float*)d_in[12];
    const float* g3  = (const float*)d_in[13];
    const float* be3 = (const float*)d_in[14];
    const float* Wl1 = (const float*)d_in[15];
    const float* bl1 = (const float*)d_in[16];
    const float* gl1 = (const float*)d_in[17];
    const float* bel1= (const float*)d_in[18];
    const float* Wl3 = (const float*)d_in[19];
    const float* bl3 = (const float*)d_in[20];
    const int* row = ei;
    const int* col = ei + NE;

    char* p = (char*)d_ws;
    auto alloc = [&](size_t bytes)->char*{
        char* r = p; p += (bytes + 255) & ~(size_t)255; return r;
    };
    float*  bufB     = (float*)alloc((size_t)FBLK*16384*4);     // agg scratch / FC1 partials
    float*  part2    = (float*)alloc((size_t)16*16384*4);
    __half* hpre     = (__half*)alloc((size_t)N_TOTAL*64*2);    // conv out fp16 (pre-BN)
    __half* xh       = (__half*)alloc((size_t)N_TOTAL*32*2);    // transposed input fp16
    float*  dinv     = (float*)alloc(N_TOTAL*4);
    int*    cnt      = (int*)  alloc(N_TOTAL*4);
    int*    startv   = (int*)  alloc(N_TOTAL*4);
    int2*   pairsB   = (int2*) alloc((size_t)NE*8);
    int2*   pairs    = (int2*) alloc((size_t)NE*8);
    int*    blkhist  = (int*)  alloc((size_t)NBUCK*NBLKC*4);
    int*    blkoff   = (int*)  alloc((size_t)NBUCK*NBLKC*4);
    int*    btot     = (int*)  alloc(NBUCK*4);
    int*    bstart   = (int*)  alloc(NBUCK*4);
    __half* Wh1      = (__half*)alloc(2048*2);
    __half* Wh2      = (__half*)alloc(4096*2);
    __half* Wh3      = (__half*)alloc(4096*2);
    float*  gsum     = (float*)alloc(256);
    float*  gsq      = (float*)alloc(256);
    float*  scale1   = (float*)alloc(256);
    float*  shift1   = (float*)alloc(256);
    float*  scale2l  = (float*)alloc(256);
    float*  shift2l  = (float*)alloc(256);
    float*  scale3   = (float*)alloc(256);
    float*  shift3   = (float*)alloc(256);
    float*  Cfc      = (float*)alloc(65536);
    float*  scaleF   = (float*)alloc(512);
    float*  shiftF   = (float*)alloc(512);
    __half* agg32    = (__half*)bufB;
    __half* agg64    = (__half*)bufB;

    const int NB_N  = 758;     // N_TOTAL/256
    const int NB_E4 = 3032;    // NE/4/256
    k_prepW<<<16,    256, 0, stream>>>(W1, W2, W3, Wh1, Wh2, Wh3);
    k_bktA <<<NBLKC, 256, 0, stream>>>(col, blkhist);
    k_bktB1<<<NBUCK, 256, 0, stream>>>(blkhist, blkoff, btot);
    k_bktB2<<<1,     256, 0, stream>>>(btot, bstart);
    k_bktC <<<NBLKC, 256, 0, stream>>>(row, col, ew, blkoff, bstart, pairsB);
    k_bktD <<<NBUCK, 256, 0, stream>>>(pairsB, bstart, btot, startv, cnt, dinv, pairs);
    k_norm <<<NB_E4, 256, 0, stream>>>(pairs, dinv);
    k_prep1<<<NB_N,  256, 0, stream>>>(x, xh);

    // ---- layer 1 (aggregate-first, 32-dim fp16) ----
    k_gatherH<32,false><<<6064, 256, 0, stream>>>(xh, dinv, startv, cnt, pairs, nullptr, nullptr, agg32);
    k_gemmMF<32>       <<<3032, 256, 0, stream>>>(agg32, Wh1, b1, hpre);
    hipMemsetAsync(gsum, 0, 512, stream);
    k_bn_reduce        <<<1024, 256, 0, stream>>>(hpre, gsum, gsq);
    k_bn_final         <<<1, 64, 0, stream>>>(gsum, gsq, g1, be1, scale1, shift1);
    // ---- layer 2 (BN1+ReLU fused into gather) ----
    k_gatherH<64,true> <<<12128, 256, 0, stream>>>(hpre, dinv, startv, cnt, pairs, scale1, shift1, agg64);
    k_gemmMF<64>       <<<3032,  256, 0, stream>>>(agg64, Wh2, b2, hpre);
    hipMemsetAsync(gsum, 0, 512, stream);
    k_bn_reduce        <<<1024,  256, 0, stream>>>(hpre, gsum, gsq);
    k_bn_final         <<<1, 64, 0, stream>>>(gsum, gsq, g2, be2, scale2l, shift2l);
    // ---- layer 3 ----
    k_gatherH<64,true> <<<12128, 256, 0, stream>>>(hpre, dinv, startv, cnt, pairs, scale2l, shift2l, agg64);
    k_gemmMF<64>       <<<3032,  256, 0, stream>>>(agg64, Wh3, b3, hpre);
    hipMemsetAsync(gsum, 0, 512, stream);
    k_bn_reduce        <<<1024,  256, 0, stream>>>(hpre, gsum, gsq);
    k_bn_final         <<<1, 64, 0, stream>>>(gsum, gsq, g3, be3, scale3, shift3);

    // ---- FC head (BN3+ReLU fused into FC1 A-fragments, MFMA) ----
    k_fc1MF    <<<FBLK, 256, 0, stream>>>(hpre, Wl1, scale3, shift3, bufB);
    k_fc1_red1 <<<1024, 256, 0, stream>>>(bufB, part2);
    k_fc1_red2 <<<64,   256, 0, stream>>>(part2, bl1, Cfc);
    k_fc_stats <<<1,    128, 0, stream>>>(Cfc, gl1, bel1, scaleF, shiftF);
    k_fc2      <<<5,    256, 0, stream>>>(Cfc, scaleF, shiftF, Wl3, bl3, (float*)d_out);
}